// Round 8
// baseline (245.503 us; speedup 1.0000x reference)
//
#include <hip/hip_runtime.h>
#include <math.h>

#define BN   2
#define CIN  96
#define HH   40
#define WW   40
#define LL   1600
#define DIN  192
#define NS   16
#define RR   6
#define KK   4
#define CH   25   // chunk length per lane (LL/64)

__device__ __forceinline__ float sigmoidf_(float x){ return 1.0f/(1.0f+expf(-x)); }
__device__ __forceinline__ float softplus_fast(float x){
  return x > 20.0f ? x : __logf(1.0f + __expf(x));
}

// ---------------- K1: in_proj (1x1) for both modalities ----------------
// grid: (L/16, 2*B), block 256. xproj layout [mb][o][p]
__global__ void k_inproj(const float* __restrict__ x_rgb, const float* __restrict__ x_e,
                         const float* __restrict__ w_rgb, const float* __restrict__ w_e,
                         float* __restrict__ xproj){
  __shared__ float xin[16][100];          // [px][c], padded row
  int l0 = blockIdx.x * 16;
  int mb = blockIdx.y;                    // m*BN + b
  int m = mb / BN, b = mb % BN;
  const float* xsrc = (m == 0 ? x_rgb : x_e) + (size_t)b * CIN * LL;
  const float* w    = (m == 0 ? w_rgb : w_e);
  for (int idx = threadIdx.x; idx < CIN * 16; idx += 256){
    int c = idx >> 4, px = idx & 15;
    xin[px][c] = xsrc[c * LL + l0 + px];
  }
  __syncthreads();
  int px = threadIdx.x & 15;
  int o0 = (threadIdx.x >> 4) * 12;       // 16 groups x 12 outputs
  float acc[12];
  #pragma unroll
  for (int i = 0; i < 12; ++i) acc[i] = 0.f;
  const float4* xv = reinterpret_cast<const float4*>(xin[px]);
  for (int cc = 0; cc < CIN / 4; ++cc){
    float4 x4 = xv[cc];
    #pragma unroll
    for (int i = 0; i < 12; ++i){
      float4 w4 = *reinterpret_cast<const float4*>(w + (o0 + i) * CIN + cc * 4);
      acc[i] += w4.x * x4.x + w4.y * x4.y + w4.z * x4.z + w4.w * x4.w;
    }
  }
  #pragma unroll
  for (int i = 0; i < 12; ++i)
    xproj[((size_t)mb * DIN + o0 + i) * LL + l0 + px] = acc[i];
}

// ------ K2: depthwise 3x3 + bias + SiLU; emit x_act, x_actT, u_ch, SE mean ---
// grid: (DIN, 2*B), block 256
__global__ void k_conv(const float* __restrict__ xproj, const float* __restrict__ conv_w,
                       const float* __restrict__ conv_b, float* __restrict__ x_act,
                       float* __restrict__ x_actT, float* __restrict__ u_chA,
                       float* __restrict__ u_chT, float* __restrict__ sq){
  __shared__ float pl[LL];
  __shared__ float sact[LL + HH];    // padded: index l + l/40
  __shared__ float red[4];
  int d  = blockIdx.x;
  int mb = blockIdx.y;
  const float* src = xproj + ((size_t)mb * DIN + d) * LL;
  for (int p = threadIdx.x; p < LL; p += blockDim.x) pl[p] = src[p];
  __syncthreads();
  float cw[9];
  #pragma unroll
  for (int j = 0; j < 9; ++j) cw[j] = conv_w[d * 9 + j];
  float bias = conv_b[d];
  float* dst = x_act + ((size_t)mb * DIN + d) * LL;
  float lsum = 0.f;
  for (int p = threadIdx.x; p < LL; p += blockDim.x){
    int py = p / WW, px = p % WW;
    float acc = bias;
    #pragma unroll
    for (int dy = -1; dy <= 1; ++dy){
      int yy = py + dy;
      if (yy < 0 || yy >= HH) continue;
      #pragma unroll
      for (int dx = -1; dx <= 1; ++dx){
        int xx = px + dx;
        if (xx < 0 || xx >= WW) continue;
        acc += cw[(dy + 1) * 3 + (dx + 1)] * pl[yy * WW + xx];
      }
    }
    float s = acc * sigmoidf_(acc);
    dst[p] = s;
    sact[p + p / WW] = s;
    lsum += s;
  }
  #pragma unroll
  for (int off = 32; off; off >>= 1) lsum += __shfl_down(lsum, off);
  if ((threadIdx.x & 63) == 0) red[threadIdx.x >> 6] = lsum;
  __syncthreads();
  if (threadIdx.x == 0)
    sq[mb * DIN + d] = (red[0] + red[1] + red[2] + red[3]) * (1.0f / LL);
  size_t po = ((size_t)mb * DIN + d) * LL;
  float* dstT = x_actT + po;
  float* uA   = u_chA + po;
  float* uT   = u_chT + po;
  for (int q = threadIdx.x; q < LL; q += blockDim.x){
    // transposed plane (row-major in q)
    int lt = (q % WW) * WW + q / WW;
    dstT[q] = sact[lt + lt / WW];
    // chunk-order planes: q = s*64+g  <->  l = g*25+s
    int l = (q & 63) * CH + (q >> 6);
    uA[q] = sact[l + l / WW];
    int pt = (l % WW) * WW + l / WW;
    uT[q] = sact[pt + pt / WW];
  }
}

// ------ K3: x_proj -> tdt_ch [mbk][r][q]; B/C in [mbk][n/4][q][4] layout ---
// grid: (L/64, K, 2*B), block 256
__global__ void k_xproj(const float* __restrict__ x_act, const float* __restrict__ x_actT,
                        const float* __restrict__ xp1, const float* __restrict__ xp2,
                        float* __restrict__ tdt_ch, float* __restrict__ B_ch,
                        float* __restrict__ C_ch){
  __shared__ float xs_t[DIN][64];
  int l0 = blockIdx.x * 64;
  int k  = blockIdx.y;
  int mb = blockIdx.z; int m = mb / BN;
  const float* xw = (m == 0 ? xp1 : xp2) + k * 38 * DIN;
  const float* xa = ((k & 1) ? x_actT : x_act) + (size_t)mb * DIN * LL;
  bool rev = (k >= 2);
  for (int idx = threadIdx.x; idx < DIN * 64; idx += blockDim.x){
    int dd = idx >> 6, ll = idx & 63;
    int l = l0 + ll; if (rev) l = LL - 1 - l;
    xs_t[dd][ll] = xa[dd * LL + l];
  }
  __syncthreads();
  int mbk = mb * KK + k;
  for (int oidx = threadIdx.x; oidx < 38 * 64; oidx += blockDim.x){
    int c = oidx >> 6, ll = oidx & 63;
    const float* wr = xw + c * DIN;
    float acc = 0.f;
    #pragma unroll 8
    for (int dd = 0; dd < DIN; ++dd) acc += wr[dd] * xs_t[dd][ll];
    int l = l0 + ll;
    int q = (l % CH) * 64 + l / CH;     // chunk-order index
    if (c < RR){
      tdt_ch[((size_t)mbk * RR + c) * LL + q] = acc;
    } else if (c < RR + NS){
      int n = c - RR;
      B_ch[(((size_t)mbk * 4 + (n >> 2)) * LL + q) * 4 + (n & 3)] = acc;
    } else {
      int n = c - RR - NS;
      C_ch[(((size_t)mbk * 4 + (n >> 2)) * LL + q) * 4 + (n & 3)] = acc;
    }
  }
}

// ---------------- K4: chunked parallel selective scan, n-split ----------
// 2 waves per chain (each owns 8 of 16 states). Coalesced interleaved-4
// B/C loads. Phase 1 emits y_local (with C); phase 2 adds carry correction
// y += sum_n carry[n]*exp(An*cumdt_s)*C[s][n] (no u/B re-loads).
// grid: 1536 blocks of 256 (2 chains/block). y_px layout [chain][pixel]
__global__ void __launch_bounds__(256, 6) k_scan(
    const float* __restrict__ u_chA, const float* __restrict__ u_chT,
    const float* __restrict__ tdt_all, const float* __restrict__ B_ch,
    const float* __restrict__ C_ch,
    const float* __restrict__ Alog1, const float* __restrict__ Alog2,
    const float* __restrict__ D1, const float* __restrict__ D2,
    const float* __restrict__ dtw1, const float* __restrict__ dtb1,
    const float* __restrict__ dtw2, const float* __restrict__ dtb2,
    float* __restrict__ y_px){
  __shared__ float ystage[2][LL + HH];      // [chain-in-blk][pad l]
  __shared__ float dt_lds[2][LL];           // [chain-in-blk][q]
  int wv   = threadIdx.x >> 6;
  int lane = threadIdx.x & 63;
  int c    = wv >> 1;                       // chain in block
  int nh   = wv & 1;                        // n-half
  int chain = blockIdx.x * 2 + c;           // = (mb*KK + k)*DIN + d
  int d   = chain % DIN;
  int mbk = chain / DIN;
  int k   = mbk % KK;
  int mb  = mbk / KK;
  int m = mb / BN, b = mb % BN;
  int kd = k * DIN + d;
  bool rev = (k >= 2);

  // zero the shared accumulator (barrier below covers this)
  for (int i = threadIdx.x; i < 2 * (LL + HH); i += 256)
    (&ystage[0][0])[i] = 0.f;

  const float* Alog = (m == 0 ? Alog1 : Alog2) + kd * NS + nh * 8;
  float An[8];
  #pragma unroll
  for (int n = 0; n < 8; ++n) An[n] = -__expf(Alog[n]);
  float Dv = (m == 0 ? D2 : D1)[kd];
  const float* dtw = (m == 0 ? dtw1 : dtw2) + kd * RR;
  float w0 = dtw[0], w1 = dtw[1], w2 = dtw[2], w3 = dtw[3], w4 = dtw[4], w5 = dtw[5];
  float dbias = (m == 0 ? dtb1 : dtb2)[kd];

  const float* t0 = tdt_all + (size_t)mbk * RR * LL;    // [r][q] rows
  const float4* B0 = reinterpret_cast<const float4*>(B_ch) + ((size_t)mbk * 4 + 2 * nh) * LL;
  const float4* B1 = B0 + LL;
  int mbk_o = ((1 - m) * BN + b) * KK + k;              // other modality's C
  const float4* C0 = reinterpret_cast<const float4*>(C_ch) + ((size_t)mbk_o * 4 + 2 * nh) * LL;
  const float4* C1 = C0 + LL;
  const float* urow = ((k & 1) ? u_chT : u_chA) + ((size_t)mb * DIN + d) * LL;

  // dt for the whole chain, computed once, split across the 2 n-half waves
  {
    int s_begin = nh ? 13 : 0;
    int s_end   = nh ? CH : 13;
    for (int s = s_begin; s < s_end; ++s){
      int q = s * 64 + lane;
      float dtpre = w0 * t0[q] + w1 * t0[LL + q] + w2 * t0[2 * LL + q]
                  + w3 * t0[3 * LL + q] + w4 * t0[4 * LL + q] + w5 * t0[5 * LL + q] + dbias;
      dt_lds[c][q] = softplus_fast(dtpre);
    }
  }
  __syncthreads();

  float h[8];
  #pragma unroll
  for (int n = 0; n < 8; ++n) h[n] = 0.f;
  float Sdt = 0.f;

  // phase 1: local chunk scan; emit y_local (local-h dot C) per step
  #pragma unroll 5
  for (int s = 0; s < CH; ++s){
    int q = s * 64 + lane;
    float dt = dt_lds[c][q];
    Sdt += dt;
    float u  = urow[rev ? (LL - 1 - q) : q];
    float du = dt * u;
    float4 b0 = B0[q], b1 = B1[q];
    float4 c0 = C0[q], c1 = C1[q];
    float Bv[8] = {b0.x, b0.y, b0.z, b0.w, b1.x, b1.y, b1.z, b1.w};
    float Cv[8] = {c0.x, c0.y, c0.z, c0.w, c1.x, c1.y, c1.z, c1.w};
    float y = (nh == 0) ? Dv * u : 0.f;
    #pragma unroll
    for (int n = 0; n < 8; ++n){
      float dA = __expf(dt * An[n]);
      h[n] = dA * h[n] + du * Bv[n];
      y += h[n] * Cv[n];
    }
    int l = lane * CH + s;
    atomicAdd(&ystage[c][l + l / WW], y);
  }
  float aP[8];
  #pragma unroll
  for (int n = 0; n < 8; ++n) aP[n] = __expf(Sdt * An[n]);

  // Kogge-Stone inclusive scan of (aP,h) across 64 lanes (chunk order)
  #pragma unroll
  for (int off = 1; off < 64; off <<= 1){
    #pragma unroll
    for (int n = 0; n < 8; ++n){
      float ap = __shfl_up(aP[n], off);
      float bp = __shfl_up(h[n],  off);
      if (lane >= off){
        h[n]  = aP[n] * bp + h[n];
        aP[n] = aP[n] * ap;
      }
    }
  }
  // carry-in for this chunk = inclusive result of previous lane
  #pragma unroll
  for (int n = 0; n < 8; ++n){
    float v = __shfl_up(h[n], 1);
    h[n] = (lane == 0) ? 0.f : v;       // h[] now holds the carry
  }
  // phase 2: correction pass — y += sum_n carry[n]*exp(An*cumdt_s)*C[s][n]
  float cum = 0.f;
  #pragma unroll 5
  for (int s = 0; s < CH; ++s){
    int q = s * 64 + lane;
    cum += dt_lds[c][q];
    float4 c0 = C0[q], c1 = C1[q];
    float Cv[8] = {c0.x, c0.y, c0.z, c0.w, c1.x, c1.y, c1.z, c1.w};
    float corr = 0.f;
    #pragma unroll
    for (int n = 0; n < 8; ++n){
      corr += h[n] * __expf(cum * An[n]) * Cv[n];
    }
    int l = lane * CH + s;
    atomicAdd(&ystage[c][l + l / WW], corr);
  }
  __syncthreads();
  // flush in PIXEL order; fold reversal (k>=2) + transpose (k odd) here.
  // both chains of this block share the same k.
  for (int idx = threadIdx.x; idx < 2 * LL; idx += 256){
    int cc = idx / LL, qq = idx - cc * LL;
    int l;
    if      (k == 0) l = qq;
    else if (k == 1) l = (qq % WW) * WW + qq / WW;
    else if (k == 2) l = LL - 1 - qq;
    else             { int qt = (qq % WW) * WW + qq / WW; l = LL - 1 - qt; }
    y_px[(size_t)(blockIdx.x * 2 + cc) * LL + qq] = ystage[cc][l + l / WW];
  }
}

// ------ K5: merge (4 coalesced adds) + LayerNorm + fused cross SE -------
// grid: (L/32, 2*B), block 256. y_final layout [mb][p][d]
__global__ void k_merge(const float* __restrict__ y_px, const float* __restrict__ sq,
                        const float* __restrict__ fc1_w1, const float* __restrict__ fc1_w2,
                        const float* __restrict__ fc2_w1, const float* __restrict__ fc2_w2,
                        const float* __restrict__ n1g, const float* __restrict__ n1b,
                        const float* __restrict__ n2g, const float* __restrict__ n2b,
                        float* __restrict__ y_final){
  __shared__ float acc[DIN][33];
  __shared__ float ps[8][32], ps2[8][32];
  __shared__ float mu_s[32], inv_s[32];
  __shared__ float sqs[DIN], hid[12], exc_s[DIN];
  int p0 = blockIdx.x * 32;
  int mb = blockIdx.y; int m = mb / BN, b = mb % BN;
  const float* yb = y_px + (size_t)mb * KK * DIN * LL;
  for (int idx = threadIdx.x; idx < DIN * 32; idx += 256){
    int dd = idx >> 5, pp = idx & 31;
    size_t o = (size_t)dd * LL + p0 + pp;
    acc[dd][pp] = yb[o] + yb[(size_t)DIN * LL + o]
                + yb[2 * (size_t)DIN * LL + o] + yb[3 * (size_t)DIN * LL + o];
  }
  // cross SE: y_m is scaled by exc of modality (1-m)
  int mbo = (1 - m) * BN + b;
  const float* w1 = (m == 1 ? fc1_w1 : fc2_w1);
  const float* w2 = (m == 1 ? fc1_w2 : fc2_w2);
  if (threadIdx.x < DIN) sqs[threadIdx.x] = sq[mbo * DIN + threadIdx.x];
  __syncthreads();
  if (threadIdx.x < 12){
    float a = 0.f;
    for (int cch = 0; cch < DIN; ++cch) a += w1[threadIdx.x * DIN + cch] * sqs[cch];
    hid[threadIdx.x] = a * sigmoidf_(a);
  }
  {
    int pp = threadIdx.x & 31, qr = threadIdx.x >> 5;
    float s = 0.f, s2 = 0.f;
    #pragma unroll 4
    for (int j = 0; j < 24; ++j){ float v = acc[qr * 24 + j][pp]; s += v; s2 += v * v; }
    ps[qr][pp] = s; ps2[qr][pp] = s2;
  }
  __syncthreads();
  if (threadIdx.x < 32){
    int pp = threadIdx.x;
    float s = 0.f, s2 = 0.f;
    #pragma unroll
    for (int qr = 0; qr < 8; ++qr){ s += ps[qr][pp]; s2 += ps2[qr][pp]; }
    float mu  = s * (1.0f / DIN);
    float var = s2 * (1.0f / DIN) - mu * mu;
    mu_s[pp] = mu; inv_s[pp] = rsqrtf(var + 1e-5f);
  }
  if (threadIdx.x >= 64 && threadIdx.x < 64 + DIN){
    int dd = threadIdx.x - 64;
    float e = 0.f;
    #pragma unroll
    for (int j = 0; j < 12; ++j) e += w2[dd * 12 + j] * hid[j];
    exc_s[dd] = sigmoidf_(e);
  }
  __syncthreads();
  const float* g  = (m == 0 ? n1g : n2g);
  const float* bb = (m == 0 ? n1b : n2b);
  for (int idx = threadIdx.x; idx < DIN * 32; idx += 256){
    int pp = idx / DIN, dd = idx - pp * DIN;
    float v = (acc[dd][pp] - mu_s[pp]) * inv_s[pp] * g[dd] + bb[dd];
    v *= exc_s[dd];
    y_final[((size_t)mb * LL + p0 + pp) * DIN + dd] = v;
  }
}

// ---------------- K6: out_proj (96 x 384) ----------------
// grid: (L/16, B), block 256. float4 chunks, reg-blocked 6 outputs
__global__ void k_out(const float* __restrict__ y_final, const float* __restrict__ wout,
                      float* __restrict__ out){
  __shared__ float yt[16][388];
  int p0 = blockIdx.x * 16;
  int b  = blockIdx.y;
  for (int idx = threadIdx.x; idx < 16 * 384; idx += 256){
    int pp = idx / 384, cch = idx % 384;
    int m = cch / DIN, dd = cch % DIN;
    yt[pp][cch] = y_final[(((size_t)(m * BN + b)) * LL + p0 + pp) * DIN + dd];
  }
  __syncthreads();
  int pp = threadIdx.x & 15;
  int o0 = (threadIdx.x >> 4) * 6;       // 16 groups x 6 outputs
  float acc[6];
  #pragma unroll
  for (int i = 0; i < 6; ++i) acc[i] = 0.f;
  const float4* yv = reinterpret_cast<const float4*>(yt[pp]);
  for (int cc = 0; cc < 96; ++cc){
    float4 x4 = yv[cc];
    #pragma unroll
    for (int i = 0; i < 6; ++i){
      float4 w4 = *reinterpret_cast<const float4*>(wout + (o0 + i) * 2 * DIN + cc * 4);
      acc[i] += w4.x * x4.x + w4.y * x4.y + w4.z * x4.z + w4.w * x4.w;
    }
  }
  #pragma unroll
  for (int i = 0; i < 6; ++i)
    out[((size_t)b * CIN + o0 + i) * LL + p0 + pp] = acc[i];
}

extern "C" void kernel_launch(void* const* d_in, const int* in_sizes, int n_in,
                              void* d_out, int out_size, void* d_ws, size_t ws_size,
                              hipStream_t stream){
  const float* x_rgb   = (const float*)d_in[0];
  const float* x_e     = (const float*)d_in[1];
  const float* in_w    = (const float*)d_in[2];
  const float* in_mx_w = (const float*)d_in[3];
  const float* conv_w  = (const float*)d_in[4];
  const float* conv_b  = (const float*)d_in[5];
  const float* xp1     = (const float*)d_in[6];
  const float* xp2     = (const float*)d_in[7];
  const float* dtw1    = (const float*)d_in[8];
  const float* dtb1    = (const float*)d_in[9];
  const float* dtw2    = (const float*)d_in[10];
  const float* dtb2    = (const float*)d_in[11];
  const float* Alog1   = (const float*)d_in[12];
  const float* Alog2   = (const float*)d_in[13];
  const float* D1      = (const float*)d_in[14];
  const float* D2      = (const float*)d_in[15];
  const float* n1g     = (const float*)d_in[16];
  const float* n1b     = (const float*)d_in[17];
  const float* n2g     = (const float*)d_in[18];
  const float* n2b     = (const float*)d_in[19];
  const float* fc1_w1  = (const float*)d_in[20];
  const float* fc1_w2  = (const float*)d_in[21];
  const float* fc2_w1  = (const float*)d_in[22];
  const float* fc2_w2  = (const float*)d_in[23];
  const float* wout    = (const float*)d_in[24];

  float* ws = (float*)d_ws;
  // region plan (floats), total 12,032,768 (= 48.1 MB):
  //   [0,        1228800) u_chA   (k_conv -> k_scan)
  //   [1228800,  2457600) u_chT   (k_conv -> k_scan)
  //   [2457600,  3686400) x_act   (k_conv -> k_xproj); y_final aliases after
  //   [3686400,  4915200) x_actT  (k_conv -> k_xproj)
  //   [4915200,  6144000) xproj   (k_inproj -> k_conv)
  //   [6144000, 11059200) y_px    (k_scan -> k_merge)
  //   [11059200,11468800) B_ch    [mbk][n/4][q][4]
  //   [11468800,11878400) C_ch    [mbk][n/4][q][4]
  //   [11878400,12032000) tdt_ch  [mbk][r][q]
  //   [12032000,12032768) sq
  float* u_chA   = ws;
  float* u_chT   = ws + 1228800;
  float* x_act   = ws + 2457600;
  float* x_actT  = ws + 3686400;
  float* xproj   = ws + 4915200;
  float* y_final = ws + 2457600;      // alias: x_act dead after k_xproj
  float* y_px    = ws + 6144000;
  float* B_ch    = ws + 11059200;
  float* C_ch    = ws + 11468800;
  float* tdt_ch  = ws + 11878400;
  float* sq      = ws + 12032000;

  k_inproj<<<dim3(LL / 16, 2 * BN), 256, 0, stream>>>(x_rgb, x_e, in_w, in_mx_w, xproj);
  k_conv  <<<dim3(DIN, 2 * BN), 256, 0, stream>>>(xproj, conv_w, conv_b,
                                                  x_act, x_actT, u_chA, u_chT, sq);
  k_xproj <<<dim3(LL / 64, KK, 2 * BN), 256, 0, stream>>>(x_act, x_actT, xp1, xp2,
                                                          tdt_ch, B_ch, C_ch);
  k_scan  <<<1536, 256, 0, stream>>>(u_chA, u_chT, tdt_ch, B_ch, C_ch,
                                     Alog1, Alog2, D1, D2,
                                     dtw1, dtb1, dtw2, dtb2, y_px);
  k_merge <<<dim3(LL / 32, 2 * BN), 256, 0, stream>>>(y_px, sq,
                                                      fc1_w1, fc1_w2, fc2_w1, fc2_w2,
                                                      n1g, n1b, n2g, n2b, y_final);
  k_out   <<<dim3(LL / 16, BN), 256, 0, stream>>>(y_final, wout, (float*)d_out);
}

// Round 9
// 205.881 us; speedup vs baseline: 1.1925x; 1.1925x over previous
//
#include <hip/hip_runtime.h>
#include <math.h>

#define BN   2
#define CIN  96
#define HH   40
#define WW   40
#define LL   1600
#define DIN  192
#define NS   16
#define RR   6
#define KK   4
#define CH   25   // chunk length per lane (LL/64)

__device__ __forceinline__ float sigmoidf_(float x){ return 1.0f/(1.0f+expf(-x)); }
__device__ __forceinline__ float softplus_fast(float x){
  return x > 20.0f ? x : __logf(1.0f + __expf(x));
}

// ---------------- K1: in_proj (1x1) for both modalities ----------------
// grid: (L/16, 2*B), block 256. xproj layout [mb][o][p]
__global__ void k_inproj(const float* __restrict__ x_rgb, const float* __restrict__ x_e,
                         const float* __restrict__ w_rgb, const float* __restrict__ w_e,
                         float* __restrict__ xproj){
  __shared__ float xin[16][100];          // [px][c], padded row
  int l0 = blockIdx.x * 16;
  int mb = blockIdx.y;                    // m*BN + b
  int m = mb / BN, b = mb % BN;
  const float* xsrc = (m == 0 ? x_rgb : x_e) + (size_t)b * CIN * LL;
  const float* w    = (m == 0 ? w_rgb : w_e);
  for (int idx = threadIdx.x; idx < CIN * 16; idx += 256){
    int c = idx >> 4, px = idx & 15;
    xin[px][c] = xsrc[c * LL + l0 + px];
  }
  __syncthreads();
  int px = threadIdx.x & 15;
  int o0 = (threadIdx.x >> 4) * 12;       // 16 groups x 12 outputs
  float acc[12];
  #pragma unroll
  for (int i = 0; i < 12; ++i) acc[i] = 0.f;
  const float4* xv = reinterpret_cast<const float4*>(xin[px]);
  for (int cc = 0; cc < CIN / 4; ++cc){
    float4 x4 = xv[cc];
    #pragma unroll
    for (int i = 0; i < 12; ++i){
      float4 w4 = *reinterpret_cast<const float4*>(w + (o0 + i) * CIN + cc * 4);
      acc[i] += w4.x * x4.x + w4.y * x4.y + w4.z * x4.z + w4.w * x4.w;
    }
  }
  #pragma unroll
  for (int i = 0; i < 12; ++i)
    xproj[((size_t)mb * DIN + o0 + i) * LL + l0 + px] = acc[i];
}

// ------ K2: depthwise 3x3 + bias + SiLU; emit x_act, x_actT, u_ch, SE mean ---
// grid: (DIN, 2*B), block 256
__global__ void k_conv(const float* __restrict__ xproj, const float* __restrict__ conv_w,
                       const float* __restrict__ conv_b, float* __restrict__ x_act,
                       float* __restrict__ x_actT, float* __restrict__ u_chA,
                       float* __restrict__ u_chT, float* __restrict__ sq){
  __shared__ float pl[LL];
  __shared__ float sact[LL + HH];    // padded: index l + l/40
  __shared__ float red[4];
  int d  = blockIdx.x;
  int mb = blockIdx.y;
  const float* src = xproj + ((size_t)mb * DIN + d) * LL;
  for (int p = threadIdx.x; p < LL; p += blockDim.x) pl[p] = src[p];
  __syncthreads();
  float cw[9];
  #pragma unroll
  for (int j = 0; j < 9; ++j) cw[j] = conv_w[d * 9 + j];
  float bias = conv_b[d];
  float* dst = x_act + ((size_t)mb * DIN + d) * LL;
  float lsum = 0.f;
  for (int p = threadIdx.x; p < LL; p += blockDim.x){
    int py = p / WW, px = p % WW;
    float acc = bias;
    #pragma unroll
    for (int dy = -1; dy <= 1; ++dy){
      int yy = py + dy;
      if (yy < 0 || yy >= HH) continue;
      #pragma unroll
      for (int dx = -1; dx <= 1; ++dx){
        int xx = px + dx;
        if (xx < 0 || xx >= WW) continue;
        acc += cw[(dy + 1) * 3 + (dx + 1)] * pl[yy * WW + xx];
      }
    }
    float s = acc * sigmoidf_(acc);
    dst[p] = s;
    sact[p + p / WW] = s;
    lsum += s;
  }
  #pragma unroll
  for (int off = 32; off; off >>= 1) lsum += __shfl_down(lsum, off);
  if ((threadIdx.x & 63) == 0) red[threadIdx.x >> 6] = lsum;
  __syncthreads();
  if (threadIdx.x == 0)
    sq[mb * DIN + d] = (red[0] + red[1] + red[2] + red[3]) * (1.0f / LL);
  size_t po = ((size_t)mb * DIN + d) * LL;
  float* dstT = x_actT + po;
  float* uA   = u_chA + po;
  float* uT   = u_chT + po;
  for (int q = threadIdx.x; q < LL; q += blockDim.x){
    // transposed plane (row-major in q)
    int lt = (q % WW) * WW + q / WW;
    dstT[q] = sact[lt + lt / WW];
    // chunk-order planes: q = s*64+g  <->  l = g*25+s
    int l = (q & 63) * CH + (q >> 6);
    uA[q] = sact[l + l / WW];
    int pt = (l % WW) * WW + l / WW;
    uT[q] = sact[pt + pt / WW];
  }
}

// ------ K3: x_proj -> tdt_ch [mbk][r][q]; B/C in [mbk][n/4][q][4] layout ---
// grid: (L/64, K, 2*B), block 256
__global__ void k_xproj(const float* __restrict__ x_act, const float* __restrict__ x_actT,
                        const float* __restrict__ xp1, const float* __restrict__ xp2,
                        float* __restrict__ tdt_ch, float* __restrict__ B_ch,
                        float* __restrict__ C_ch){
  __shared__ float xs_t[DIN][64];
  int l0 = blockIdx.x * 64;
  int k  = blockIdx.y;
  int mb = blockIdx.z; int m = mb / BN;
  const float* xw = (m == 0 ? xp1 : xp2) + k * 38 * DIN;
  const float* xa = ((k & 1) ? x_actT : x_act) + (size_t)mb * DIN * LL;
  bool rev = (k >= 2);
  for (int idx = threadIdx.x; idx < DIN * 64; idx += blockDim.x){
    int dd = idx >> 6, ll = idx & 63;
    int l = l0 + ll; if (rev) l = LL - 1 - l;
    xs_t[dd][ll] = xa[dd * LL + l];
  }
  __syncthreads();
  int mbk = mb * KK + k;
  for (int oidx = threadIdx.x; oidx < 38 * 64; oidx += blockDim.x){
    int c = oidx >> 6, ll = oidx & 63;
    const float* wr = xw + c * DIN;
    float acc = 0.f;
    #pragma unroll 8
    for (int dd = 0; dd < DIN; ++dd) acc += wr[dd] * xs_t[dd][ll];
    int l = l0 + ll;
    int q = (l % CH) * 64 + l / CH;     // chunk-order index
    if (c < RR){
      tdt_ch[((size_t)mbk * RR + c) * LL + q] = acc;
    } else if (c < RR + NS){
      int n = c - RR;
      B_ch[(((size_t)mbk * 4 + (n >> 2)) * LL + q) * 4 + (n & 3)] = acc;
    } else {
      int n = c - RR - NS;
      C_ch[(((size_t)mbk * 4 + (n >> 2)) * LL + q) * 4 + (n & 3)] = acc;
    }
  }
}

// ---------------- K4: chunked parallel selective scan ----------
// 4 waves/block = 4 chains (same mbk). Each wave owns 2 d-chains x 8 states:
// B/C loads are shared across the 2 d's (halves duplicated L2 traffic).
// dt computed once per chain (one wave each) into LDS.
// grid: 768 blocks of 256. y_px layout [chain][pixel]
__global__ void __launch_bounds__(256, 3) k_scan(
    const float* __restrict__ u_chA, const float* __restrict__ u_chT,
    const float* __restrict__ tdt_all, const float* __restrict__ B_ch,
    const float* __restrict__ C_ch,
    const float* __restrict__ Alog1, const float* __restrict__ Alog2,
    const float* __restrict__ D1, const float* __restrict__ D2,
    const float* __restrict__ dtw1, const float* __restrict__ dtb1,
    const float* __restrict__ dtw2, const float* __restrict__ dtb2,
    float* __restrict__ y_px){
  __shared__ float ystage[4][LL + HH];      // [chain-in-blk][pad l]
  __shared__ float dt_lds[4][LL];           // [chain-in-blk][q]
  int wv   = threadIdx.x >> 6;
  int lane = threadIdx.x & 63;
  int p    = wv >> 1;                       // d-pair in block (0,1)
  int nh   = wv & 1;                        // n-half
  int cbase  = blockIdx.x * 4;              // first chain of block
  int chain0 = cbase + 2 * p;               // this wave's first chain
  int d0  = chain0 % DIN;                   // second is d0+1
  int mbk = chain0 / DIN;
  int k   = mbk % KK;
  int mb  = mbk / KK;
  int m = mb / BN, b = mb % BN;
  bool rev = (k >= 2);

  // zero the shared accumulator (covered by the barrier below)
  for (int i = threadIdx.x; i < 4 * (LL + HH); i += 256)
    (&ystage[0][0])[i] = 0.f;

  const float* AlogS = (m == 0 ? Alog1 : Alog2);
  const float* DvS   = (m == 0 ? D2 : D1);
  float An[2][8], Dv[2];
  #pragma unroll
  for (int dl = 0; dl < 2; ++dl){
    int kd = k * DIN + d0 + dl;
    #pragma unroll
    for (int n = 0; n < 8; ++n)
      An[dl][n] = -__expf(AlogS[kd * NS + nh * 8 + n]);
    Dv[dl] = DvS[kd];
  }

  const float* t0 = tdt_all + (size_t)mbk * RR * LL;    // [r][q] rows
  // dt for chain (2p + nh): each wave computes exactly one chain's dt
  {
    int cl = 2 * p + nh;
    int kd = k * DIN + d0 + nh;
    const float* dtw = (m == 0 ? dtw1 : dtw2) + kd * RR;
    float w0 = dtw[0], w1 = dtw[1], w2 = dtw[2], w3 = dtw[3], w4 = dtw[4], w5 = dtw[5];
    float dbias = (m == 0 ? dtb1 : dtb2)[kd];
    for (int s = 0; s < CH; ++s){
      int q = s * 64 + lane;
      float dtpre = w0 * t0[q] + w1 * t0[LL + q] + w2 * t0[2 * LL + q]
                  + w3 * t0[3 * LL + q] + w4 * t0[4 * LL + q] + w5 * t0[5 * LL + q] + dbias;
      dt_lds[cl][q] = softplus_fast(dtpre);
    }
  }
  __syncthreads();

  const float4* B0 = reinterpret_cast<const float4*>(B_ch) + ((size_t)mbk * 4 + 2 * nh) * LL;
  const float4* B1 = B0 + LL;
  int mbk_o = ((1 - m) * BN + b) * KK + k;              // other modality's C
  const float4* C0 = reinterpret_cast<const float4*>(C_ch) + ((size_t)mbk_o * 4 + 2 * nh) * LL;
  const float4* C1 = C0 + LL;
  const float* urow0 = ((k & 1) ? u_chT : u_chA) + ((size_t)mb * DIN + d0) * LL;
  const float* urow1 = urow0 + LL;

  float h[2][8];
  #pragma unroll
  for (int dl = 0; dl < 2; ++dl)
    #pragma unroll
    for (int n = 0; n < 8; ++n) h[dl][n] = 0.f;
  float Sdt0 = 0.f, Sdt1 = 0.f;

  // phase 1: local chunk scan -> h_local_end
  for (int s = 0; s < CH; ++s){
    int q = s * 64 + lane;
    float dta = dt_lds[2 * p][q];
    float dtb = dt_lds[2 * p + 1][q];
    Sdt0 += dta; Sdt1 += dtb;
    int qi = rev ? (LL - 1 - q) : q;
    float dua = dta * urow0[qi];
    float dub = dtb * urow1[qi];
    float4 b0 = B0[q], b1 = B1[q];
    float Bv[8] = {b0.x, b0.y, b0.z, b0.w, b1.x, b1.y, b1.z, b1.w};
    #pragma unroll
    for (int n = 0; n < 8; ++n){
      h[0][n] = __expf(dta * An[0][n]) * h[0][n] + dua * Bv[n];
      h[1][n] = __expf(dtb * An[1][n]) * h[1][n] + dub * Bv[n];
    }
  }
  float aP[2][8];
  #pragma unroll
  for (int n = 0; n < 8; ++n){
    aP[0][n] = __expf(Sdt0 * An[0][n]);
    aP[1][n] = __expf(Sdt1 * An[1][n]);
  }

  // Kogge-Stone inclusive scan of (aP,h) across 64 lanes (chunk order)
  #pragma unroll
  for (int off = 1; off < 64; off <<= 1){
    #pragma unroll
    for (int dl = 0; dl < 2; ++dl){
      #pragma unroll
      for (int n = 0; n < 8; ++n){
        float ap = __shfl_up(aP[dl][n], off);
        float bp = __shfl_up(h[dl][n],  off);
        if (lane >= off){
          h[dl][n]  = aP[dl][n] * bp + h[dl][n];
          aP[dl][n] = aP[dl][n] * ap;
        }
      }
    }
  }
  // carry-in for this chunk = inclusive result of previous lane
  #pragma unroll
  for (int dl = 0; dl < 2; ++dl)
    #pragma unroll
    for (int n = 0; n < 8; ++n){
      float v = __shfl_up(h[dl][n], 1);
      h[dl][n] = (lane == 0) ? 0.f : v;
    }
  // phase 2: rescan with carry, accumulate partial y into shared ystage
  for (int s = 0; s < CH; ++s){
    int q = s * 64 + lane;
    float dta = dt_lds[2 * p][q];
    float dtb = dt_lds[2 * p + 1][q];
    int qi = rev ? (LL - 1 - q) : q;
    float ua = urow0[qi], ub = urow1[qi];
    float dua = dta * ua, dub = dtb * ub;
    float4 b0 = B0[q], b1 = B1[q];
    float Bv[8] = {b0.x, b0.y, b0.z, b0.w, b1.x, b1.y, b1.z, b1.w};
    float4 c0 = C0[q], c1 = C1[q];
    float Cv[8] = {c0.x, c0.y, c0.z, c0.w, c1.x, c1.y, c1.z, c1.w};
    float y0 = (nh == 0) ? Dv[0] * ua : 0.f;
    float y1 = (nh == 0) ? Dv[1] * ub : 0.f;
    #pragma unroll
    for (int n = 0; n < 8; ++n){
      h[0][n] = __expf(dta * An[0][n]) * h[0][n] + dua * Bv[n];
      y0 += h[0][n] * Cv[n];
      h[1][n] = __expf(dtb * An[1][n]) * h[1][n] + dub * Bv[n];
      y1 += h[1][n] * Cv[n];
    }
    int l = lane * CH + s;
    atomicAdd(&ystage[2 * p][l + l / WW], y0);
    atomicAdd(&ystage[2 * p + 1][l + l / WW], y1);
  }
  __syncthreads();
  // flush in PIXEL order; fold reversal (k>=2) + transpose (k odd) here.
  // all 4 chains of this block share the same k.
  for (int idx = threadIdx.x; idx < 4 * LL; idx += 256){
    int cc = idx / LL, qq = idx - cc * LL;
    int l;
    if      (k == 0) l = qq;
    else if (k == 1) l = (qq % WW) * WW + qq / WW;
    else if (k == 2) l = LL - 1 - qq;
    else             { int qt = (qq % WW) * WW + qq / WW; l = LL - 1 - qt; }
    y_px[(size_t)(cbase + cc) * LL + qq] = ystage[cc][l + l / WW];
  }
}

// ------ K5: merge (4 coalesced adds) + LayerNorm + fused cross SE -------
// grid: (L/32, 2*B), block 256. y_final layout [mb][p][d]
__global__ void k_merge(const float* __restrict__ y_px, const float* __restrict__ sq,
                        const float* __restrict__ fc1_w1, const float* __restrict__ fc1_w2,
                        const float* __restrict__ fc2_w1, const float* __restrict__ fc2_w2,
                        const float* __restrict__ n1g, const float* __restrict__ n1b,
                        const float* __restrict__ n2g, const float* __restrict__ n2b,
                        float* __restrict__ y_final){
  __shared__ float acc[DIN][33];
  __shared__ float ps[8][32], ps2[8][32];
  __shared__ float mu_s[32], inv_s[32];
  __shared__ float sqs[DIN], hid[12], exc_s[DIN];
  int p0 = blockIdx.x * 32;
  int mb = blockIdx.y; int m = mb / BN, b = mb % BN;
  const float* yb = y_px + (size_t)mb * KK * DIN * LL;
  for (int idx = threadIdx.x; idx < DIN * 32; idx += 256){
    int dd = idx >> 5, pp = idx & 31;
    size_t o = (size_t)dd * LL + p0 + pp;
    acc[dd][pp] = yb[o] + yb[(size_t)DIN * LL + o]
                + yb[2 * (size_t)DIN * LL + o] + yb[3 * (size_t)DIN * LL + o];
  }
  // cross SE: y_m is scaled by exc of modality (1-m)
  int mbo = (1 - m) * BN + b;
  const float* w1 = (m == 1 ? fc1_w1 : fc2_w1);
  const float* w2 = (m == 1 ? fc1_w2 : fc2_w2);
  if (threadIdx.x < DIN) sqs[threadIdx.x] = sq[mbo * DIN + threadIdx.x];
  __syncthreads();
  if (threadIdx.x < 12){
    float a = 0.f;
    for (int cch = 0; cch < DIN; ++cch) a += w1[threadIdx.x * DIN + cch] * sqs[cch];
    hid[threadIdx.x] = a * sigmoidf_(a);
  }
  {
    int pp = threadIdx.x & 31, qr = threadIdx.x >> 5;
    float s = 0.f, s2 = 0.f;
    #pragma unroll 4
    for (int j = 0; j < 24; ++j){ float v = acc[qr * 24 + j][pp]; s += v; s2 += v * v; }
    ps[qr][pp] = s; ps2[qr][pp] = s2;
  }
  __syncthreads();
  if (threadIdx.x < 32){
    int pp = threadIdx.x;
    float s = 0.f, s2 = 0.f;
    #pragma unroll
    for (int qr = 0; qr < 8; ++qr){ s += ps[qr][pp]; s2 += ps2[qr][pp]; }
    float mu  = s * (1.0f / DIN);
    float var = s2 * (1.0f / DIN) - mu * mu;
    mu_s[pp] = mu; inv_s[pp] = rsqrtf(var + 1e-5f);
  }
  if (threadIdx.x >= 64 && threadIdx.x < 64 + DIN){
    int dd = threadIdx.x - 64;
    float e = 0.f;
    #pragma unroll
    for (int j = 0; j < 12; ++j) e += w2[dd * 12 + j] * hid[j];
    exc_s[dd] = sigmoidf_(e);
  }
  __syncthreads();
  const float* g  = (m == 0 ? n1g : n2g);
  const float* bb = (m == 0 ? n1b : n2b);
  for (int idx = threadIdx.x; idx < DIN * 32; idx += 256){
    int pp = idx / DIN, dd = idx - pp * DIN;
    float v = (acc[dd][pp] - mu_s[pp]) * inv_s[pp] * g[dd] + bb[dd];
    v *= exc_s[dd];
    y_final[((size_t)mb * LL + p0 + pp) * DIN + dd] = v;
  }
}

// ---------------- K6: out_proj (96 x 384) ----------------
// grid: (L/16, B), block 256. float4 chunks, reg-blocked 6 outputs
__global__ void k_out(const float* __restrict__ y_final, const float* __restrict__ wout,
                      float* __restrict__ out){
  __shared__ float yt[16][388];
  int p0 = blockIdx.x * 16;
  int b  = blockIdx.y;
  for (int idx = threadIdx.x; idx < 16 * 384; idx += 256){
    int pp = idx / 384, cch = idx % 384;
    int m = cch / DIN, dd = cch % DIN;
    yt[pp][cch] = y_final[(((size_t)(m * BN + b)) * LL + p0 + pp) * DIN + dd];
  }
  __syncthreads();
  int pp = threadIdx.x & 15;
  int o0 = (threadIdx.x >> 4) * 6;       // 16 groups x 6 outputs
  float acc[6];
  #pragma unroll
  for (int i = 0; i < 6; ++i) acc[i] = 0.f;
  const float4* yv = reinterpret_cast<const float4*>(yt[pp]);
  for (int cc = 0; cc < 96; ++cc){
    float4 x4 = yv[cc];
    #pragma unroll
    for (int i = 0; i < 6; ++i){
      float4 w4 = *reinterpret_cast<const float4*>(wout + (o0 + i) * 2 * DIN + cc * 4);
      acc[i] += w4.x * x4.x + w4.y * x4.y + w4.z * x4.z + w4.w * x4.w;
    }
  }
  #pragma unroll
  for (int i = 0; i < 6; ++i)
    out[((size_t)b * CIN + o0 + i) * LL + p0 + pp] = acc[i];
}

extern "C" void kernel_launch(void* const* d_in, const int* in_sizes, int n_in,
                              void* d_out, int out_size, void* d_ws, size_t ws_size,
                              hipStream_t stream){
  const float* x_rgb   = (const float*)d_in[0];
  const float* x_e     = (const float*)d_in[1];
  const float* in_w    = (const float*)d_in[2];
  const float* in_mx_w = (const float*)d_in[3];
  const float* conv_w  = (const float*)d_in[4];
  const float* conv_b  = (const float*)d_in[5];
  const float* xp1     = (const float*)d_in[6];
  const float* xp2     = (const float*)d_in[7];
  const float* dtw1    = (const float*)d_in[8];
  const float* dtb1    = (const float*)d_in[9];
  const float* dtw2    = (const float*)d_in[10];
  const float* dtb2    = (const float*)d_in[11];
  const float* Alog1   = (const float*)d_in[12];
  const float* Alog2   = (const float*)d_in[13];
  const float* D1      = (const float*)d_in[14];
  const float* D2      = (const float*)d_in[15];
  const float* n1g     = (const float*)d_in[16];
  const float* n1b     = (const float*)d_in[17];
  const float* n2g     = (const float*)d_in[18];
  const float* n2b     = (const float*)d_in[19];
  const float* fc1_w1  = (const float*)d_in[20];
  const float* fc1_w2  = (const float*)d_in[21];
  const float* fc2_w1  = (const float*)d_in[22];
  const float* fc2_w2  = (const float*)d_in[23];
  const float* wout    = (const float*)d_in[24];

  float* ws = (float*)d_ws;
  // region plan (floats), total 12,032,768 (= 48.1 MB):
  //   [0,        1228800) u_chA   (k_conv -> k_scan)
  //   [1228800,  2457600) u_chT   (k_conv -> k_scan)
  //   [2457600,  3686400) x_act   (k_conv -> k_xproj); y_final aliases after
  //   [3686400,  4915200) x_actT  (k_conv -> k_xproj)
  //   [4915200,  6144000) xproj   (k_inproj -> k_conv)
  //   [6144000, 11059200) y_px    (k_scan -> k_merge)
  //   [11059200,11468800) B_ch    [mbk][n/4][q][4]
  //   [11468800,11878400) C_ch    [mbk][n/4][q][4]
  //   [11878400,12032000) tdt_ch  [mbk][r][q]
  //   [12032000,12032768) sq
  float* u_chA   = ws;
  float* u_chT   = ws + 1228800;
  float* x_act   = ws + 2457600;
  float* x_actT  = ws + 3686400;
  float* xproj   = ws + 4915200;
  float* y_final = ws + 2457600;      // alias: x_act dead after k_xproj
  float* y_px    = ws + 6144000;
  float* B_ch    = ws + 11059200;
  float* C_ch    = ws + 11468800;
  float* tdt_ch  = ws + 11878400;
  float* sq      = ws + 12032000;

  k_inproj<<<dim3(LL / 16, 2 * BN), 256, 0, stream>>>(x_rgb, x_e, in_w, in_mx_w, xproj);
  k_conv  <<<dim3(DIN, 2 * BN), 256, 0, stream>>>(xproj, conv_w, conv_b,
                                                  x_act, x_actT, u_chA, u_chT, sq);
  k_xproj <<<dim3(LL / 64, KK, 2 * BN), 256, 0, stream>>>(x_act, x_actT, xp1, xp2,
                                                          tdt_ch, B_ch, C_ch);
  k_scan  <<<768, 256, 0, stream>>>(u_chA, u_chT, tdt_ch, B_ch, C_ch,
                                    Alog1, Alog2, D1, D2,
                                    dtw1, dtb1, dtw2, dtb2, y_px);
  k_merge <<<dim3(LL / 32, 2 * BN), 256, 0, stream>>>(y_px, sq,
                                                      fc1_w1, fc1_w2, fc2_w1, fc2_w2,
                                                      n1g, n1b, n2g, n2b, y_final);
  k_out   <<<dim3(LL / 16, BN), 256, 0, stream>>>(y_final, wout, (float*)d_out);
}

// Round 10
// 193.668 us; speedup vs baseline: 1.2676x; 1.0631x over previous
//
#include <hip/hip_runtime.h>
#include <math.h>

#define BN   2
#define CIN  96
#define HH   40
#define WW   40
#define LL   1600
#define DIN  192
#define NS   16
#define RR   6
#define KK   4
#define CH   25   // chunk length per lane (LL/64)

__device__ __forceinline__ float sigmoidf_(float x){ return 1.0f/(1.0f+expf(-x)); }
__device__ __forceinline__ float softplus_fast(float x){
  return x > 20.0f ? x : __logf(1.0f + __expf(x));
}

// ---------------- K1: in_proj (1x1) for both modalities ----------------
// grid: (L/16, 2*B), block 256. xproj layout [mb][o][p]
__global__ void k_inproj(const float* __restrict__ x_rgb, const float* __restrict__ x_e,
                         const float* __restrict__ w_rgb, const float* __restrict__ w_e,
                         float* __restrict__ xproj){
  __shared__ float xin[16][100];          // [px][c], padded row
  int l0 = blockIdx.x * 16;
  int mb = blockIdx.y;                    // m*BN + b
  int m = mb / BN, b = mb % BN;
  const float* xsrc = (m == 0 ? x_rgb : x_e) + (size_t)b * CIN * LL;
  const float* w    = (m == 0 ? w_rgb : w_e);
  for (int idx = threadIdx.x; idx < CIN * 16; idx += 256){
    int c = idx >> 4, px = idx & 15;
    xin[px][c] = xsrc[c * LL + l0 + px];
  }
  __syncthreads();
  int px = threadIdx.x & 15;
  int o0 = (threadIdx.x >> 4) * 12;       // 16 groups x 12 outputs
  float acc[12];
  #pragma unroll
  for (int i = 0; i < 12; ++i) acc[i] = 0.f;
  const float4* xv = reinterpret_cast<const float4*>(xin[px]);
  for (int cc = 0; cc < CIN / 4; ++cc){
    float4 x4 = xv[cc];
    #pragma unroll
    for (int i = 0; i < 12; ++i){
      float4 w4 = *reinterpret_cast<const float4*>(w + (o0 + i) * CIN + cc * 4);
      acc[i] += w4.x * x4.x + w4.y * x4.y + w4.z * x4.z + w4.w * x4.w;
    }
  }
  #pragma unroll
  for (int i = 0; i < 12; ++i)
    xproj[((size_t)mb * DIN + o0 + i) * LL + l0 + px] = acc[i];
}

// ------ K2: depthwise 3x3 + bias + SiLU; emit x_act, x_actT, u_ch, SE mean ---
// grid: (DIN, 2*B), block 256
__global__ void k_conv(const float* __restrict__ xproj, const float* __restrict__ conv_w,
                       const float* __restrict__ conv_b, float* __restrict__ x_act,
                       float* __restrict__ x_actT, float* __restrict__ u_chA,
                       float* __restrict__ u_chT, float* __restrict__ sq){
  __shared__ float pl[LL];
  __shared__ float sact[LL + HH];    // padded: index l + l/40
  __shared__ float red[4];
  int d  = blockIdx.x;
  int mb = blockIdx.y;
  const float* src = xproj + ((size_t)mb * DIN + d) * LL;
  for (int p = threadIdx.x; p < LL; p += blockDim.x) pl[p] = src[p];
  __syncthreads();
  float cw[9];
  #pragma unroll
  for (int j = 0; j < 9; ++j) cw[j] = conv_w[d * 9 + j];
  float bias = conv_b[d];
  float* dst = x_act + ((size_t)mb * DIN + d) * LL;
  float lsum = 0.f;
  for (int p = threadIdx.x; p < LL; p += blockDim.x){
    int py = p / WW, px = p % WW;
    float acc = bias;
    #pragma unroll
    for (int dy = -1; dy <= 1; ++dy){
      int yy = py + dy;
      if (yy < 0 || yy >= HH) continue;
      #pragma unroll
      for (int dx = -1; dx <= 1; ++dx){
        int xx = px + dx;
        if (xx < 0 || xx >= WW) continue;
        acc += cw[(dy + 1) * 3 + (dx + 1)] * pl[yy * WW + xx];
      }
    }
    float s = acc * sigmoidf_(acc);
    dst[p] = s;
    sact[p + p / WW] = s;
    lsum += s;
  }
  #pragma unroll
  for (int off = 32; off; off >>= 1) lsum += __shfl_down(lsum, off);
  if ((threadIdx.x & 63) == 0) red[threadIdx.x >> 6] = lsum;
  __syncthreads();
  if (threadIdx.x == 0)
    sq[mb * DIN + d] = (red[0] + red[1] + red[2] + red[3]) * (1.0f / LL);
  size_t po = ((size_t)mb * DIN + d) * LL;
  float* dstT = x_actT + po;
  float* uA   = u_chA + po;
  float* uT   = u_chT + po;
  for (int q = threadIdx.x; q < LL; q += blockDim.x){
    int lt = (q % WW) * WW + q / WW;
    dstT[q] = sact[lt + lt / WW];
    int l = (q & 63) * CH + (q >> 6);
    uA[q] = sact[l + l / WW];
    int pt = (l % WW) * WW + l / WW;
    uT[q] = sact[pt + pt / WW];
  }
}

// ------ K3: x_proj -> tdt_ch [mbk][r][q]; B/C in [mbk][n/4][q][4] layout ---
// grid: (L/64, K, 2*B), block 256
__global__ void k_xproj(const float* __restrict__ x_act, const float* __restrict__ x_actT,
                        const float* __restrict__ xp1, const float* __restrict__ xp2,
                        float* __restrict__ tdt_ch, float* __restrict__ B_ch,
                        float* __restrict__ C_ch){
  __shared__ float xs_t[DIN][64];
  int l0 = blockIdx.x * 64;
  int k  = blockIdx.y;
  int mb = blockIdx.z; int m = mb / BN;
  const float* xw = (m == 0 ? xp1 : xp2) + k * 38 * DIN;
  const float* xa = ((k & 1) ? x_actT : x_act) + (size_t)mb * DIN * LL;
  bool rev = (k >= 2);
  for (int idx = threadIdx.x; idx < DIN * 64; idx += blockDim.x){
    int dd = idx >> 6, ll = idx & 63;
    int l = l0 + ll; if (rev) l = LL - 1 - l;
    xs_t[dd][ll] = xa[dd * LL + l];
  }
  __syncthreads();
  int mbk = mb * KK + k;
  for (int oidx = threadIdx.x; oidx < 38 * 64; oidx += blockDim.x){
    int c = oidx >> 6, ll = oidx & 63;
    const float* wr = xw + c * DIN;
    float acc = 0.f;
    #pragma unroll 8
    for (int dd = 0; dd < DIN; ++dd) acc += wr[dd] * xs_t[dd][ll];
    int l = l0 + ll;
    int q = (l % CH) * 64 + l / CH;     // chunk-order index
    if (c < RR){
      tdt_ch[((size_t)mbk * RR + c) * LL + q] = acc;
    } else if (c < RR + NS){
      int n = c - RR;
      B_ch[(((size_t)mbk * 4 + (n >> 2)) * LL + q) * 4 + (n & 3)] = acc;
    } else {
      int n = c - RR - NS;
      C_ch[(((size_t)mbk * 4 + (n >> 2)) * LL + q) * 4 + (n & 3)] = acc;
    }
  }
}

// ---------------- K4: chunked parallel selective scan, n-split ----------
// 2 waves per chain (8 states each). dt once per chain into LDS.
// FAST-EXP: when An[n] == -(idx+1) (the A_log = log(1..16) structure,
// verified at runtime, generic fallback otherwise), dA_n = r^(idx+1)
// with r = exp(-dt): 1 transcendental + mul-chain instead of 8 exps.
// grid: 1536 blocks of 256 (2 chains/block). y_px layout [chain][pixel]
__global__ void __launch_bounds__(256, 6) k_scan(
    const float* __restrict__ u_chA, const float* __restrict__ u_chT,
    const float* __restrict__ tdt_all, const float* __restrict__ B_ch,
    const float* __restrict__ C_ch,
    const float* __restrict__ Alog1, const float* __restrict__ Alog2,
    const float* __restrict__ D1, const float* __restrict__ D2,
    const float* __restrict__ dtw1, const float* __restrict__ dtb1,
    const float* __restrict__ dtw2, const float* __restrict__ dtb2,
    float* __restrict__ y_px){
  __shared__ float ystage[2][LL + HH];      // [chain-in-blk][pad l]
  __shared__ float dt_lds[2][LL];           // [chain-in-blk][q]
  int wv   = threadIdx.x >> 6;
  int lane = threadIdx.x & 63;
  int c    = wv >> 1;                       // chain in block
  int nh   = wv & 1;                        // n-half
  int chain = blockIdx.x * 2 + c;           // = (mb*KK + k)*DIN + d
  int d   = chain % DIN;
  int mbk = chain / DIN;
  int k   = mbk % KK;
  int mb  = mbk / KK;
  int m = mb / BN, b = mb % BN;
  int kd = k * DIN + d;
  bool rev = (k >= 2);

  // zero the shared accumulator (covered by the barrier below)
  for (int i = threadIdx.x; i < 2 * (LL + HH); i += 256)
    (&ystage[0][0])[i] = 0.f;

  const float* Alog = (m == 0 ? Alog1 : Alog2) + kd * NS + nh * 8;
  float An[8];
  #pragma unroll
  for (int n = 0; n < 8; ++n) An[n] = -__expf(Alog[n]);
  // wave-uniform fast-path check: An[n] == -(nh*8+n+1) ?
  bool fastA = true;
  #pragma unroll
  for (int n = 0; n < 8; ++n){
    float expect = -(float)(nh * 8 + n + 1);
    fastA = fastA && (fabsf(An[n] - expect) <= 1e-4f * (float)(nh * 8 + n + 1));
  }
  float Dv = (m == 0 ? D2 : D1)[kd];
  const float* dtw = (m == 0 ? dtw1 : dtw2) + kd * RR;
  float w0 = dtw[0], w1 = dtw[1], w2 = dtw[2], w3 = dtw[3], w4 = dtw[4], w5 = dtw[5];
  float dbias = (m == 0 ? dtb1 : dtb2)[kd];

  const float* t0 = tdt_all + (size_t)mbk * RR * LL;    // [r][q] rows
  const float4* B0 = reinterpret_cast<const float4*>(B_ch) + ((size_t)mbk * 4 + 2 * nh) * LL;
  const float4* B1 = B0 + LL;
  int mbk_o = ((1 - m) * BN + b) * KK + k;              // other modality's C
  const float4* C0 = reinterpret_cast<const float4*>(C_ch) + ((size_t)mbk_o * 4 + 2 * nh) * LL;
  const float4* C1 = C0 + LL;
  const float* urow = ((k & 1) ? u_chT : u_chA) + ((size_t)mb * DIN + d) * LL;

  // dt for the whole chain, computed once, split across the 2 n-half waves
  {
    int s_begin = nh ? 13 : 0;
    int s_end   = nh ? CH : 13;
    for (int s = s_begin; s < s_end; ++s){
      int q = s * 64 + lane;
      float dtpre = w0 * t0[q] + w1 * t0[LL + q] + w2 * t0[2 * LL + q]
                  + w3 * t0[3 * LL + q] + w4 * t0[4 * LL + q] + w5 * t0[5 * LL + q] + dbias;
      dt_lds[c][q] = softplus_fast(dtpre);
    }
  }
  __syncthreads();

  float h[8];
  #pragma unroll
  for (int n = 0; n < 8; ++n) h[n] = 0.f;
  float Sdt = 0.f;

  // phase 1: local chunk scan -> h_local_end
  if (fastA){
    #pragma unroll 5
    for (int s = 0; s < CH; ++s){
      int q = s * 64 + lane;
      float dt = dt_lds[c][q];
      Sdt += dt;
      float u  = urow[rev ? (LL - 1 - q) : q];
      float du = dt * u;
      float4 b0 = B0[q], b1 = B1[q];
      float Bv[8] = {b0.x, b0.y, b0.z, b0.w, b1.x, b1.y, b1.z, b1.w};
      float r = __expf(-dt);
      float p;
      if (nh){ float r2 = r * r; float r4 = r2 * r2; p = r4 * r4; } else p = 1.f;
      #pragma unroll
      for (int n = 0; n < 8; ++n){
        p *= r;                       // p = r^(nh*8+n+1) = exp(dt*An[n])
        h[n] = p * h[n] + du * Bv[n];
      }
    }
  } else {
    #pragma unroll 5
    for (int s = 0; s < CH; ++s){
      int q = s * 64 + lane;
      float dt = dt_lds[c][q];
      Sdt += dt;
      float u  = urow[rev ? (LL - 1 - q) : q];
      float du = dt * u;
      float4 b0 = B0[q], b1 = B1[q];
      float Bv[8] = {b0.x, b0.y, b0.z, b0.w, b1.x, b1.y, b1.z, b1.w};
      #pragma unroll
      for (int n = 0; n < 8; ++n){
        float dA = __expf(dt * An[n]);
        h[n] = dA * h[n] + du * Bv[n];
      }
    }
  }
  float aP[8];
  if (fastA){
    float R = __expf(-Sdt);
    float P;
    if (nh){ float R2 = R * R; float R4 = R2 * R2; P = R4 * R4; } else P = 1.f;
    #pragma unroll
    for (int n = 0; n < 8; ++n){ P *= R; aP[n] = P; }
  } else {
    #pragma unroll
    for (int n = 0; n < 8; ++n) aP[n] = __expf(Sdt * An[n]);
  }

  // Kogge-Stone inclusive scan of (aP,h) across 64 lanes (chunk order)
  #pragma unroll
  for (int off = 1; off < 64; off <<= 1){
    #pragma unroll
    for (int n = 0; n < 8; ++n){
      float ap = __shfl_up(aP[n], off);
      float bp = __shfl_up(h[n],  off);
      if (lane >= off){
        h[n]  = aP[n] * bp + h[n];
        aP[n] = aP[n] * ap;
      }
    }
  }
  // carry-in for this chunk = inclusive result of previous lane
  #pragma unroll
  for (int n = 0; n < 8; ++n){
    float v = __shfl_up(h[n], 1);
    h[n] = (lane == 0) ? 0.f : v;
  }
  // phase 2: rescan with carry, accumulate partial y into shared ystage
  if (fastA){
    #pragma unroll 5
    for (int s = 0; s < CH; ++s){
      int q = s * 64 + lane;
      float dt = dt_lds[c][q];
      float u  = urow[rev ? (LL - 1 - q) : q];
      float du = dt * u;
      float4 b0 = B0[q], b1 = B1[q];
      float Bv[8] = {b0.x, b0.y, b0.z, b0.w, b1.x, b1.y, b1.z, b1.w};
      float4 c0 = C0[q], c1 = C1[q];
      float Cv[8] = {c0.x, c0.y, c0.z, c0.w, c1.x, c1.y, c1.z, c1.w};
      float r = __expf(-dt);
      float p;
      if (nh){ float r2 = r * r; float r4 = r2 * r2; p = r4 * r4; } else p = 1.f;
      float y = (nh == 0) ? Dv * u : 0.f;
      #pragma unroll
      for (int n = 0; n < 8; ++n){
        p *= r;
        h[n] = p * h[n] + du * Bv[n];
        y += h[n] * Cv[n];
      }
      int l = lane * CH + s;
      atomicAdd(&ystage[c][l + l / WW], y);
    }
  } else {
    #pragma unroll 5
    for (int s = 0; s < CH; ++s){
      int q = s * 64 + lane;
      float dt = dt_lds[c][q];
      float u  = urow[rev ? (LL - 1 - q) : q];
      float du = dt * u;
      float4 b0 = B0[q], b1 = B1[q];
      float Bv[8] = {b0.x, b0.y, b0.z, b0.w, b1.x, b1.y, b1.z, b1.w};
      float4 c0 = C0[q], c1 = C1[q];
      float Cv[8] = {c0.x, c0.y, c0.z, c0.w, c1.x, c1.y, c1.z, c1.w};
      float y = (nh == 0) ? Dv * u : 0.f;
      #pragma unroll
      for (int n = 0; n < 8; ++n){
        float dA = __expf(dt * An[n]);
        h[n] = dA * h[n] + du * Bv[n];
        y += h[n] * Cv[n];
      }
      int l = lane * CH + s;
      atomicAdd(&ystage[c][l + l / WW], y);
    }
  }
  __syncthreads();
  // flush in PIXEL order; fold reversal (k>=2) + transpose (k odd) here.
  for (int idx = threadIdx.x; idx < 2 * LL; idx += 256){
    int cc = idx / LL, qq = idx - cc * LL;
    int l;
    if      (k == 0) l = qq;
    else if (k == 1) l = (qq % WW) * WW + qq / WW;
    else if (k == 2) l = LL - 1 - qq;
    else             { int qt = (qq % WW) * WW + qq / WW; l = LL - 1 - qt; }
    y_px[(size_t)(blockIdx.x * 2 + cc) * LL + qq] = ystage[cc][l + l / WW];
  }
}

// ------ K5: FUSED merge + LayerNorm + cross SE + out_proj ---------------
// grid: (L/16, B), block 256. Handles BOTH modalities per block, then the
// 96x384 out-GEMM straight from LDS (y_final round-trip eliminated).
__global__ void __launch_bounds__(256) k_mergeout(
    const float* __restrict__ y_px, const float* __restrict__ sq,
    const float* __restrict__ fc1_w1, const float* __restrict__ fc1_w2,
    const float* __restrict__ fc2_w1, const float* __restrict__ fc2_w2,
    const float* __restrict__ n1g, const float* __restrict__ n1b,
    const float* __restrict__ n2g, const float* __restrict__ n2b,
    const float* __restrict__ wout, float* __restrict__ out){
  __shared__ float acc[2 * DIN][17];      // [(m*DIN+dd)][pp]
  __shared__ float yt[16][388];           // [pp][m*DIN+dd], GEMM operand
  __shared__ float ps[2][16][8], ps2[2][16][8];
  __shared__ float mu_s[2][16], inv_s[2][16];
  __shared__ float sqs[2][DIN];           // sq of the OTHER modality, per m
  __shared__ float hid[2][12];
  __shared__ float exc_s[2][DIN];
  int p0 = blockIdx.x * 16;
  int b  = blockIdx.y;
  int tid = threadIdx.x;
  // region A: 4-direction merged sums + sq loads
  for (int idx = tid; idx < 2 * DIN * 16; idx += 256){
    int pp = idx & 15, row = idx >> 4;
    int mm = (row >= DIN), dd = row - mm * DIN;
    const float* yb = y_px + (((size_t)(mm * BN + b) * KK) * DIN + dd) * LL + p0 + pp;
    acc[row][pp] = yb[0] + yb[(size_t)DIN * LL]
                 + yb[2 * (size_t)DIN * LL] + yb[3 * (size_t)DIN * LL];
  }
  for (int i = tid; i < 2 * DIN; i += 256){
    int mm = (i >= DIN), dd = i - mm * DIN;
    sqs[mm][dd] = sq[((1 - mm) * BN + b) * DIN + dd];
  }
  __syncthreads();
  // region B: SE hidden layer (24 thr) + LN stats partials (all 256)
  if (tid < 24){
    int mm = tid / 12, j = tid - mm * 12;
    const float* w1 = (mm == 1 ? fc1_w1 : fc2_w1);
    float a = 0.f;
    for (int cch = 0; cch < DIN; ++cch) a += w1[j * DIN + cch] * sqs[mm][cch];
    hid[mm][j] = a * sigmoidf_(a);
  }
  {
    int g = tid >> 5, mm = (tid >> 4) & 1, pp = tid & 15;
    float s = 0.f, s2 = 0.f;
    #pragma unroll 4
    for (int j = 0; j < 24; ++j){
      float v = acc[mm * DIN + g * 24 + j][pp];
      s += v; s2 += v * v;
    }
    ps[mm][pp][g] = s; ps2[mm][pp][g] = s2;
  }
  __syncthreads();
  // region C: LN stats final (32 thr) + SE excitation (all, strided)
  if (tid < 32){
    int mm = tid >> 4, pp = tid & 15;
    float s = 0.f, s2 = 0.f;
    #pragma unroll
    for (int g = 0; g < 8; ++g){ s += ps[mm][pp][g]; s2 += ps2[mm][pp][g]; }
    float mu  = s * (1.0f / DIN);
    float var = s2 * (1.0f / DIN) - mu * mu;
    mu_s[mm][pp] = mu; inv_s[mm][pp] = rsqrtf(var + 1e-5f);
  }
  for (int i = tid; i < 2 * DIN; i += 256){
    int mm = (i >= DIN), dd = i - mm * DIN;
    const float* w2 = (mm == 1 ? fc1_w2 : fc2_w2);
    float e = 0.f;
    #pragma unroll
    for (int j = 0; j < 12; ++j) e += w2[dd * 12 + j] * hid[mm][j];
    exc_s[mm][dd] = sigmoidf_(e);
  }
  __syncthreads();
  // region D: normalize + SE scale into yt
  for (int idx = tid; idx < 2 * DIN * 16; idx += 256){
    int pp = idx & 15, row = idx >> 4;
    int mm = (row >= DIN), dd = row - mm * DIN;
    float g  = (mm ? n2g : n1g)[dd];
    float bb = (mm ? n2b : n1b)[dd];
    float v = (acc[row][pp] - mu_s[mm][pp]) * inv_s[mm][pp] * g + bb;
    yt[pp][row] = v * exc_s[mm][dd];
  }
  __syncthreads();
  // region E: out_proj 96x384 from LDS
  int pp = tid & 15;
  int o0 = (tid >> 4) * 6;                // 16 groups x 6 outputs
  float a6[6];
  #pragma unroll
  for (int i = 0; i < 6; ++i) a6[i] = 0.f;
  const float4* yv = reinterpret_cast<const float4*>(yt[pp]);
  for (int cc = 0; cc < 96; ++cc){
    float4 x4 = yv[cc];
    #pragma unroll
    for (int i = 0; i < 6; ++i){
      float4 w4 = *reinterpret_cast<const float4*>(wout + (o0 + i) * 2 * DIN + cc * 4);
      a6[i] += w4.x * x4.x + w4.y * x4.y + w4.z * x4.z + w4.w * x4.w;
    }
  }
  #pragma unroll
  for (int i = 0; i < 6; ++i)
    out[((size_t)b * CIN + o0 + i) * LL + p0 + pp] = a6[i];
}

extern "C" void kernel_launch(void* const* d_in, const int* in_sizes, int n_in,
                              void* d_out, int out_size, void* d_ws, size_t ws_size,
                              hipStream_t stream){
  const float* x_rgb   = (const float*)d_in[0];
  const float* x_e     = (const float*)d_in[1];
  const float* in_w    = (const float*)d_in[2];
  const float* in_mx_w = (const float*)d_in[3];
  const float* conv_w  = (const float*)d_in[4];
  const float* conv_b  = (const float*)d_in[5];
  const float* xp1     = (const float*)d_in[6];
  const float* xp2     = (const float*)d_in[7];
  const float* dtw1    = (const float*)d_in[8];
  const float* dtb1    = (const float*)d_in[9];
  const float* dtw2    = (const float*)d_in[10];
  const float* dtb2    = (const float*)d_in[11];
  const float* Alog1   = (const float*)d_in[12];
  const float* Alog2   = (const float*)d_in[13];
  const float* D1      = (const float*)d_in[14];
  const float* D2      = (const float*)d_in[15];
  const float* n1g     = (const float*)d_in[16];
  const float* n1b     = (const float*)d_in[17];
  const float* n2g     = (const float*)d_in[18];
  const float* n2b     = (const float*)d_in[19];
  const float* fc1_w1  = (const float*)d_in[20];
  const float* fc1_w2  = (const float*)d_in[21];
  const float* fc2_w1  = (const float*)d_in[22];
  const float* fc2_w2  = (const float*)d_in[23];
  const float* wout    = (const float*)d_in[24];

  float* ws = (float*)d_ws;
  // region plan (floats), total 12,032,768 (= 48.1 MB):
  //   [0,        1228800) u_chA   (k_conv -> k_scan)
  //   [1228800,  2457600) u_chT   (k_conv -> k_scan)
  //   [2457600,  3686400) x_act   (k_conv -> k_xproj)
  //   [3686400,  4915200) x_actT  (k_conv -> k_xproj)
  //   [4915200,  6144000) xproj   (k_inproj -> k_conv)
  //   [6144000, 11059200) y_px    (k_scan -> k_mergeout)
  //   [11059200,11468800) B_ch    [mbk][n/4][q][4]
  //   [11468800,11878400) C_ch    [mbk][n/4][q][4]
  //   [11878400,12032000) tdt_ch  [mbk][r][q]
  //   [12032000,12032768) sq
  float* u_chA   = ws;
  float* u_chT   = ws + 1228800;
  float* x_act   = ws + 2457600;
  float* x_actT  = ws + 3686400;
  float* xproj   = ws + 4915200;
  float* y_px    = ws + 6144000;
  float* B_ch    = ws + 11059200;
  float* C_ch    = ws + 11468800;
  float* tdt_ch  = ws + 11878400;
  float* sq      = ws + 12032000;

  k_inproj  <<<dim3(LL / 16, 2 * BN), 256, 0, stream>>>(x_rgb, x_e, in_w, in_mx_w, xproj);
  k_conv    <<<dim3(DIN, 2 * BN), 256, 0, stream>>>(xproj, conv_w, conv_b,
                                                    x_act, x_actT, u_chA, u_chT, sq);
  k_xproj   <<<dim3(LL / 64, KK, 2 * BN), 256, 0, stream>>>(x_act, x_actT, xp1, xp2,
                                                            tdt_ch, B_ch, C_ch);
  k_scan    <<<1536, 256, 0, stream>>>(u_chA, u_chT, tdt_ch, B_ch, C_ch,
                                       Alog1, Alog2, D1, D2,
                                       dtw1, dtb1, dtw2, dtb2, y_px);
  k_mergeout<<<dim3(LL / 16, BN), 256, 0, stream>>>(y_px, sq,
                                                    fc1_w1, fc1_w2, fc2_w1, fc2_w2,
                                                    n1g, n1b, n2g, n2b,
                                                    wout, (float*)d_out);
}

// Round 11
// 189.475 us; speedup vs baseline: 1.2957x; 1.0221x over previous
//
#include <hip/hip_runtime.h>
#include <math.h>

#define BN   2
#define CIN  96
#define HH   40
#define WW   40
#define LL   1600
#define DIN  192
#define NS   16
#define RR   6
#define KK   4
#define CH   25   // chunk length per lane (LL/64)

__device__ __forceinline__ float sigmoidf_(float x){ return 1.0f/(1.0f+expf(-x)); }
__device__ __forceinline__ float softplus_fast(float x){
  return x > 20.0f ? x : __logf(1.0f + __expf(x));
}

// ---------------- K1: in_proj (1x1) for both modalities ----------------
// grid: (L/16, 2*B), block 256. xproj layout [mb][o][p]
__global__ void k_inproj(const float* __restrict__ x_rgb, const float* __restrict__ x_e,
                         const float* __restrict__ w_rgb, const float* __restrict__ w_e,
                         float* __restrict__ xproj){
  __shared__ float xin[16][100];          // [px][c], padded row
  int l0 = blockIdx.x * 16;
  int mb = blockIdx.y;                    // m*BN + b
  int m = mb / BN, b = mb % BN;
  const float* xsrc = (m == 0 ? x_rgb : x_e) + (size_t)b * CIN * LL;
  const float* w    = (m == 0 ? w_rgb : w_e);
  for (int idx = threadIdx.x; idx < CIN * 16; idx += 256){
    int c = idx >> 4, px = idx & 15;
    xin[px][c] = xsrc[c * LL + l0 + px];
  }
  __syncthreads();
  int px = threadIdx.x & 15;
  int o0 = (threadIdx.x >> 4) * 12;       // 16 groups x 12 outputs
  float acc[12];
  #pragma unroll
  for (int i = 0; i < 12; ++i) acc[i] = 0.f;
  const float4* xv = reinterpret_cast<const float4*>(xin[px]);
  for (int cc = 0; cc < CIN / 4; ++cc){
    float4 x4 = xv[cc];
    #pragma unroll
    for (int i = 0; i < 12; ++i){
      float4 w4 = *reinterpret_cast<const float4*>(w + (o0 + i) * CIN + cc * 4);
      acc[i] += w4.x * x4.x + w4.y * x4.y + w4.z * x4.z + w4.w * x4.w;
    }
  }
  #pragma unroll
  for (int i = 0; i < 12; ++i)
    xproj[((size_t)mb * DIN + o0 + i) * LL + l0 + px] = acc[i];
}

// ------ K2: depthwise 3x3 + bias + SiLU; emit x_act, x_actT, u_ch, SE mean ---
// grid: (DIN, 2*B), block 256
__global__ void k_conv(const float* __restrict__ xproj, const float* __restrict__ conv_w,
                       const float* __restrict__ conv_b, float* __restrict__ x_act,
                       float* __restrict__ x_actT, float* __restrict__ u_chA,
                       float* __restrict__ u_chT, float* __restrict__ sq){
  __shared__ float pl[LL];
  __shared__ float sact[LL + HH];    // padded: index l + l/40
  __shared__ float red[4];
  int d  = blockIdx.x;
  int mb = blockIdx.y;
  const float* src = xproj + ((size_t)mb * DIN + d) * LL;
  for (int p = threadIdx.x; p < LL; p += blockDim.x) pl[p] = src[p];
  __syncthreads();
  float cw[9];
  #pragma unroll
  for (int j = 0; j < 9; ++j) cw[j] = conv_w[d * 9 + j];
  float bias = conv_b[d];
  float* dst = x_act + ((size_t)mb * DIN + d) * LL;
  float lsum = 0.f;
  for (int p = threadIdx.x; p < LL; p += blockDim.x){
    int py = p / WW, px = p % WW;
    float acc = bias;
    #pragma unroll
    for (int dy = -1; dy <= 1; ++dy){
      int yy = py + dy;
      if (yy < 0 || yy >= HH) continue;
      #pragma unroll
      for (int dx = -1; dx <= 1; ++dx){
        int xx = px + dx;
        if (xx < 0 || xx >= WW) continue;
        acc += cw[(dy + 1) * 3 + (dx + 1)] * pl[yy * WW + xx];
      }
    }
    float s = acc * sigmoidf_(acc);
    dst[p] = s;
    sact[p + p / WW] = s;
    lsum += s;
  }
  #pragma unroll
  for (int off = 32; off; off >>= 1) lsum += __shfl_down(lsum, off);
  if ((threadIdx.x & 63) == 0) red[threadIdx.x >> 6] = lsum;
  __syncthreads();
  if (threadIdx.x == 0)
    sq[mb * DIN + d] = (red[0] + red[1] + red[2] + red[3]) * (1.0f / LL);
  size_t po = ((size_t)mb * DIN + d) * LL;
  float* dstT = x_actT + po;
  float* uA   = u_chA + po;
  float* uT   = u_chT + po;
  for (int q = threadIdx.x; q < LL; q += blockDim.x){
    int lt = (q % WW) * WW + q / WW;
    dstT[q] = sact[lt + lt / WW];
    int l = (q & 63) * CH + (q >> 6);
    uA[q] = sact[l + l / WW];
    int pt = (l % WW) * WW + l / WW;
    uT[q] = sact[pt + pt / WW];
  }
}

// ------ K3: x_proj -> tdt_ch [mbk][r][q]; B/C in [mbk][n/4][q][4] layout ---
// grid: (L/64, K, 2*B), block 256
__global__ void k_xproj(const float* __restrict__ x_act, const float* __restrict__ x_actT,
                        const float* __restrict__ xp1, const float* __restrict__ xp2,
                        float* __restrict__ tdt_ch, float* __restrict__ B_ch,
                        float* __restrict__ C_ch){
  __shared__ float xs_t[DIN][64];
  int l0 = blockIdx.x * 64;
  int k  = blockIdx.y;
  int mb = blockIdx.z; int m = mb / BN;
  const float* xw = (m == 0 ? xp1 : xp2) + k * 38 * DIN;
  const float* xa = ((k & 1) ? x_actT : x_act) + (size_t)mb * DIN * LL;
  bool rev = (k >= 2);
  for (int idx = threadIdx.x; idx < DIN * 64; idx += blockDim.x){
    int dd = idx >> 6, ll = idx & 63;
    int l = l0 + ll; if (rev) l = LL - 1 - l;
    xs_t[dd][ll] = xa[dd * LL + l];
  }
  __syncthreads();
  int mbk = mb * KK + k;
  for (int oidx = threadIdx.x; oidx < 38 * 64; oidx += blockDim.x){
    int c = oidx >> 6, ll = oidx & 63;
    const float* wr = xw + c * DIN;
    float acc = 0.f;
    #pragma unroll 8
    for (int dd = 0; dd < DIN; ++dd) acc += wr[dd] * xs_t[dd][ll];
    int l = l0 + ll;
    int q = (l % CH) * 64 + l / CH;     // chunk-order index
    if (c < RR){
      tdt_ch[((size_t)mbk * RR + c) * LL + q] = acc;
    } else if (c < RR + NS){
      int n = c - RR;
      B_ch[(((size_t)mbk * 4 + (n >> 2)) * LL + q) * 4 + (n & 3)] = acc;
    } else {
      int n = c - RR - NS;
      C_ch[(((size_t)mbk * 4 + (n >> 2)) * LL + q) * 4 + (n & 3)] = acc;
    }
  }
}

// ---------------- K4: chunked parallel selective scan -------------------
// ONE WAVE PER CHAIN, all 16 states in registers. All LDS (dt, ystage) is
// wave-private -> NO barriers, NO atomics. Phase 1: local scan + y_local
// store (u,B,C loaded once). Phase 2: correction-only pass
// (y += sum_n carry[n]*Rcum^(n+1)*C[n], C reload only, 1 exp/step).
// fastA: An[n] == -(n+1) (A_log = log(1..16)), generic fallback otherwise.
// grid: 768 blocks of 256 (4 chains/block). y_px layout [chain][pixel]
__global__ void __launch_bounds__(256, 3) k_scan(
    const float* __restrict__ u_chA, const float* __restrict__ u_chT,
    const float* __restrict__ tdt_all, const float* __restrict__ B_ch,
    const float* __restrict__ C_ch,
    const float* __restrict__ Alog1, const float* __restrict__ Alog2,
    const float* __restrict__ D1, const float* __restrict__ D2,
    const float* __restrict__ dtw1, const float* __restrict__ dtb1,
    const float* __restrict__ dtw2, const float* __restrict__ dtb2,
    float* __restrict__ y_px){
  __shared__ float ystage[4][LL + HH];      // [wave][pad l]  (wave-private)
  __shared__ float dt_lds[4][LL];           // [wave][q]      (wave-private)
  int wv   = threadIdx.x >> 6;
  int lane = threadIdx.x & 63;
  int chain = blockIdx.x * 4 + wv;          // = (mb*KK + k)*DIN + d
  int d   = chain % DIN;
  int mbk = chain / DIN;
  int k   = mbk % KK;
  int mb  = mbk / KK;
  int m = mb / BN, b = mb % BN;
  int kd = k * DIN + d;
  bool rev = (k >= 2);

  const float* Alog = (m == 0 ? Alog1 : Alog2) + kd * NS;
  float An[NS];
  bool fastA = true;
  #pragma unroll
  for (int n = 0; n < NS; ++n){
    An[n] = -__expf(Alog[n]);
    fastA = fastA && (fabsf(An[n] + (float)(n + 1)) <= 1e-4f * (float)(n + 1));
  }
  float Dv = (m == 0 ? D2 : D1)[kd];
  const float* dtw = (m == 0 ? dtw1 : dtw2) + kd * RR;
  float w0 = dtw[0], w1 = dtw[1], w2 = dtw[2], w3 = dtw[3], w4 = dtw[4], w5 = dtw[5];
  float dbias = (m == 0 ? dtb1 : dtb2)[kd];

  const float* t0 = tdt_all + (size_t)mbk * RR * LL;    // [r][q] rows
  // dt for this wave's chain (wave-private LDS; compiler orders ds ops)
  for (int s = 0; s < CH; ++s){
    int q = s * 64 + lane;
    float dtpre = w0 * t0[q] + w1 * t0[LL + q] + w2 * t0[2 * LL + q]
                + w3 * t0[3 * LL + q] + w4 * t0[4 * LL + q] + w5 * t0[5 * LL + q] + dbias;
    dt_lds[wv][q] = softplus_fast(dtpre);
  }

  const float4* B0 = reinterpret_cast<const float4*>(B_ch) + (size_t)mbk * 4 * LL;
  int mbk_o = ((1 - m) * BN + b) * KK + k;              // other modality's C
  const float4* C0 = reinterpret_cast<const float4*>(C_ch) + (size_t)mbk_o * 4 * LL;
  const float* urow = ((k & 1) ? u_chT : u_chA) + ((size_t)mb * DIN + d) * LL;

  float h[NS];
  #pragma unroll
  for (int n = 0; n < NS; ++n) h[n] = 0.f;
  float Sdt = 0.f;

  // phase 1: local chunk scan, emit y_local (plain store, single writer)
  if (fastA){
    #pragma unroll 5
    for (int s = 0; s < CH; ++s){
      int q = s * 64 + lane;
      float dt = dt_lds[wv][q];
      Sdt += dt;
      float u  = urow[rev ? (LL - 1 - q) : q];
      float du = dt * u;
      float4 b0 = B0[q], b1 = B0[LL + q], b2 = B0[2 * LL + q], b3 = B0[3 * LL + q];
      float4 c0 = C0[q], c1 = C0[LL + q], c2 = C0[2 * LL + q], c3 = C0[3 * LL + q];
      float Bv[NS] = {b0.x,b0.y,b0.z,b0.w, b1.x,b1.y,b1.z,b1.w,
                      b2.x,b2.y,b2.z,b2.w, b3.x,b3.y,b3.z,b3.w};
      float Cv[NS] = {c0.x,c0.y,c0.z,c0.w, c1.x,c1.y,c1.z,c1.w,
                      c2.x,c2.y,c2.z,c2.w, c3.x,c3.y,c3.z,c3.w};
      float r = __expf(-dt);
      float p = 1.f;
      float y = Dv * u;
      #pragma unroll
      for (int n = 0; n < NS; ++n){
        p *= r;                          // p = r^(n+1) = exp(dt*An[n])
        h[n] = p * h[n] + du * Bv[n];
        y += h[n] * Cv[n];
      }
      int l = lane * CH + s;
      ystage[wv][l + l / WW] = y;
    }
  } else {
    #pragma unroll 5
    for (int s = 0; s < CH; ++s){
      int q = s * 64 + lane;
      float dt = dt_lds[wv][q];
      Sdt += dt;
      float u  = urow[rev ? (LL - 1 - q) : q];
      float du = dt * u;
      float4 b0 = B0[q], b1 = B0[LL + q], b2 = B0[2 * LL + q], b3 = B0[3 * LL + q];
      float4 c0 = C0[q], c1 = C0[LL + q], c2 = C0[2 * LL + q], c3 = C0[3 * LL + q];
      float Bv[NS] = {b0.x,b0.y,b0.z,b0.w, b1.x,b1.y,b1.z,b1.w,
                      b2.x,b2.y,b2.z,b2.w, b3.x,b3.y,b3.z,b3.w};
      float Cv[NS] = {c0.x,c0.y,c0.z,c0.w, c1.x,c1.y,c1.z,c1.w,
                      c2.x,c2.y,c2.z,c2.w, c3.x,c3.y,c3.z,c3.w};
      float y = Dv * u;
      #pragma unroll
      for (int n = 0; n < NS; ++n){
        float dA = __expf(dt * An[n]);
        h[n] = dA * h[n] + du * Bv[n];
        y += h[n] * Cv[n];
      }
      int l = lane * CH + s;
      ystage[wv][l + l / WW] = y;
    }
  }
  float aP[NS];
  if (fastA){
    float R = __expf(-Sdt);
    float P = 1.f;
    #pragma unroll
    for (int n = 0; n < NS; ++n){ P *= R; aP[n] = P; }
  } else {
    #pragma unroll
    for (int n = 0; n < NS; ++n) aP[n] = __expf(Sdt * An[n]);
  }

  // Kogge-Stone inclusive scan of (aP,h) across 64 lanes (chunk order)
  #pragma unroll
  for (int off = 1; off < 64; off <<= 1){
    #pragma unroll
    for (int n = 0; n < NS; ++n){
      float ap = __shfl_up(aP[n], off);
      float bp = __shfl_up(h[n],  off);
      if (lane >= off){
        h[n]  = aP[n] * bp + h[n];
        aP[n] = aP[n] * ap;
      }
    }
  }
  // carry-in for this chunk = inclusive result of previous lane
  #pragma unroll
  for (int n = 0; n < NS; ++n){
    float v = __shfl_up(h[n], 1);
    h[n] = (lane == 0) ? 0.f : v;      // h[] now holds the carry
  }

  // phase 2: correction pass — ystage[l] += sum_n carry[n]*E_s^(n+1)*C[n]
  if (fastA){
    float Rcum = 1.f;
    #pragma unroll 5
    for (int s = 0; s < CH; ++s){
      int q = s * 64 + lane;
      Rcum *= __expf(-dt_lds[wv][q]);          // = exp(-cum_s)
      float4 c0 = C0[q], c1 = C0[LL + q], c2 = C0[2 * LL + q], c3 = C0[3 * LL + q];
      float Cv[NS] = {c0.x,c0.y,c0.z,c0.w, c1.x,c1.y,c1.z,c1.w,
                      c2.x,c2.y,c2.z,c2.w, c3.x,c3.y,c3.z,c3.w};
      float p = 1.f, corr = 0.f;
      #pragma unroll
      for (int n = 0; n < NS; ++n){
        p *= Rcum;                             // p = exp(An[n]*cum_s)
        corr += h[n] * p * Cv[n];
      }
      int l = lane * CH + s;
      ystage[wv][l + l / WW] += corr;
    }
  } else {
    float cum = 0.f;
    #pragma unroll 5
    for (int s = 0; s < CH; ++s){
      int q = s * 64 + lane;
      cum += dt_lds[wv][q];
      float4 c0 = C0[q], c1 = C0[LL + q], c2 = C0[2 * LL + q], c3 = C0[3 * LL + q];
      float Cv[NS] = {c0.x,c0.y,c0.z,c0.w, c1.x,c1.y,c1.z,c1.w,
                      c2.x,c2.y,c2.z,c2.w, c3.x,c3.y,c3.z,c3.w};
      float corr = 0.f;
      #pragma unroll
      for (int n = 0; n < NS; ++n)
        corr += h[n] * __expf(cum * An[n]) * Cv[n];
      int l = lane * CH + s;
      ystage[wv][l + l / WW] += corr;
    }
  }

  // flush OWN ystage in PIXEL order (no barrier — wave-private buffer).
  // fold reversal (k>=2) + transpose (k odd) here.
  float* yo = y_px + (size_t)chain * LL;
  for (int qq = lane; qq < LL; qq += 64){
    int l;
    if      (k == 0) l = qq;
    else if (k == 1) l = (qq % WW) * WW + qq / WW;
    else if (k == 2) l = LL - 1 - qq;
    else             { int qt = (qq % WW) * WW + qq / WW; l = LL - 1 - qt; }
    yo[qq] = ystage[wv][l + l / WW];
  }
}

// ------ K5: FUSED merge + LayerNorm + cross SE + out_proj ---------------
// grid: (L/16, B), block 256. Handles BOTH modalities per block, then the
// 96x384 out-GEMM straight from LDS (y_final round-trip eliminated).
__global__ void __launch_bounds__(256) k_mergeout(
    const float* __restrict__ y_px, const float* __restrict__ sq,
    const float* __restrict__ fc1_w1, const float* __restrict__ fc1_w2,
    const float* __restrict__ fc2_w1, const float* __restrict__ fc2_w2,
    const float* __restrict__ n1g, const float* __restrict__ n1b,
    const float* __restrict__ n2g, const float* __restrict__ n2b,
    const float* __restrict__ wout, float* __restrict__ out){
  __shared__ float acc[2 * DIN][17];      // [(m*DIN+dd)][pp]
  __shared__ float yt[16][388];           // [pp][m*DIN+dd], GEMM operand
  __shared__ float ps[2][16][8], ps2[2][16][8];
  __shared__ float mu_s[2][16], inv_s[2][16];
  __shared__ float sqs[2][DIN];           // sq of the OTHER modality, per m
  __shared__ float hid[2][12];
  __shared__ float exc_s[2][DIN];
  int p0 = blockIdx.x * 16;
  int b  = blockIdx.y;
  int tid = threadIdx.x;
  // region A: 4-direction merged sums + sq loads
  for (int idx = tid; idx < 2 * DIN * 16; idx += 256){
    int pp = idx & 15, row = idx >> 4;
    int mm = (row >= DIN), dd = row - mm * DIN;
    const float* yb = y_px + (((size_t)(mm * BN + b) * KK) * DIN + dd) * LL + p0 + pp;
    acc[row][pp] = yb[0] + yb[(size_t)DIN * LL]
                 + yb[2 * (size_t)DIN * LL] + yb[3 * (size_t)DIN * LL];
  }
  for (int i = tid; i < 2 * DIN; i += 256){
    int mm = (i >= DIN), dd = i - mm * DIN;
    sqs[mm][dd] = sq[((1 - mm) * BN + b) * DIN + dd];
  }
  __syncthreads();
  // region B: SE hidden layer (24 thr) + LN stats partials (all 256)
  if (tid < 24){
    int mm = tid / 12, j = tid - mm * 12;
    const float* w1 = (mm == 1 ? fc1_w1 : fc2_w1);
    float a = 0.f;
    for (int cch = 0; cch < DIN; ++cch) a += w1[j * DIN + cch] * sqs[mm][cch];
    hid[mm][j] = a * sigmoidf_(a);
  }
  {
    int g = tid >> 5, mm = (tid >> 4) & 1, pp = tid & 15;
    float s = 0.f, s2 = 0.f;
    #pragma unroll 4
    for (int j = 0; j < 24; ++j){
      float v = acc[mm * DIN + g * 24 + j][pp];
      s += v; s2 += v * v;
    }
    ps[mm][pp][g] = s; ps2[mm][pp][g] = s2;
  }
  __syncthreads();
  // region C: LN stats final (32 thr) + SE excitation (all, strided)
  if (tid < 32){
    int mm = tid >> 4, pp = tid & 15;
    float s = 0.f, s2 = 0.f;
    #pragma unroll
    for (int g = 0; g < 8; ++g){ s += ps[mm][pp][g]; s2 += ps2[mm][pp][g]; }
    float mu  = s * (1.0f / DIN);
    float var = s2 * (1.0f / DIN) - mu * mu;
    mu_s[mm][pp] = mu; inv_s[mm][pp] = rsqrtf(var + 1e-5f);
  }
  for (int i = tid; i < 2 * DIN; i += 256){
    int mm = (i >= DIN), dd = i - mm * DIN;
    const float* w2 = (mm == 1 ? fc1_w2 : fc2_w2);
    float e = 0.f;
    #pragma unroll
    for (int j = 0; j < 12; ++j) e += w2[dd * 12 + j] * hid[mm][j];
    exc_s[mm][dd] = sigmoidf_(e);
  }
  __syncthreads();
  // region D: normalize + SE scale into yt
  for (int idx = tid; idx < 2 * DIN * 16; idx += 256){
    int pp = idx & 15, row = idx >> 4;
    int mm = (row >= DIN), dd = row - mm * DIN;
    float g  = (mm ? n2g : n1g)[dd];
    float bb = (mm ? n2b : n1b)[dd];
    float v = (acc[row][pp] - mu_s[mm][pp]) * inv_s[mm][pp] * g + bb;
    yt[pp][row] = v * exc_s[mm][dd];
  }
  __syncthreads();
  // region E: out_proj 96x384 from LDS
  int pp = tid & 15;
  int o0 = (tid >> 4) * 6;                // 16 groups x 6 outputs
  float a6[6];
  #pragma unroll
  for (int i = 0; i < 6; ++i) a6[i] = 0.f;
  const float4* yv = reinterpret_cast<const float4*>(yt[pp]);
  for (int cc = 0; cc < 96; ++cc){
    float4 x4 = yv[cc];
    #pragma unroll
    for (int i = 0; i < 6; ++i){
      float4 w4 = *reinterpret_cast<const float4*>(wout + (o0 + i) * 2 * DIN + cc * 4);
      a6[i] += w4.x * x4.x + w4.y * x4.y + w4.z * x4.z + w4.w * x4.w;
    }
  }
  #pragma unroll
  for (int i = 0; i < 6; ++i)
    out[((size_t)b * CIN + o0 + i) * LL + p0 + pp] = a6[i];
}

extern "C" void kernel_launch(void* const* d_in, const int* in_sizes, int n_in,
                              void* d_out, int out_size, void* d_ws, size_t ws_size,
                              hipStream_t stream){
  const float* x_rgb   = (const float*)d_in[0];
  const float* x_e     = (const float*)d_in[1];
  const float* in_w    = (const float*)d_in[2];
  const float* in_mx_w = (const float*)d_in[3];
  const float* conv_w  = (const float*)d_in[4];
  const float* conv_b  = (const float*)d_in[5];
  const float* xp1     = (const float*)d_in[6];
  const float* xp2     = (const float*)d_in[7];
  const float* dtw1    = (const float*)d_in[8];
  const float* dtb1    = (const float*)d_in[9];
  const float* dtw2    = (const float*)d_in[10];
  const float* dtb2    = (const float*)d_in[11];
  const float* Alog1   = (const float*)d_in[12];
  const float* Alog2   = (const float*)d_in[13];
  const float* D1      = (const float*)d_in[14];
  const float* D2      = (const float*)d_in[15];
  const float* n1g     = (const float*)d_in[16];
  const float* n1b     = (const float*)d_in[17];
  const float* n2g     = (const float*)d_in[18];
  const float* n2b     = (const float*)d_in[19];
  const float* fc1_w1  = (const float*)d_in[20];
  const float* fc1_w2  = (const float*)d_in[21];
  const float* fc2_w1  = (const float*)d_in[22];
  const float* fc2_w2  = (const float*)d_in[23];
  const float* wout    = (const float*)d_in[24];

  float* ws = (float*)d_ws;
  // region plan (floats), total 12,032,768 (= 48.1 MB):
  //   [0,        1228800) u_chA   (k_conv -> k_scan)
  //   [1228800,  2457600) u_chT   (k_conv -> k_scan)
  //   [2457600,  3686400) x_act   (k_conv -> k_xproj)
  //   [3686400,  4915200) x_actT  (k_conv -> k_xproj)
  //   [4915200,  6144000) xproj   (k_inproj -> k_conv)
  //   [6144000, 11059200) y_px    (k_scan -> k_mergeout)
  //   [11059200,11468800) B_ch    [mbk][n/4][q][4]
  //   [11468800,11878400) C_ch    [mbk][n/4][q][4]
  //   [11878400,12032000) tdt_ch  [mbk][r][q]
  //   [12032000,12032768) sq
  float* u_chA   = ws;
  float* u_chT   = ws + 1228800;
  float* x_act   = ws + 2457600;
  float* x_actT  = ws + 3686400;
  float* xproj   = ws + 4915200;
  float* y_px    = ws + 6144000;
  float* B_ch    = ws + 11059200;
  float* C_ch    = ws + 11468800;
  float* tdt_ch  = ws + 11878400;
  float* sq      = ws + 12032000;

  k_inproj  <<<dim3(LL / 16, 2 * BN), 256, 0, stream>>>(x_rgb, x_e, in_w, in_mx_w, xproj);
  k_conv    <<<dim3(DIN, 2 * BN), 256, 0, stream>>>(xproj, conv_w, conv_b,
                                                    x_act, x_actT, u_chA, u_chT, sq);
  k_xproj   <<<dim3(LL / 64, KK, 2 * BN), 256, 0, stream>>>(x_act, x_actT, xp1, xp2,
                                                            tdt_ch, B_ch, C_ch);
  k_scan    <<<768, 256, 0, stream>>>(u_chA, u_chT, tdt_ch, B_ch, C_ch,
                                      Alog1, Alog2, D1, D2,
                                      dtw1, dtb1, dtw2, dtb2, y_px);
  k_mergeout<<<dim3(LL / 16, BN), 256, 0, stream>>>(y_px, sq,
                                                    fc1_w1, fc1_w2, fc2_w1, fc2_w2,
                                                    n1g, n1b, n2g, n2b,
                                                    wout, (float*)d_out);
}

// Round 12
// 180.198 us; speedup vs baseline: 1.3624x; 1.0515x over previous
//
#include <hip/hip_runtime.h>
#include <math.h>

#define BN   2
#define CIN  96
#define HH   40
#define WW   40
#define LL   1600
#define DIN  192
#define NS   16
#define RR   6
#define KK   4
#define CH   25   // chunk length per lane (LL/64)

__device__ __forceinline__ float sigmoidf_(float x){ return 1.0f/(1.0f+expf(-x)); }
__device__ __forceinline__ float softplus_fast(float x){
  return x > 20.0f ? x : __logf(1.0f + __expf(x));
}

// p[i] = R^(i+1) for i=0..15, log-depth tree (depth ~4, 15 muls)
__device__ __forceinline__ void pow_tree(float R, float* p){
  float R2 = R * R;
  float R4 = R2 * R2;
  float R8 = R4 * R4;
  p[0]  = R;        p[1]  = R2;       p[2]  = R2 * R;   p[3]  = R4;
  p[4]  = R4 * R;   p[5]  = R4 * R2;  p[6]  = R4 * p[2];p[7]  = R8;
  p[8]  = R8 * R;   p[9]  = R8 * R2;  p[10] = R8 * p[2];p[11] = R8 * R4;
  p[12] = R8 * p[4];p[13] = R8 * p[5];p[14] = R8 * p[6];p[15] = R8 * R8;
}

// ---------------- K1: in_proj (1x1) for both modalities ----------------
// grid: (L/16, 2*B), block 256. xproj layout [mb][o][p]
__global__ void k_inproj(const float* __restrict__ x_rgb, const float* __restrict__ x_e,
                         const float* __restrict__ w_rgb, const float* __restrict__ w_e,
                         float* __restrict__ xproj){
  __shared__ float xin[16][100];          // [px][c], padded row
  int l0 = blockIdx.x * 16;
  int mb = blockIdx.y;                    // m*BN + b
  int m = mb / BN, b = mb % BN;
  const float* xsrc = (m == 0 ? x_rgb : x_e) + (size_t)b * CIN * LL;
  const float* w    = (m == 0 ? w_rgb : w_e);
  for (int idx = threadIdx.x; idx < CIN * 16; idx += 256){
    int c = idx >> 4, px = idx & 15;
    xin[px][c] = xsrc[c * LL + l0 + px];
  }
  __syncthreads();
  int px = threadIdx.x & 15;
  int o0 = (threadIdx.x >> 4) * 12;       // 16 groups x 12 outputs
  float acc[12];
  #pragma unroll
  for (int i = 0; i < 12; ++i) acc[i] = 0.f;
  const float4* xv = reinterpret_cast<const float4*>(xin[px]);
  for (int cc = 0; cc < CIN / 4; ++cc){
    float4 x4 = xv[cc];
    #pragma unroll
    for (int i = 0; i < 12; ++i){
      float4 w4 = *reinterpret_cast<const float4*>(w + (o0 + i) * CIN + cc * 4);
      acc[i] += w4.x * x4.x + w4.y * x4.y + w4.z * x4.z + w4.w * x4.w;
    }
  }
  #pragma unroll
  for (int i = 0; i < 12; ++i)
    xproj[((size_t)mb * DIN + o0 + i) * LL + l0 + px] = acc[i];
}

// ------ K2: depthwise 3x3 + bias + SiLU; emit x_act, x_actT, u_ch, SE mean ---
// grid: (DIN, 2*B), block 256
__global__ void k_conv(const float* __restrict__ xproj, const float* __restrict__ conv_w,
                       const float* __restrict__ conv_b, float* __restrict__ x_act,
                       float* __restrict__ x_actT, float* __restrict__ u_chA,
                       float* __restrict__ u_chT, float* __restrict__ sq){
  __shared__ float pl[LL];
  __shared__ float sact[LL + HH];    // padded: index l + l/40
  __shared__ float red[4];
  int d  = blockIdx.x;
  int mb = blockIdx.y;
  const float* src = xproj + ((size_t)mb * DIN + d) * LL;
  for (int p = threadIdx.x; p < LL; p += blockDim.x) pl[p] = src[p];
  __syncthreads();
  float cw[9];
  #pragma unroll
  for (int j = 0; j < 9; ++j) cw[j] = conv_w[d * 9 + j];
  float bias = conv_b[d];
  float* dst = x_act + ((size_t)mb * DIN + d) * LL;
  float lsum = 0.f;
  for (int p = threadIdx.x; p < LL; p += blockDim.x){
    int py = p / WW, px = p % WW;
    float acc = bias;
    #pragma unroll
    for (int dy = -1; dy <= 1; ++dy){
      int yy = py + dy;
      if (yy < 0 || yy >= HH) continue;
      #pragma unroll
      for (int dx = -1; dx <= 1; ++dx){
        int xx = px + dx;
        if (xx < 0 || xx >= WW) continue;
        acc += cw[(dy + 1) * 3 + (dx + 1)] * pl[yy * WW + xx];
      }
    }
    float s = acc * sigmoidf_(acc);
    dst[p] = s;
    sact[p + p / WW] = s;
    lsum += s;
  }
  #pragma unroll
  for (int off = 32; off; off >>= 1) lsum += __shfl_down(lsum, off);
  if ((threadIdx.x & 63) == 0) red[threadIdx.x >> 6] = lsum;
  __syncthreads();
  if (threadIdx.x == 0)
    sq[mb * DIN + d] = (red[0] + red[1] + red[2] + red[3]) * (1.0f / LL);
  size_t po = ((size_t)mb * DIN + d) * LL;
  float* dstT = x_actT + po;
  float* uA   = u_chA + po;
  float* uT   = u_chT + po;
  for (int q = threadIdx.x; q < LL; q += blockDim.x){
    int lt = (q % WW) * WW + q / WW;
    dstT[q] = sact[lt + lt / WW];
    int l = (q & 63) * CH + (q >> 6);
    uA[q] = sact[l + l / WW];
    int pt = (l % WW) * WW + l / WW;
    uT[q] = sact[pt + pt / WW];
  }
}

// ------ K3: x_proj -> tdt_ch [mbk][r][q]; B/C in [mbk][n/4][q][4] layout ---
// grid: (L/64, K, 2*B), block 256
__global__ void k_xproj(const float* __restrict__ x_act, const float* __restrict__ x_actT,
                        const float* __restrict__ xp1, const float* __restrict__ xp2,
                        float* __restrict__ tdt_ch, float* __restrict__ B_ch,
                        float* __restrict__ C_ch){
  __shared__ float xs_t[DIN][64];
  int l0 = blockIdx.x * 64;
  int k  = blockIdx.y;
  int mb = blockIdx.z; int m = mb / BN;
  const float* xw = (m == 0 ? xp1 : xp2) + k * 38 * DIN;
  const float* xa = ((k & 1) ? x_actT : x_act) + (size_t)mb * DIN * LL;
  bool rev = (k >= 2);
  for (int idx = threadIdx.x; idx < DIN * 64; idx += blockDim.x){
    int dd = idx >> 6, ll = idx & 63;
    int l = l0 + ll; if (rev) l = LL - 1 - l;
    xs_t[dd][ll] = xa[dd * LL + l];
  }
  __syncthreads();
  int mbk = mb * KK + k;
  for (int oidx = threadIdx.x; oidx < 38 * 64; oidx += blockDim.x){
    int c = oidx >> 6, ll = oidx & 63;
    const float* wr = xw + c * DIN;
    float acc = 0.f;
    #pragma unroll 8
    for (int dd = 0; dd < DIN; ++dd) acc += wr[dd] * xs_t[dd][ll];
    int l = l0 + ll;
    int q = (l % CH) * 64 + l / CH;     // chunk-order index
    if (c < RR){
      tdt_ch[((size_t)mbk * RR + c) * LL + q] = acc;
    } else if (c < RR + NS){
      int n = c - RR;
      B_ch[(((size_t)mbk * 4 + (n >> 2)) * LL + q) * 4 + (n & 3)] = acc;
    } else {
      int n = c - RR - NS;
      C_ch[(((size_t)mbk * 4 + (n >> 2)) * LL + q) * 4 + (n & 3)] = acc;
    }
  }
}

// ---------------- K4: chunked parallel selective scan -------------------
// ONE WAVE PER CHAIN, 16 states in registers, wave-private LDS (no barrier,
// no atomic). This round: dependency-chain shortening — pow_tree for
// R^(n+1) (depth 16->4), 4-way split y accumulators (depth 16->6), and
// phase-2 exp taken off the serial chain (cum-add, independent exp).
// grid: 768 blocks of 256 (4 chains/block). y_px layout [chain][pixel]
__global__ void __launch_bounds__(256, 3) k_scan(
    const float* __restrict__ u_chA, const float* __restrict__ u_chT,
    const float* __restrict__ tdt_all, const float* __restrict__ B_ch,
    const float* __restrict__ C_ch,
    const float* __restrict__ Alog1, const float* __restrict__ Alog2,
    const float* __restrict__ D1, const float* __restrict__ D2,
    const float* __restrict__ dtw1, const float* __restrict__ dtb1,
    const float* __restrict__ dtw2, const float* __restrict__ dtb2,
    float* __restrict__ y_px){
  __shared__ float ystage[4][LL + HH];      // [wave][pad l]  (wave-private)
  __shared__ float dt_lds[4][LL];           // [wave][q]      (wave-private)
  int wv   = threadIdx.x >> 6;
  int lane = threadIdx.x & 63;
  int chain = blockIdx.x * 4 + wv;          // = (mb*KK + k)*DIN + d
  int d   = chain % DIN;
  int mbk = chain / DIN;
  int k   = mbk % KK;
  int mb  = mbk / KK;
  int m = mb / BN, b = mb % BN;
  int kd = k * DIN + d;
  bool rev = (k >= 2);

  const float* Alog = (m == 0 ? Alog1 : Alog2) + kd * NS;
  float An[NS];
  bool fastA = true;
  #pragma unroll
  for (int n = 0; n < NS; ++n){
    An[n] = -__expf(Alog[n]);
    fastA = fastA && (fabsf(An[n] + (float)(n + 1)) <= 1e-4f * (float)(n + 1));
  }
  float Dv = (m == 0 ? D2 : D1)[kd];
  const float* dtw = (m == 0 ? dtw1 : dtw2) + kd * RR;
  float w0 = dtw[0], w1 = dtw[1], w2 = dtw[2], w3 = dtw[3], w4 = dtw[4], w5 = dtw[5];
  float dbias = (m == 0 ? dtb1 : dtb2)[kd];

  const float* t0 = tdt_all + (size_t)mbk * RR * LL;    // [r][q] rows
  for (int s = 0; s < CH; ++s){
    int q = s * 64 + lane;
    float dtpre = w0 * t0[q] + w1 * t0[LL + q] + w2 * t0[2 * LL + q]
                + w3 * t0[3 * LL + q] + w4 * t0[4 * LL + q] + w5 * t0[5 * LL + q] + dbias;
    dt_lds[wv][q] = softplus_fast(dtpre);
  }

  const float4* B0 = reinterpret_cast<const float4*>(B_ch) + (size_t)mbk * 4 * LL;
  int mbk_o = ((1 - m) * BN + b) * KK + k;              // other modality's C
  const float4* C0 = reinterpret_cast<const float4*>(C_ch) + (size_t)mbk_o * 4 * LL;
  const float* urow = ((k & 1) ? u_chT : u_chA) + ((size_t)mb * DIN + d) * LL;

  float h[NS];
  #pragma unroll
  for (int n = 0; n < NS; ++n) h[n] = 0.f;
  float Sdt = 0.f;

  // phase 1: local chunk scan, emit y_local (plain store, single writer)
  if (fastA){
    #pragma unroll 5
    for (int s = 0; s < CH; ++s){
      int q = s * 64 + lane;
      float dt = dt_lds[wv][q];
      Sdt += dt;
      float u  = urow[rev ? (LL - 1 - q) : q];
      float du = dt * u;
      float4 b0 = B0[q], b1 = B0[LL + q], b2 = B0[2 * LL + q], b3 = B0[3 * LL + q];
      float4 c0 = C0[q], c1 = C0[LL + q], c2 = C0[2 * LL + q], c3 = C0[3 * LL + q];
      float Bv[NS] = {b0.x,b0.y,b0.z,b0.w, b1.x,b1.y,b1.z,b1.w,
                      b2.x,b2.y,b2.z,b2.w, b3.x,b3.y,b3.z,b3.w};
      float Cv[NS] = {c0.x,c0.y,c0.z,c0.w, c1.x,c1.y,c1.z,c1.w,
                      c2.x,c2.y,c2.z,c2.w, c3.x,c3.y,c3.z,c3.w};
      float p[NS];
      pow_tree(__expf(-dt), p);         // p[n] = exp(dt*An[n]), depth ~4
      float y0 = Dv * u, y1 = 0.f, y2 = 0.f, y3 = 0.f;
      #pragma unroll
      for (int n = 0; n < NS; ++n){
        h[n] = p[n] * h[n] + du * Bv[n];
        float t = h[n] * Cv[n];
        if      ((n & 3) == 0) y0 += t;
        else if ((n & 3) == 1) y1 += t;
        else if ((n & 3) == 2) y2 += t;
        else                   y3 += t;
      }
      int l = lane * CH + s;
      ystage[wv][l + l / WW] = (y0 + y1) + (y2 + y3);
    }
  } else {
    #pragma unroll 5
    for (int s = 0; s < CH; ++s){
      int q = s * 64 + lane;
      float dt = dt_lds[wv][q];
      Sdt += dt;
      float u  = urow[rev ? (LL - 1 - q) : q];
      float du = dt * u;
      float4 b0 = B0[q], b1 = B0[LL + q], b2 = B0[2 * LL + q], b3 = B0[3 * LL + q];
      float4 c0 = C0[q], c1 = C0[LL + q], c2 = C0[2 * LL + q], c3 = C0[3 * LL + q];
      float Bv[NS] = {b0.x,b0.y,b0.z,b0.w, b1.x,b1.y,b1.z,b1.w,
                      b2.x,b2.y,b2.z,b2.w, b3.x,b3.y,b3.z,b3.w};
      float Cv[NS] = {c0.x,c0.y,c0.z,c0.w, c1.x,c1.y,c1.z,c1.w,
                      c2.x,c2.y,c2.z,c2.w, c3.x,c3.y,c3.z,c3.w};
      float y0 = Dv * u, y1 = 0.f, y2 = 0.f, y3 = 0.f;
      #pragma unroll
      for (int n = 0; n < NS; ++n){
        float dA = __expf(dt * An[n]);
        h[n] = dA * h[n] + du * Bv[n];
        float t = h[n] * Cv[n];
        if      ((n & 3) == 0) y0 += t;
        else if ((n & 3) == 1) y1 += t;
        else if ((n & 3) == 2) y2 += t;
        else                   y3 += t;
      }
      int l = lane * CH + s;
      ystage[wv][l + l / WW] = (y0 + y1) + (y2 + y3);
    }
  }
  float aP[NS];
  if (fastA){
    pow_tree(__expf(-Sdt), aP);
  } else {
    #pragma unroll
    for (int n = 0; n < NS; ++n) aP[n] = __expf(Sdt * An[n]);
  }

  // Kogge-Stone inclusive scan of (aP,h) across 64 lanes (chunk order)
  #pragma unroll
  for (int off = 1; off < 64; off <<= 1){
    #pragma unroll
    for (int n = 0; n < NS; ++n){
      float ap = __shfl_up(aP[n], off);
      float bp = __shfl_up(h[n],  off);
      if (lane >= off){
        h[n]  = aP[n] * bp + h[n];
        aP[n] = aP[n] * ap;
      }
    }
  }
  // carry-in for this chunk = inclusive result of previous lane
  #pragma unroll
  for (int n = 0; n < NS; ++n){
    float v = __shfl_up(h[n], 1);
    h[n] = (lane == 0) ? 0.f : v;      // h[] now holds the carry
  }

  // phase 2: correction pass — ystage[l] += sum_n carry[n]*E_s^(n+1)*C[n]
  if (fastA){
    float cum = 0.f;
    #pragma unroll 5
    for (int s = 0; s < CH; ++s){
      int q = s * 64 + lane;
      cum += dt_lds[wv][q];                    // serial add chain only
      float Rc = __expf(-cum);                 // off the serial chain
      float4 c0 = C0[q], c1 = C0[LL + q], c2 = C0[2 * LL + q], c3 = C0[3 * LL + q];
      float Cv[NS] = {c0.x,c0.y,c0.z,c0.w, c1.x,c1.y,c1.z,c1.w,
                      c2.x,c2.y,c2.z,c2.w, c3.x,c3.y,c3.z,c3.w};
      float p[NS];
      pow_tree(Rc, p);                         // p[n] = exp(An[n]*cum)
      float s0 = 0.f, s1 = 0.f, s2 = 0.f, s3 = 0.f;
      #pragma unroll
      for (int n = 0; n < NS; ++n){
        float t = h[n] * p[n] * Cv[n];
        if      ((n & 3) == 0) s0 += t;
        else if ((n & 3) == 1) s1 += t;
        else if ((n & 3) == 2) s2 += t;
        else                   s3 += t;
      }
      int l = lane * CH + s;
      ystage[wv][l + l / WW] += (s0 + s1) + (s2 + s3);
    }
  } else {
    float cum = 0.f;
    #pragma unroll 5
    for (int s = 0; s < CH; ++s){
      int q = s * 64 + lane;
      cum += dt_lds[wv][q];
      float4 c0 = C0[q], c1 = C0[LL + q], c2 = C0[2 * LL + q], c3 = C0[3 * LL + q];
      float Cv[NS] = {c0.x,c0.y,c0.z,c0.w, c1.x,c1.y,c1.z,c1.w,
                      c2.x,c2.y,c2.z,c2.w, c3.x,c3.y,c3.z,c3.w};
      float s0 = 0.f, s1 = 0.f, s2 = 0.f, s3 = 0.f;
      #pragma unroll
      for (int n = 0; n < NS; ++n){
        float t = h[n] * __expf(cum * An[n]) * Cv[n];
        if      ((n & 3) == 0) s0 += t;
        else if ((n & 3) == 1) s1 += t;
        else if ((n & 3) == 2) s2 += t;
        else                   s3 += t;
      }
      int l = lane * CH + s;
      ystage[wv][l + l / WW] += (s0 + s1) + (s2 + s3);
    }
  }

  // flush OWN ystage in PIXEL order (no barrier — wave-private buffer).
  float* yo = y_px + (size_t)chain * LL;
  for (int qq = lane; qq < LL; qq += 64){
    int l;
    if      (k == 0) l = qq;
    else if (k == 1) l = (qq % WW) * WW + qq / WW;
    else if (k == 2) l = LL - 1 - qq;
    else             { int qt = (qq % WW) * WW + qq / WW; l = LL - 1 - qt; }
    yo[qq] = ystage[wv][l + l / WW];
  }
}

// ------ K5: FUSED merge + LayerNorm + cross SE + out_proj ---------------
// grid: (L/16, B), block 256.
__global__ void __launch_bounds__(256) k_mergeout(
    const float* __restrict__ y_px, const float* __restrict__ sq,
    const float* __restrict__ fc1_w1, const float* __restrict__ fc1_w2,
    const float* __restrict__ fc2_w1, const float* __restrict__ fc2_w2,
    const float* __restrict__ n1g, const float* __restrict__ n1b,
    const float* __restrict__ n2g, const float* __restrict__ n2b,
    const float* __restrict__ wout, float* __restrict__ out){
  __shared__ float acc[2 * DIN][17];      // [(m*DIN+dd)][pp]
  __shared__ float yt[16][388];           // [pp][m*DIN+dd], GEMM operand
  __shared__ float ps[2][16][8], ps2[2][16][8];
  __shared__ float mu_s[2][16], inv_s[2][16];
  __shared__ float sqs[2][DIN];           // sq of the OTHER modality, per m
  __shared__ float hid[2][12];
  __shared__ float exc_s[2][DIN];
  int p0 = blockIdx.x * 16;
  int b  = blockIdx.y;
  int tid = threadIdx.x;
  for (int idx = tid; idx < 2 * DIN * 16; idx += 256){
    int pp = idx & 15, row = idx >> 4;
    int mm = (row >= DIN), dd = row - mm * DIN;
    const float* yb = y_px + (((size_t)(mm * BN + b) * KK) * DIN + dd) * LL + p0 + pp;
    acc[row][pp] = yb[0] + yb[(size_t)DIN * LL]
                 + yb[2 * (size_t)DIN * LL] + yb[3 * (size_t)DIN * LL];
  }
  for (int i = tid; i < 2 * DIN; i += 256){
    int mm = (i >= DIN), dd = i - mm * DIN;
    sqs[mm][dd] = sq[((1 - mm) * BN + b) * DIN + dd];
  }
  __syncthreads();
  if (tid < 24){
    int mm = tid / 12, j = tid - mm * 12;
    const float* w1 = (mm == 1 ? fc1_w1 : fc2_w1);
    float a = 0.f;
    for (int cch = 0; cch < DIN; ++cch) a += w1[j * DIN + cch] * sqs[mm][cch];
    hid[mm][j] = a * sigmoidf_(a);
  }
  {
    int g = tid >> 5, mm = (tid >> 4) & 1, pp = tid & 15;
    float s = 0.f, s2 = 0.f;
    #pragma unroll 4
    for (int j = 0; j < 24; ++j){
      float v = acc[mm * DIN + g * 24 + j][pp];
      s += v; s2 += v * v;
    }
    ps[mm][pp][g] = s; ps2[mm][pp][g] = s2;
  }
  __syncthreads();
  if (tid < 32){
    int mm = tid >> 4, pp = tid & 15;
    float s = 0.f, s2 = 0.f;
    #pragma unroll
    for (int g = 0; g < 8; ++g){ s += ps[mm][pp][g]; s2 += ps2[mm][pp][g]; }
    float mu  = s * (1.0f / DIN);
    float var = s2 * (1.0f / DIN) - mu * mu;
    mu_s[mm][pp] = mu; inv_s[mm][pp] = rsqrtf(var + 1e-5f);
  }
  for (int i = tid; i < 2 * DIN; i += 256){
    int mm = (i >= DIN), dd = i - mm * DIN;
    const float* w2 = (mm == 1 ? fc1_w2 : fc2_w2);
    float e = 0.f;
    #pragma unroll
    for (int j = 0; j < 12; ++j) e += w2[dd * 12 + j] * hid[mm][j];
    exc_s[mm][dd] = sigmoidf_(e);
  }
  __syncthreads();
  for (int idx = tid; idx < 2 * DIN * 16; idx += 256){
    int pp = idx & 15, row = idx >> 4;
    int mm = (row >= DIN), dd = row - mm * DIN;
    float g  = (mm ? n2g : n1g)[dd];
    float bb = (mm ? n2b : n1b)[dd];
    float v = (acc[row][pp] - mu_s[mm][pp]) * inv_s[mm][pp] * g + bb;
    yt[pp][row] = v * exc_s[mm][dd];
  }
  __syncthreads();
  int pp = tid & 15;
  int o0 = (tid >> 4) * 6;                // 16 groups x 6 outputs
  float a6[6];
  #pragma unroll
  for (int i = 0; i < 6; ++i) a6[i] = 0.f;
  const float4* yv = reinterpret_cast<const float4*>(yt[pp]);
  for (int cc = 0; cc < 96; ++cc){
    float4 x4 = yv[cc];
    #pragma unroll
    for (int i = 0; i < 6; ++i){
      float4 w4 = *reinterpret_cast<const float4*>(wout + (o0 + i) * 2 * DIN + cc * 4);
      a6[i] += w4.x * x4.x + w4.y * x4.y + w4.z * x4.z + w4.w * x4.w;
    }
  }
  #pragma unroll
  for (int i = 0; i < 6; ++i)
    out[((size_t)b * CIN + o0 + i) * LL + p0 + pp] = a6[i];
}

extern "C" void kernel_launch(void* const* d_in, const int* in_sizes, int n_in,
                              void* d_out, int out_size, void* d_ws, size_t ws_size,
                              hipStream_t stream){
  const float* x_rgb   = (const float*)d_in[0];
  const float* x_e     = (const float*)d_in[1];
  const float* in_w    = (const float*)d_in[2];
  const float* in_mx_w = (const float*)d_in[3];
  const float* conv_w  = (const float*)d_in[4];
  const float* conv_b  = (const float*)d_in[5];
  const float* xp1     = (const float*)d_in[6];
  const float* xp2     = (const float*)d_in[7];
  const float* dtw1    = (const float*)d_in[8];
  const float* dtb1    = (const float*)d_in[9];
  const float* dtw2    = (const float*)d_in[10];
  const float* dtb2    = (const float*)d_in[11];
  const float* Alog1   = (const float*)d_in[12];
  const float* Alog2   = (const float*)d_in[13];
  const float* D1      = (const float*)d_in[14];
  const float* D2      = (const float*)d_in[15];
  const float* n1g     = (const float*)d_in[16];
  const float* n1b     = (const float*)d_in[17];
  const float* n2g     = (const float*)d_in[18];
  const float* n2b     = (const float*)d_in[19];
  const float* fc1_w1  = (const float*)d_in[20];
  const float* fc1_w2  = (const float*)d_in[21];
  const float* fc2_w1  = (const float*)d_in[22];
  const float* fc2_w2  = (const float*)d_in[23];
  const float* wout    = (const float*)d_in[24];

  float* ws = (float*)d_ws;
  float* u_chA   = ws;
  float* u_chT   = ws + 1228800;
  float* x_act   = ws + 2457600;
  float* x_actT  = ws + 3686400;
  float* xproj   = ws + 4915200;
  float* y_px    = ws + 6144000;
  float* B_ch    = ws + 11059200;
  float* C_ch    = ws + 11468800;
  float* tdt_ch  = ws + 11878400;
  float* sq      = ws + 12032000;

  k_inproj  <<<dim3(LL / 16, 2 * BN), 256, 0, stream>>>(x_rgb, x_e, in_w, in_mx_w, xproj);
  k_conv    <<<dim3(DIN, 2 * BN), 256, 0, stream>>>(xproj, conv_w, conv_b,
                                                    x_act, x_actT, u_chA, u_chT, sq);
  k_xproj   <<<dim3(LL / 64, KK, 2 * BN), 256, 0, stream>>>(x_act, x_actT, xp1, xp2,
                                                            tdt_ch, B_ch, C_ch);
  k_scan    <<<768, 256, 0, stream>>>(u_chA, u_chT, tdt_ch, B_ch, C_ch,
                                      Alog1, Alog2, D1, D2,
                                      dtw1, dtb1, dtw2, dtb2, y_px);
  k_mergeout<<<dim3(LL / 16, BN), 256, 0, stream>>>(y_px, sq,
                                                    fc1_w1, fc1_w2, fc2_w1, fc2_w2,
                                                    n1g, n1b, n2g, n2b,
                                                    wout, (float*)d_out);
}

// Round 13
// 173.966 us; speedup vs baseline: 1.4112x; 1.0358x over previous
//
#include <hip/hip_runtime.h>
#include <math.h>

#define BN   2
#define CIN  96
#define HH   40
#define WW   40
#define LL   1600
#define DIN  192
#define NS   16
#define RR   6
#define KK   4
#define CH   25   // chunk length per lane (LL/64)

__device__ __forceinline__ float sigmoidf_(float x){ return 1.0f/(1.0f+expf(-x)); }
__device__ __forceinline__ float softplus_fast(float x){
  return x > 20.0f ? x : __logf(1.0f + __expf(x));
}

// p[i] = R^(i+1) for i=0..15, log-depth tree (depth ~4, 15 muls)
__device__ __forceinline__ void pow_tree(float R, float* p){
  float R2 = R * R;
  float R4 = R2 * R2;
  float R8 = R4 * R4;
  p[0]  = R;        p[1]  = R2;       p[2]  = R2 * R;   p[3]  = R4;
  p[4]  = R4 * R;   p[5]  = R4 * R2;  p[6]  = R4 * p[2];p[7]  = R8;
  p[8]  = R8 * R;   p[9]  = R8 * R2;  p[10] = R8 * p[2];p[11] = R8 * R4;
  p[12] = R8 * p[4];p[13] = R8 * p[5];p[14] = R8 * p[6];p[15] = R8 * R8;
}

// ---------------- K1: in_proj (1x1) for both modalities ----------------
// grid: (L/16, 2*B), block 256. xproj layout [mb][o][p]
__global__ void k_inproj(const float* __restrict__ x_rgb, const float* __restrict__ x_e,
                         const float* __restrict__ w_rgb, const float* __restrict__ w_e,
                         float* __restrict__ xproj){
  __shared__ float xin[16][100];          // [px][c], padded row
  int l0 = blockIdx.x * 16;
  int mb = blockIdx.y;                    // m*BN + b
  int m = mb / BN, b = mb % BN;
  const float* xsrc = (m == 0 ? x_rgb : x_e) + (size_t)b * CIN * LL;
  const float* w    = (m == 0 ? w_rgb : w_e);
  for (int idx = threadIdx.x; idx < CIN * 16; idx += 256){
    int c = idx >> 4, px = idx & 15;
    xin[px][c] = xsrc[c * LL + l0 + px];
  }
  __syncthreads();
  int px = threadIdx.x & 15;
  int o0 = (threadIdx.x >> 4) * 12;       // 16 groups x 12 outputs
  float acc[12];
  #pragma unroll
  for (int i = 0; i < 12; ++i) acc[i] = 0.f;
  const float4* xv = reinterpret_cast<const float4*>(xin[px]);
  for (int cc = 0; cc < CIN / 4; ++cc){
    float4 x4 = xv[cc];
    #pragma unroll
    for (int i = 0; i < 12; ++i){
      float4 w4 = *reinterpret_cast<const float4*>(w + (o0 + i) * CIN + cc * 4);
      acc[i] += w4.x * x4.x + w4.y * x4.y + w4.z * x4.z + w4.w * x4.w;
    }
  }
  #pragma unroll
  for (int i = 0; i < 12; ++i)
    xproj[((size_t)mb * DIN + o0 + i) * LL + l0 + px] = acc[i];
}

// ------ K2: depthwise 3x3 + bias + SiLU; emit x_act, x_actT, u_ch, SE mean ---
// grid: (DIN, 2*B), block 256
__global__ void k_conv(const float* __restrict__ xproj, const float* __restrict__ conv_w,
                       const float* __restrict__ conv_b, float* __restrict__ x_act,
                       float* __restrict__ x_actT, float* __restrict__ u_chA,
                       float* __restrict__ u_chT, float* __restrict__ sq){
  __shared__ float pl[LL];
  __shared__ float sact[LL + HH];    // padded: index l + l/40
  __shared__ float red[4];
  int d  = blockIdx.x;
  int mb = blockIdx.y;
  const float* src = xproj + ((size_t)mb * DIN + d) * LL;
  for (int p = threadIdx.x; p < LL; p += blockDim.x) pl[p] = src[p];
  __syncthreads();
  float cw[9];
  #pragma unroll
  for (int j = 0; j < 9; ++j) cw[j] = conv_w[d * 9 + j];
  float bias = conv_b[d];
  float* dst = x_act + ((size_t)mb * DIN + d) * LL;
  float lsum = 0.f;
  for (int p = threadIdx.x; p < LL; p += blockDim.x){
    int py = p / WW, px = p % WW;
    float acc = bias;
    #pragma unroll
    for (int dy = -1; dy <= 1; ++dy){
      int yy = py + dy;
      if (yy < 0 || yy >= HH) continue;
      #pragma unroll
      for (int dx = -1; dx <= 1; ++dx){
        int xx = px + dx;
        if (xx < 0 || xx >= WW) continue;
        acc += cw[(dy + 1) * 3 + (dx + 1)] * pl[yy * WW + xx];
      }
    }
    float s = acc * sigmoidf_(acc);
    dst[p] = s;
    sact[p + p / WW] = s;
    lsum += s;
  }
  #pragma unroll
  for (int off = 32; off; off >>= 1) lsum += __shfl_down(lsum, off);
  if ((threadIdx.x & 63) == 0) red[threadIdx.x >> 6] = lsum;
  __syncthreads();
  if (threadIdx.x == 0)
    sq[mb * DIN + d] = (red[0] + red[1] + red[2] + red[3]) * (1.0f / LL);
  size_t po = ((size_t)mb * DIN + d) * LL;
  float* dstT = x_actT + po;
  float* uA   = u_chA + po;
  float* uT   = u_chT + po;
  for (int q = threadIdx.x; q < LL; q += blockDim.x){
    int lt = (q % WW) * WW + q / WW;
    dstT[q] = sact[lt + lt / WW];
    int l = (q & 63) * CH + (q >> 6);
    uA[q] = sact[l + l / WW];
    int pt = (l % WW) * WW + l / WW;
    uT[q] = sact[pt + pt / WW];
  }
}

// ------ K3: x_proj — register-blocked, no LDS staging --------------------
// grid: (L/64, K, 2*B), block 256. Each wave = one output group (weights
// wave-uniform -> scalar loads); each thread = one pixel x 8-10 outputs.
__global__ void k_xproj(const float* __restrict__ x_act, const float* __restrict__ x_actT,
                        const float* __restrict__ xp1, const float* __restrict__ xp2,
                        float* __restrict__ tdt_ch, float* __restrict__ B_ch,
                        float* __restrict__ C_ch){
  int l0 = blockIdx.x * 64;
  int k  = blockIdx.y;
  int mb = blockIdx.z; int m = mb / BN;
  const float* xw = (m == 0 ? xp1 : xp2) + k * 38 * DIN;
  const float* xa = ((k & 1) ? x_actT : x_act) + (size_t)mb * DIN * LL;
  bool rev = (k >= 2);
  int ll = threadIdx.x & 63;
  int g  = threadIdx.x >> 6;            // wave id = output group
  int c0 = g * 10;                      // groups: 10,10,10,8 outputs
  int l  = l0 + ll; if (rev) l = LL - 1 - l;
  const float* xcol = xa + l;           // xcol[dd*LL]
  float acc[10];
  #pragma unroll
  for (int i = 0; i < 10; ++i) acc[i] = 0.f;
  if (g < 3){
    for (int dd = 0; dd < DIN; ++dd){
      float xv = xcol[(size_t)dd * LL];
      #pragma unroll
      for (int i = 0; i < 10; ++i) acc[i] += xw[(c0 + i) * DIN + dd] * xv;
    }
  } else {
    for (int dd = 0; dd < DIN; ++dd){
      float xv = xcol[(size_t)dd * LL];
      #pragma unroll
      for (int i = 0; i < 8; ++i) acc[i] += xw[(c0 + i) * DIN + dd] * xv;
    }
  }
  int mbk = mb * KK + k;
  int lq = l0 + ll;                     // scan position (un-reversed)
  int q = (lq % CH) * 64 + lq / CH;     // chunk-order index
  int nc = (g < 3) ? 10 : 8;
  for (int i = 0; i < nc; ++i){
    int c = c0 + i;
    float v = acc[i];
    if (c < RR){
      tdt_ch[((size_t)mbk * RR + c) * LL + q] = v;
    } else if (c < RR + NS){
      int n = c - RR;
      B_ch[(((size_t)mbk * 4 + (n >> 2)) * LL + q) * 4 + (n & 3)] = v;
    } else {
      int n = c - RR - NS;
      C_ch[(((size_t)mbk * 4 + (n >> 2)) * LL + q) * 4 + (n & 3)] = v;
    }
  }
}

// ---------------- K4: chunked parallel selective scan -------------------
// ONE WAVE PER CHAIN, 16 states in registers, wave-private LDS (no barrier,
// no atomic). pow_tree exps, split accumulators. ystage UNPADDED: scan-order
// stores are stride-25 (coprime 32 -> free); only k-odd flush pays ~10-way.
// grid: 768 blocks of 256 (4 chains/block). y_px layout [chain][pixel]
__global__ void __launch_bounds__(256, 3) k_scan(
    const float* __restrict__ u_chA, const float* __restrict__ u_chT,
    const float* __restrict__ tdt_all, const float* __restrict__ B_ch,
    const float* __restrict__ C_ch,
    const float* __restrict__ Alog1, const float* __restrict__ Alog2,
    const float* __restrict__ D1, const float* __restrict__ D2,
    const float* __restrict__ dtw1, const float* __restrict__ dtb1,
    const float* __restrict__ dtw2, const float* __restrict__ dtb2,
    float* __restrict__ y_px){
  __shared__ float ystage[4][LL];           // [wave][l]  (wave-private)
  __shared__ float dt_lds[4][LL];           // [wave][q]  (wave-private)
  int wv   = threadIdx.x >> 6;
  int lane = threadIdx.x & 63;
  int chain = blockIdx.x * 4 + wv;          // = (mb*KK + k)*DIN + d
  int d   = chain % DIN;
  int mbk = chain / DIN;
  int k   = mbk % KK;
  int mb  = mbk / KK;
  int m = mb / BN, b = mb % BN;
  int kd = k * DIN + d;
  bool rev = (k >= 2);

  const float* Alog = (m == 0 ? Alog1 : Alog2) + kd * NS;
  float An[NS];
  bool fastA = true;
  #pragma unroll
  for (int n = 0; n < NS; ++n){
    An[n] = -__expf(Alog[n]);
    fastA = fastA && (fabsf(An[n] + (float)(n + 1)) <= 1e-4f * (float)(n + 1));
  }
  float Dv = (m == 0 ? D2 : D1)[kd];
  const float* dtw = (m == 0 ? dtw1 : dtw2) + kd * RR;
  float w0 = dtw[0], w1 = dtw[1], w2 = dtw[2], w3 = dtw[3], w4 = dtw[4], w5 = dtw[5];
  float dbias = (m == 0 ? dtb1 : dtb2)[kd];

  const float* t0 = tdt_all + (size_t)mbk * RR * LL;    // [r][q] rows
  for (int s = 0; s < CH; ++s){
    int q = s * 64 + lane;
    float dtpre = w0 * t0[q] + w1 * t0[LL + q] + w2 * t0[2 * LL + q]
                + w3 * t0[3 * LL + q] + w4 * t0[4 * LL + q] + w5 * t0[5 * LL + q] + dbias;
    dt_lds[wv][q] = softplus_fast(dtpre);
  }

  const float4* B0 = reinterpret_cast<const float4*>(B_ch) + (size_t)mbk * 4 * LL;
  int mbk_o = ((1 - m) * BN + b) * KK + k;              // other modality's C
  const float4* C0 = reinterpret_cast<const float4*>(C_ch) + (size_t)mbk_o * 4 * LL;
  const float* urow = ((k & 1) ? u_chT : u_chA) + ((size_t)mb * DIN + d) * LL;

  float h[NS];
  #pragma unroll
  for (int n = 0; n < NS; ++n) h[n] = 0.f;
  float Sdt = 0.f;

  // phase 1: local chunk scan, emit y_local (plain store, single writer)
  if (fastA){
    #pragma unroll 5
    for (int s = 0; s < CH; ++s){
      int q = s * 64 + lane;
      float dt = dt_lds[wv][q];
      Sdt += dt;
      float u  = urow[rev ? (LL - 1 - q) : q];
      float du = dt * u;
      float4 b0 = B0[q], b1 = B0[LL + q], b2 = B0[2 * LL + q], b3 = B0[3 * LL + q];
      float4 c0 = C0[q], c1 = C0[LL + q], c2 = C0[2 * LL + q], c3 = C0[3 * LL + q];
      float Bv[NS] = {b0.x,b0.y,b0.z,b0.w, b1.x,b1.y,b1.z,b1.w,
                      b2.x,b2.y,b2.z,b2.w, b3.x,b3.y,b3.z,b3.w};
      float Cv[NS] = {c0.x,c0.y,c0.z,c0.w, c1.x,c1.y,c1.z,c1.w,
                      c2.x,c2.y,c2.z,c2.w, c3.x,c3.y,c3.z,c3.w};
      float p[NS];
      pow_tree(__expf(-dt), p);         // p[n] = exp(dt*An[n]), depth ~4
      float y0 = Dv * u, y1 = 0.f, y2 = 0.f, y3 = 0.f;
      #pragma unroll
      for (int n = 0; n < NS; ++n){
        h[n] = p[n] * h[n] + du * Bv[n];
        float t = h[n] * Cv[n];
        if      ((n & 3) == 0) y0 += t;
        else if ((n & 3) == 1) y1 += t;
        else if ((n & 3) == 2) y2 += t;
        else                   y3 += t;
      }
      ystage[wv][lane * CH + s] = (y0 + y1) + (y2 + y3);
    }
  } else {
    #pragma unroll 5
    for (int s = 0; s < CH; ++s){
      int q = s * 64 + lane;
      float dt = dt_lds[wv][q];
      Sdt += dt;
      float u  = urow[rev ? (LL - 1 - q) : q];
      float du = dt * u;
      float4 b0 = B0[q], b1 = B0[LL + q], b2 = B0[2 * LL + q], b3 = B0[3 * LL + q];
      float4 c0 = C0[q], c1 = C0[LL + q], c2 = C0[2 * LL + q], c3 = C0[3 * LL + q];
      float Bv[NS] = {b0.x,b0.y,b0.z,b0.w, b1.x,b1.y,b1.z,b1.w,
                      b2.x,b2.y,b2.z,b2.w, b3.x,b3.y,b3.z,b3.w};
      float Cv[NS] = {c0.x,c0.y,c0.z,c0.w, c1.x,c1.y,c1.z,c1.w,
                      c2.x,c2.y,c2.z,c2.w, c3.x,c3.y,c3.z,c3.w};
      float y0 = Dv * u, y1 = 0.f, y2 = 0.f, y3 = 0.f;
      #pragma unroll
      for (int n = 0; n < NS; ++n){
        float dA = __expf(dt * An[n]);
        h[n] = dA * h[n] + du * Bv[n];
        float t = h[n] * Cv[n];
        if      ((n & 3) == 0) y0 += t;
        else if ((n & 3) == 1) y1 += t;
        else if ((n & 3) == 2) y2 += t;
        else                   y3 += t;
      }
      ystage[wv][lane * CH + s] = (y0 + y1) + (y2 + y3);
    }
  }
  float aP[NS];
  if (fastA){
    pow_tree(__expf(-Sdt), aP);
  } else {
    #pragma unroll
    for (int n = 0; n < NS; ++n) aP[n] = __expf(Sdt * An[n]);
  }

  // Kogge-Stone inclusive scan of (aP,h) across 64 lanes (chunk order)
  #pragma unroll
  for (int off = 1; off < 64; off <<= 1){
    #pragma unroll
    for (int n = 0; n < NS; ++n){
      float ap = __shfl_up(aP[n], off);
      float bp = __shfl_up(h[n],  off);
      if (lane >= off){
        h[n]  = aP[n] * bp + h[n];
        aP[n] = aP[n] * ap;
      }
    }
  }
  // carry-in for this chunk = inclusive result of previous lane
  #pragma unroll
  for (int n = 0; n < NS; ++n){
    float v = __shfl_up(h[n], 1);
    h[n] = (lane == 0) ? 0.f : v;      // h[] now holds the carry
  }

  // phase 2: correction pass — ystage[l] += sum_n carry[n]*E_s^(n+1)*C[n]
  if (fastA){
    float cum = 0.f;
    #pragma unroll 5
    for (int s = 0; s < CH; ++s){
      int q = s * 64 + lane;
      cum += dt_lds[wv][q];                    // serial add chain only
      float Rc = __expf(-cum);                 // off the serial chain
      float4 c0 = C0[q], c1 = C0[LL + q], c2 = C0[2 * LL + q], c3 = C0[3 * LL + q];
      float Cv[NS] = {c0.x,c0.y,c0.z,c0.w, c1.x,c1.y,c1.z,c1.w,
                      c2.x,c2.y,c2.z,c2.w, c3.x,c3.y,c3.z,c3.w};
      float p[NS];
      pow_tree(Rc, p);                         // p[n] = exp(An[n]*cum)
      float s0 = 0.f, s1 = 0.f, s2 = 0.f, s3 = 0.f;
      #pragma unroll
      for (int n = 0; n < NS; ++n){
        float t = h[n] * p[n] * Cv[n];
        if      ((n & 3) == 0) s0 += t;
        else if ((n & 3) == 1) s1 += t;
        else if ((n & 3) == 2) s2 += t;
        else                   s3 += t;
      }
      ystage[wv][lane * CH + s] += (s0 + s1) + (s2 + s3);
    }
  } else {
    float cum = 0.f;
    #pragma unroll 5
    for (int s = 0; s < CH; ++s){
      int q = s * 64 + lane;
      cum += dt_lds[wv][q];
      float4 c0 = C0[q], c1 = C0[LL + q], c2 = C0[2 * LL + q], c3 = C0[3 * LL + q];
      float Cv[NS] = {c0.x,c0.y,c0.z,c0.w, c1.x,c1.y,c1.z,c1.w,
                      c2.x,c2.y,c2.z,c2.w, c3.x,c3.y,c3.z,c3.w};
      float s0 = 0.f, s1 = 0.f, s2 = 0.f, s3 = 0.f;
      #pragma unroll
      for (int n = 0; n < NS; ++n){
        float t = h[n] * __expf(cum * An[n]) * Cv[n];
        if      ((n & 3) == 0) s0 += t;
        else if ((n & 3) == 1) s1 += t;
        else if ((n & 3) == 2) s2 += t;
        else                   s3 += t;
      }
      ystage[wv][lane * CH + s] += (s0 + s1) + (s2 + s3);
    }
  }

  // flush OWN ystage in PIXEL order (no barrier — wave-private buffer).
  float* yo = y_px + (size_t)chain * LL;
  for (int qq = lane; qq < LL; qq += 64){
    int l;
    if      (k == 0) l = qq;
    else if (k == 1) l = (qq % WW) * WW + qq / WW;
    else if (k == 2) l = LL - 1 - qq;
    else             { int qt = (qq % WW) * WW + qq / WW; l = LL - 1 - qt; }
    yo[qq] = ystage[wv][l];
  }
}

// ------ K5: FUSED merge + LayerNorm + cross SE + out_proj ---------------
// grid: (L/8, B), block 256 — 400 blocks (was 200, CUs under-filled).
__global__ void __launch_bounds__(256) k_mergeout(
    const float* __restrict__ y_px, const float* __restrict__ sq,
    const float* __restrict__ fc1_w1, const float* __restrict__ fc1_w2,
    const float* __restrict__ fc2_w1, const float* __restrict__ fc2_w2,
    const float* __restrict__ n1g, const float* __restrict__ n1b,
    const float* __restrict__ n2g, const float* __restrict__ n2b,
    const float* __restrict__ wout, float* __restrict__ out){
  __shared__ float acc[2 * DIN][9];       // [(m*DIN+dd)][pp]
  __shared__ float yt[8][388];            // [pp][m*DIN+dd], GEMM operand
  __shared__ float ps[2][8][16], ps2[2][8][16];
  __shared__ float mu_s[2][8], inv_s[2][8];
  __shared__ float sqs[2][DIN];           // sq of the OTHER modality, per m
  __shared__ float hid[2][12];
  __shared__ float exc_s[2][DIN];
  int p0 = blockIdx.x * 8;
  int b  = blockIdx.y;
  int tid = threadIdx.x;
  // region A: 4-direction merged sums + sq loads
  for (int idx = tid; idx < 2 * DIN * 8; idx += 256){
    int pp = idx & 7, row = idx >> 3;
    int mm = (row >= DIN), dd = row - mm * DIN;
    const float* yb = y_px + ((size_t)(mm * BN + b) * KK * DIN + dd) * LL + p0 + pp;
    acc[row][pp] = yb[0] + yb[(size_t)DIN * LL]
                 + yb[2 * (size_t)DIN * LL] + yb[3 * (size_t)DIN * LL];
  }
  for (int i = tid; i < 2 * DIN; i += 256){
    int mm = (i >= DIN), dd = i - mm * DIN;
    sqs[mm][dd] = sq[((1 - mm) * BN + b) * DIN + dd];
  }
  __syncthreads();
  // region B: SE hidden layer (24 thr) + LN stats partials (all 256)
  if (tid < 24){
    int mm = tid / 12, j = tid - mm * 12;
    const float* w1 = (mm == 1 ? fc1_w1 : fc2_w1);
    float a = 0.f;
    for (int cch = 0; cch < DIN; ++cch) a += w1[j * DIN + cch] * sqs[mm][cch];
    hid[mm][j] = a * sigmoidf_(a);
  }
  {
    int pp = tid & 7, mm = (tid >> 3) & 1, g = tid >> 4;   // g in 0..15
    float s = 0.f, s2 = 0.f;
    #pragma unroll 4
    for (int j = 0; j < 12; ++j){
      float v = acc[mm * DIN + g * 12 + j][pp];
      s += v; s2 += v * v;
    }
    ps[mm][pp][g] = s; ps2[mm][pp][g] = s2;
  }
  __syncthreads();
  // region C: LN stats final (16 thr) + SE excitation (all, strided)
  if (tid < 16){
    int mm = tid >> 3, pp = tid & 7;
    float s = 0.f, s2 = 0.f;
    #pragma unroll
    for (int g = 0; g < 16; ++g){ s += ps[mm][pp][g]; s2 += ps2[mm][pp][g]; }
    float mu  = s * (1.0f / DIN);
    float var = s2 * (1.0f / DIN) - mu * mu;
    mu_s[mm][pp] = mu; inv_s[mm][pp] = rsqrtf(var + 1e-5f);
  }
  for (int i = tid; i < 2 * DIN; i += 256){
    int mm = (i >= DIN), dd = i - mm * DIN;
    const float* w2 = (mm == 1 ? fc1_w2 : fc2_w2);
    float e = 0.f;
    #pragma unroll
    for (int j = 0; j < 12; ++j) e += w2[dd * 12 + j] * hid[mm][j];
    exc_s[mm][dd] = sigmoidf_(e);
  }
  __syncthreads();
  // region D: normalize + SE scale into yt
  for (int idx = tid; idx < 2 * DIN * 8; idx += 256){
    int pp = idx & 7, row = idx >> 3;
    int mm = (row >= DIN), dd = row - mm * DIN;
    float g  = (mm ? n2g : n1g)[dd];
    float bb = (mm ? n2b : n1b)[dd];
    float v = (acc[row][pp] - mu_s[mm][pp]) * inv_s[mm][pp] * g + bb;
    yt[pp][row] = v * exc_s[mm][dd];
  }
  __syncthreads();
  // region E: out_proj 96x384 from LDS (32 groups x 3 outputs)
  int pp = tid & 7;
  int o0 = (tid >> 3) * 3;
  float a3[3] = {0.f, 0.f, 0.f};
  const float4* yv = reinterpret_cast<const float4*>(yt[pp]);
  for (int cc = 0; cc < 96; ++cc){
    float4 x4 = yv[cc];
    #pragma unroll
    for (int i = 0; i < 3; ++i){
      float4 w4 = *reinterpret_cast<const float4*>(wout + (o0 + i) * 2 * DIN + cc * 4);
      a3[i] += w4.x * x4.x + w4.y * x4.y + w4.z * x4.z + w4.w * x4.w;
    }
  }
  #pragma unroll
  for (int i = 0; i < 3; ++i)
    out[((size_t)b * CIN + o0 + i) * LL + p0 + pp] = a3[i];
}

extern "C" void kernel_launch(void* const* d_in, const int* in_sizes, int n_in,
                              void* d_out, int out_size, void* d_ws, size_t ws_size,
                              hipStream_t stream){
  const float* x_rgb   = (const float*)d_in[0];
  const float* x_e     = (const float*)d_in[1];
  const float* in_w    = (const float*)d_in[2];
  const float* in_mx_w = (const float*)d_in[3];
  const float* conv_w  = (const float*)d_in[4];
  const float* conv_b  = (const float*)d_in[5];
  const float* xp1     = (const float*)d_in[6];
  const float* xp2     = (const float*)d_in[7];
  const float* dtw1    = (const float*)d_in[8];
  const float* dtb1    = (const float*)d_in[9];
  const float* dtw2    = (const float*)d_in[10];
  const float* dtb2    = (const float*)d_in[11];
  const float* Alog1   = (const float*)d_in[12];
  const float* Alog2   = (const float*)d_in[13];
  const float* D1      = (const float*)d_in[14];
  const float* D2      = (const float*)d_in[15];
  const float* n1g     = (const float*)d_in[16];
  const float* n1b     = (const float*)d_in[17];
  const float* n2g     = (const float*)d_in[18];
  const float* n2b     = (const float*)d_in[19];
  const float* fc1_w1  = (const float*)d_in[20];
  const float* fc1_w2  = (const float*)d_in[21];
  const float* fc2_w1  = (const float*)d_in[22];
  const float* fc2_w2  = (const float*)d_in[23];
  const float* wout    = (const float*)d_in[24];

  float* ws = (float*)d_ws;
  float* u_chA   = ws;
  float* u_chT   = ws + 1228800;
  float* x_act   = ws + 2457600;
  float* x_actT  = ws + 3686400;
  float* xproj   = ws + 4915200;
  float* y_px    = ws + 6144000;
  float* B_ch    = ws + 11059200;
  float* C_ch    = ws + 11468800;
  float* tdt_ch  = ws + 11878400;
  float* sq      = ws + 12032000;

  k_inproj  <<<dim3(LL / 16, 2 * BN), 256, 0, stream>>>(x_rgb, x_e, in_w, in_mx_w, xproj);
  k_conv    <<<dim3(DIN, 2 * BN), 256, 0, stream>>>(xproj, conv_w, conv_b,
                                                    x_act, x_actT, u_chA, u_chT, sq);
  k_xproj   <<<dim3(LL / 64, KK, 2 * BN), 256, 0, stream>>>(x_act, x_actT, xp1, xp2,
                                                            tdt_ch, B_ch, C_ch);
  k_scan    <<<768, 256, 0, stream>>>(u_chA, u_chT, tdt_ch, B_ch, C_ch,
                                      Alog1, Alog2, D1, D2,
                                      dtw1, dtb1, dtw2, dtb2, y_px);
  k_mergeout<<<dim3(LL / 8, BN), 256, 0, stream>>>(y_px, sq,
                                                   fc1_w1, fc1_w2, fc2_w1, fc2_w2,
                                                   n1g, n1b, n2g, n2b,
                                                   wout, (float*)d_out);
}

// Round 14
// 167.966 us; speedup vs baseline: 1.4616x; 1.0357x over previous
//
#include <hip/hip_runtime.h>
#include <math.h>

#define BN   2
#define CIN  96
#define HH   40
#define WW   40
#define LL   1600
#define DIN  192
#define NS   16
#define RR   6
#define KK   4
#define CH   25   // chunk length per lane (LL/64)

__device__ __forceinline__ float sigmoidf_(float x){ return 1.0f/(1.0f+expf(-x)); }
__device__ __forceinline__ float softplus_fast(float x){
  return x > 20.0f ? x : __logf(1.0f + __expf(x));
}

// p[i] = R^(i+1) for i=0..15, log-depth tree (depth ~4, 15 muls)
__device__ __forceinline__ void pow_tree(float R, float* p){
  float R2 = R * R;
  float R4 = R2 * R2;
  float R8 = R4 * R4;
  p[0]  = R;        p[1]  = R2;       p[2]  = R2 * R;   p[3]  = R4;
  p[4]  = R4 * R;   p[5]  = R4 * R2;  p[6]  = R4 * p[2];p[7]  = R8;
  p[8]  = R8 * R;   p[9]  = R8 * R2;  p[10] = R8 * p[2];p[11] = R8 * R4;
  p[12] = R8 * p[4];p[13] = R8 * p[5];p[14] = R8 * p[6];p[15] = R8 * R8;
}

// ---------------- K1: in_proj (1x1) for both modalities ----------------
// grid: (L/16, 2*B), block 256. xproj layout [mb][o][p]
__global__ void k_inproj(const float* __restrict__ x_rgb, const float* __restrict__ x_e,
                         const float* __restrict__ w_rgb, const float* __restrict__ w_e,
                         float* __restrict__ xproj){
  __shared__ float xin[16][100];          // [px][c], padded row
  int l0 = blockIdx.x * 16;
  int mb = blockIdx.y;                    // m*BN + b
  int m = mb / BN, b = mb % BN;
  const float* xsrc = (m == 0 ? x_rgb : x_e) + (size_t)b * CIN * LL;
  const float* w    = (m == 0 ? w_rgb : w_e);
  for (int idx = threadIdx.x; idx < CIN * 16; idx += 256){
    int c = idx >> 4, px = idx & 15;
    xin[px][c] = xsrc[c * LL + l0 + px];
  }
  __syncthreads();
  int px = threadIdx.x & 15;
  int o0 = (threadIdx.x >> 4) * 12;       // 16 groups x 12 outputs
  float acc[12];
  #pragma unroll
  for (int i = 0; i < 12; ++i) acc[i] = 0.f;
  const float4* xv = reinterpret_cast<const float4*>(xin[px]);
  for (int cc = 0; cc < CIN / 4; ++cc){
    float4 x4 = xv[cc];
    #pragma unroll
    for (int i = 0; i < 12; ++i){
      float4 w4 = *reinterpret_cast<const float4*>(w + (o0 + i) * CIN + cc * 4);
      acc[i] += w4.x * x4.x + w4.y * x4.y + w4.z * x4.z + w4.w * x4.w;
    }
  }
  #pragma unroll
  for (int i = 0; i < 12; ++i)
    xproj[((size_t)mb * DIN + o0 + i) * LL + l0 + px] = acc[i];
}

// ------ K2: depthwise 3x3 + bias + SiLU; emit x_act, x_actT, u_ch, SE mean ---
// grid: (DIN, 2*B), block 256
__global__ void k_conv(const float* __restrict__ xproj, const float* __restrict__ conv_w,
                       const float* __restrict__ conv_b, float* __restrict__ x_act,
                       float* __restrict__ x_actT, float* __restrict__ u_chA,
                       float* __restrict__ u_chT, float* __restrict__ sq){
  __shared__ float pl[LL];
  __shared__ float sact[LL + HH];    // padded: index l + l/40
  __shared__ float red[4];
  int d  = blockIdx.x;
  int mb = blockIdx.y;
  const float* src = xproj + ((size_t)mb * DIN + d) * LL;
  for (int p = threadIdx.x; p < LL; p += blockDim.x) pl[p] = src[p];
  __syncthreads();
  float cw[9];
  #pragma unroll
  for (int j = 0; j < 9; ++j) cw[j] = conv_w[d * 9 + j];
  float bias = conv_b[d];
  float* dst = x_act + ((size_t)mb * DIN + d) * LL;
  float lsum = 0.f;
  for (int p = threadIdx.x; p < LL; p += blockDim.x){
    int py = p / WW, px = p % WW;
    float acc = bias;
    #pragma unroll
    for (int dy = -1; dy <= 1; ++dy){
      int yy = py + dy;
      if (yy < 0 || yy >= HH) continue;
      #pragma unroll
      for (int dx = -1; dx <= 1; ++dx){
        int xx = px + dx;
        if (xx < 0 || xx >= WW) continue;
        acc += cw[(dy + 1) * 3 + (dx + 1)] * pl[yy * WW + xx];
      }
    }
    float s = acc * sigmoidf_(acc);
    dst[p] = s;
    sact[p + p / WW] = s;
    lsum += s;
  }
  #pragma unroll
  for (int off = 32; off; off >>= 1) lsum += __shfl_down(lsum, off);
  if ((threadIdx.x & 63) == 0) red[threadIdx.x >> 6] = lsum;
  __syncthreads();
  if (threadIdx.x == 0)
    sq[mb * DIN + d] = (red[0] + red[1] + red[2] + red[3]) * (1.0f / LL);
  size_t po = ((size_t)mb * DIN + d) * LL;
  float* dstT = x_actT + po;
  float* uA   = u_chA + po;
  float* uT   = u_chT + po;
  for (int q = threadIdx.x; q < LL; q += blockDim.x){
    int lt = (q % WW) * WW + q / WW;
    dstT[q] = sact[lt + lt / WW];
    int l = (q & 63) * CH + (q >> 6);
    uA[q] = sact[l + l / WW];
    int pt = (l % WW) * WW + l / WW;
    uT[q] = sact[pt + pt / WW];
  }
}

// ------ K3: x_proj — register-blocked, no LDS staging --------------------
// grid: (L/64, K, 2*B), block 256. Each wave = one output group (weights
// wave-uniform -> scalar loads); each thread = one pixel x 8-10 outputs.
__global__ void k_xproj(const float* __restrict__ x_act, const float* __restrict__ x_actT,
                        const float* __restrict__ xp1, const float* __restrict__ xp2,
                        float* __restrict__ tdt_ch, float* __restrict__ B_ch,
                        float* __restrict__ C_ch){
  int l0 = blockIdx.x * 64;
  int k  = blockIdx.y;
  int mb = blockIdx.z; int m = mb / BN;
  const float* xw = (m == 0 ? xp1 : xp2) + k * 38 * DIN;
  const float* xa = ((k & 1) ? x_actT : x_act) + (size_t)mb * DIN * LL;
  bool rev = (k >= 2);
  int ll = threadIdx.x & 63;
  int g  = threadIdx.x >> 6;            // wave id = output group
  int c0 = g * 10;                      // groups: 10,10,10,8 outputs
  int l  = l0 + ll; if (rev) l = LL - 1 - l;
  const float* xcol = xa + l;           // xcol[dd*LL]
  float acc[10];
  #pragma unroll
  for (int i = 0; i < 10; ++i) acc[i] = 0.f;
  if (g < 3){
    for (int dd = 0; dd < DIN; ++dd){
      float xv = xcol[(size_t)dd * LL];
      #pragma unroll
      for (int i = 0; i < 10; ++i) acc[i] += xw[(c0 + i) * DIN + dd] * xv;
    }
  } else {
    for (int dd = 0; dd < DIN; ++dd){
      float xv = xcol[(size_t)dd * LL];
      #pragma unroll
      for (int i = 0; i < 8; ++i) acc[i] += xw[(c0 + i) * DIN + dd] * xv;
    }
  }
  int mbk = mb * KK + k;
  int lq = l0 + ll;                     // scan position (un-reversed)
  int q = (lq % CH) * 64 + lq / CH;     // chunk-order index
  int nc = (g < 3) ? 10 : 8;
  for (int i = 0; i < nc; ++i){
    int c = c0 + i;
    float v = acc[i];
    if (c < RR){
      tdt_ch[((size_t)mbk * RR + c) * LL + q] = v;
    } else if (c < RR + NS){
      int n = c - RR;
      B_ch[(((size_t)mbk * 4 + (n >> 2)) * LL + q) * 4 + (n & 3)] = v;
    } else {
      int n = c - RR - NS;
      C_ch[(((size_t)mbk * 4 + (n >> 2)) * LL + q) * 4 + (n & 3)] = v;
    }
  }
}

// ---------------- K4: chunked parallel selective scan -------------------
// ONE WAVE PER CHAIN, 16 states in registers, wave-private LDS (no barrier,
// no atomic). This round: REGISTER DOUBLE-BUFFERED loads (B/C/u/dt for step
// s+1 issued before computing step s) + half-precision ystage (LDS 51->38KB,
// 4 blocks/CU) with launch_bounds(256,4) giving the prefetch its registers.
// grid: 768 blocks of 256 (4 chains/block). y_px layout [chain][pixel]
__global__ void __launch_bounds__(256, 4) k_scan(
    const float* __restrict__ u_chA, const float* __restrict__ u_chT,
    const float* __restrict__ tdt_all, const float* __restrict__ B_ch,
    const float* __restrict__ C_ch,
    const float* __restrict__ Alog1, const float* __restrict__ Alog2,
    const float* __restrict__ D1, const float* __restrict__ D2,
    const float* __restrict__ dtw1, const float* __restrict__ dtb1,
    const float* __restrict__ dtw2, const float* __restrict__ dtb2,
    float* __restrict__ y_px){
  __shared__ _Float16 ysth[4][LL];          // [wave][l]  (wave-private)
  __shared__ float dt_lds[4][LL];           // [wave][q]  (wave-private)
  int wv   = threadIdx.x >> 6;
  int lane = threadIdx.x & 63;
  int chain = blockIdx.x * 4 + wv;          // = (mb*KK + k)*DIN + d
  int d   = chain % DIN;
  int mbk = chain / DIN;
  int k   = mbk % KK;
  int mb  = mbk / KK;
  int m = mb / BN, b = mb % BN;
  int kd = k * DIN + d;
  bool rev = (k >= 2);

  const float* Alog = (m == 0 ? Alog1 : Alog2) + kd * NS;
  float An[NS];
  bool fastA = true;
  #pragma unroll
  for (int n = 0; n < NS; ++n){
    An[n] = -__expf(Alog[n]);
    fastA = fastA && (fabsf(An[n] + (float)(n + 1)) <= 1e-4f * (float)(n + 1));
  }
  float Dv = (m == 0 ? D2 : D1)[kd];
  const float* dtw = (m == 0 ? dtw1 : dtw2) + kd * RR;
  float w0 = dtw[0], w1 = dtw[1], w2 = dtw[2], w3 = dtw[3], w4 = dtw[4], w5 = dtw[5];
  float dbias = (m == 0 ? dtb1 : dtb2)[kd];

  const float* t0 = tdt_all + (size_t)mbk * RR * LL;    // [r][q] rows
  for (int s = 0; s < CH; ++s){
    int q = s * 64 + lane;
    float dtpre = w0 * t0[q] + w1 * t0[LL + q] + w2 * t0[2 * LL + q]
                + w3 * t0[3 * LL + q] + w4 * t0[4 * LL + q] + w5 * t0[5 * LL + q] + dbias;
    dt_lds[wv][q] = softplus_fast(dtpre);
  }

  const float4* B0 = reinterpret_cast<const float4*>(B_ch) + (size_t)mbk * 4 * LL;
  int mbk_o = ((1 - m) * BN + b) * KK + k;              // other modality's C
  const float4* C0 = reinterpret_cast<const float4*>(C_ch) + (size_t)mbk_o * 4 * LL;
  const float* urow = ((k & 1) ? u_chT : u_chA) + ((size_t)mb * DIN + d) * LL;

  float h[NS];
  #pragma unroll
  for (int n = 0; n < NS; ++n) h[n] = 0.f;
  float Sdt = 0.f;

  // phase 1: local chunk scan with register double-buffered loads
  if (fastA){
    float4 bP[4], cP[4]; float uP, dtP;
    {
      int q0 = lane;
      dtP = dt_lds[wv][q0];
      uP  = urow[rev ? (LL - 1 - q0) : q0];
      bP[0]=B0[q0]; bP[1]=B0[LL+q0]; bP[2]=B0[2*LL+q0]; bP[3]=B0[3*LL+q0];
      cP[0]=C0[q0]; cP[1]=C0[LL+q0]; cP[2]=C0[2*LL+q0]; cP[3]=C0[3*LL+q0];
    }
    #pragma unroll 5
    for (int s = 0; s < CH; ++s){
      float dt = dtP, u = uP;
      float4 b0=bP[0], b1=bP[1], b2=bP[2], b3=bP[3];
      float4 c0=cP[0], c1=cP[1], c2=cP[2], c3=cP[3];
      if (s + 1 < CH){
        int q1 = (s + 1) * 64 + lane;
        dtP = dt_lds[wv][q1];
        uP  = urow[rev ? (LL - 1 - q1) : q1];
        bP[0]=B0[q1]; bP[1]=B0[LL+q1]; bP[2]=B0[2*LL+q1]; bP[3]=B0[3*LL+q1];
        cP[0]=C0[q1]; cP[1]=C0[LL+q1]; cP[2]=C0[2*LL+q1]; cP[3]=C0[3*LL+q1];
      }
      Sdt += dt;
      float du = dt * u;
      float Bv[NS] = {b0.x,b0.y,b0.z,b0.w, b1.x,b1.y,b1.z,b1.w,
                      b2.x,b2.y,b2.z,b2.w, b3.x,b3.y,b3.z,b3.w};
      float Cv[NS] = {c0.x,c0.y,c0.z,c0.w, c1.x,c1.y,c1.z,c1.w,
                      c2.x,c2.y,c2.z,c2.w, c3.x,c3.y,c3.z,c3.w};
      float p[NS];
      pow_tree(__expf(-dt), p);         // p[n] = exp(dt*An[n]), depth ~4
      float y0 = Dv * u, y1 = 0.f, y2 = 0.f, y3 = 0.f;
      #pragma unroll
      for (int n = 0; n < NS; ++n){
        h[n] = p[n] * h[n] + du * Bv[n];
        float t = h[n] * Cv[n];
        if      ((n & 3) == 0) y0 += t;
        else if ((n & 3) == 1) y1 += t;
        else if ((n & 3) == 2) y2 += t;
        else                   y3 += t;
      }
      ysth[wv][lane * CH + s] = (_Float16)((y0 + y1) + (y2 + y3));
    }
  } else {
    #pragma unroll 5
    for (int s = 0; s < CH; ++s){
      int q = s * 64 + lane;
      float dt = dt_lds[wv][q];
      Sdt += dt;
      float u  = urow[rev ? (LL - 1 - q) : q];
      float du = dt * u;
      float4 b0 = B0[q], b1 = B0[LL + q], b2 = B0[2 * LL + q], b3 = B0[3 * LL + q];
      float4 c0 = C0[q], c1 = C0[LL + q], c2 = C0[2 * LL + q], c3 = C0[3 * LL + q];
      float Bv[NS] = {b0.x,b0.y,b0.z,b0.w, b1.x,b1.y,b1.z,b1.w,
                      b2.x,b2.y,b2.z,b2.w, b3.x,b3.y,b3.z,b3.w};
      float Cv[NS] = {c0.x,c0.y,c0.z,c0.w, c1.x,c1.y,c1.z,c1.w,
                      c2.x,c2.y,c2.z,c2.w, c3.x,c3.y,c3.z,c3.w};
      float y0 = Dv * u, y1 = 0.f, y2 = 0.f, y3 = 0.f;
      #pragma unroll
      for (int n = 0; n < NS; ++n){
        float dA = __expf(dt * An[n]);
        h[n] = dA * h[n] + du * Bv[n];
        float t = h[n] * Cv[n];
        if      ((n & 3) == 0) y0 += t;
        else if ((n & 3) == 1) y1 += t;
        else if ((n & 3) == 2) y2 += t;
        else                   y3 += t;
      }
      ysth[wv][lane * CH + s] = (_Float16)((y0 + y1) + (y2 + y3));
    }
  }
  float aP[NS];
  if (fastA){
    pow_tree(__expf(-Sdt), aP);
  } else {
    #pragma unroll
    for (int n = 0; n < NS; ++n) aP[n] = __expf(Sdt * An[n]);
  }

  // Kogge-Stone inclusive scan of (aP,h) across 64 lanes (chunk order)
  #pragma unroll
  for (int off = 1; off < 64; off <<= 1){
    #pragma unroll
    for (int n = 0; n < NS; ++n){
      float ap = __shfl_up(aP[n], off);
      float bp = __shfl_up(h[n],  off);
      if (lane >= off){
        h[n]  = aP[n] * bp + h[n];
        aP[n] = aP[n] * ap;
      }
    }
  }
  // carry-in for this chunk = inclusive result of previous lane
  #pragma unroll
  for (int n = 0; n < NS; ++n){
    float v = __shfl_up(h[n], 1);
    h[n] = (lane == 0) ? 0.f : v;      // h[] now holds the carry
  }

  // phase 2: correction pass — ysth[l] += sum_n carry[n]*E_s^(n+1)*C[n]
  if (fastA){
    float4 cP[4]; float dtP;
    {
      int q0 = lane;
      dtP = dt_lds[wv][q0];
      cP[0]=C0[q0]; cP[1]=C0[LL+q0]; cP[2]=C0[2*LL+q0]; cP[3]=C0[3*LL+q0];
    }
    float cum = 0.f;
    #pragma unroll 5
    for (int s = 0; s < CH; ++s){
      float dt = dtP;
      float4 c0=cP[0], c1=cP[1], c2=cP[2], c3=cP[3];
      if (s + 1 < CH){
        int q1 = (s + 1) * 64 + lane;
        dtP = dt_lds[wv][q1];
        cP[0]=C0[q1]; cP[1]=C0[LL+q1]; cP[2]=C0[2*LL+q1]; cP[3]=C0[3*LL+q1];
      }
      cum += dt;                               // serial add chain only
      float Rc = __expf(-cum);                 // off the serial chain
      float Cv[NS] = {c0.x,c0.y,c0.z,c0.w, c1.x,c1.y,c1.z,c1.w,
                      c2.x,c2.y,c2.z,c2.w, c3.x,c3.y,c3.z,c3.w};
      float p[NS];
      pow_tree(Rc, p);                         // p[n] = exp(An[n]*cum)
      float s0 = 0.f, s1 = 0.f, s2 = 0.f, s3 = 0.f;
      #pragma unroll
      for (int n = 0; n < NS; ++n){
        float t = h[n] * p[n] * Cv[n];
        if      ((n & 3) == 0) s0 += t;
        else if ((n & 3) == 1) s1 += t;
        else if ((n & 3) == 2) s2 += t;
        else                   s3 += t;
      }
      int li = lane * CH + s;
      ysth[wv][li] = (_Float16)((float)ysth[wv][li] + (s0 + s1) + (s2 + s3));
    }
  } else {
    float cum = 0.f;
    #pragma unroll 5
    for (int s = 0; s < CH; ++s){
      int q = s * 64 + lane;
      cum += dt_lds[wv][q];
      float4 c0 = C0[q], c1 = C0[LL + q], c2 = C0[2 * LL + q], c3 = C0[3 * LL + q];
      float Cv[NS] = {c0.x,c0.y,c0.z,c0.w, c1.x,c1.y,c1.z,c1.w,
                      c2.x,c2.y,c2.z,c2.w, c3.x,c3.y,c3.z,c3.w};
      float s0 = 0.f, s1 = 0.f, s2 = 0.f, s3 = 0.f;
      #pragma unroll
      for (int n = 0; n < NS; ++n){
        float t = h[n] * __expf(cum * An[n]) * Cv[n];
        if      ((n & 3) == 0) s0 += t;
        else if ((n & 3) == 1) s1 += t;
        else if ((n & 3) == 2) s2 += t;
        else                   s3 += t;
      }
      int li = lane * CH + s;
      ysth[wv][li] = (_Float16)((float)ysth[wv][li] + (s0 + s1) + (s2 + s3));
    }
  }

  // flush OWN ystage in PIXEL order (no barrier — wave-private buffer).
  float* yo = y_px + (size_t)chain * LL;
  for (int qq = lane; qq < LL; qq += 64){
    int l;
    if      (k == 0) l = qq;
    else if (k == 1) l = (qq % WW) * WW + qq / WW;
    else if (k == 2) l = LL - 1 - qq;
    else             { int qt = (qq % WW) * WW + qq / WW; l = LL - 1 - qt; }
    yo[qq] = (float)ysth[wv][l];
  }
}

// ------ K5: FUSED merge + LayerNorm + cross SE + out_proj ---------------
// grid: (L/8, B), block 256 — 400 blocks.
__global__ void __launch_bounds__(256) k_mergeout(
    const float* __restrict__ y_px, const float* __restrict__ sq,
    const float* __restrict__ fc1_w1, const float* __restrict__ fc1_w2,
    const float* __restrict__ fc2_w1, const float* __restrict__ fc2_w2,
    const float* __restrict__ n1g, const float* __restrict__ n1b,
    const float* __restrict__ n2g, const float* __restrict__ n2b,
    const float* __restrict__ wout, float* __restrict__ out){
  __shared__ float acc[2 * DIN][9];       // [(m*DIN+dd)][pp]
  __shared__ float yt[8][388];            // [pp][m*DIN+dd], GEMM operand
  __shared__ float ps[2][8][16], ps2[2][8][16];
  __shared__ float mu_s[2][8], inv_s[2][8];
  __shared__ float sqs[2][DIN];           // sq of the OTHER modality, per m
  __shared__ float hid[2][12];
  __shared__ float exc_s[2][DIN];
  int p0 = blockIdx.x * 8;
  int b  = blockIdx.y;
  int tid = threadIdx.x;
  // region A: 4-direction merged sums + sq loads
  for (int idx = tid; idx < 2 * DIN * 8; idx += 256){
    int pp = idx & 7, row = idx >> 3;
    int mm = (row >= DIN), dd = row - mm * DIN;
    const float* yb = y_px + ((size_t)(mm * BN + b) * KK * DIN + dd) * LL + p0 + pp;
    acc[row][pp] = yb[0] + yb[(size_t)DIN * LL]
                 + yb[2 * (size_t)DIN * LL] + yb[3 * (size_t)DIN * LL];
  }
  for (int i = tid; i < 2 * DIN; i += 256){
    int mm = (i >= DIN), dd = i - mm * DIN;
    sqs[mm][dd] = sq[((1 - mm) * BN + b) * DIN + dd];
  }
  __syncthreads();
  // region B: SE hidden layer (24 thr) + LN stats partials (all 256)
  if (tid < 24){
    int mm = tid / 12, j = tid - mm * 12;
    const float* w1 = (mm == 1 ? fc1_w1 : fc2_w1);
    float a = 0.f;
    for (int cch = 0; cch < DIN; ++cch) a += w1[j * DIN + cch] * sqs[mm][cch];
    hid[mm][j] = a * sigmoidf_(a);
  }
  {
    int pp = tid & 7, mm = (tid >> 3) & 1, g = tid >> 4;   // g in 0..15
    float s = 0.f, s2 = 0.f;
    #pragma unroll 4
    for (int j = 0; j < 12; ++j){
      float v = acc[mm * DIN + g * 12 + j][pp];
      s += v; s2 += v * v;
    }
    ps[mm][pp][g] = s; ps2[mm][pp][g] = s2;
  }
  __syncthreads();
  // region C: LN stats final (16 thr) + SE excitation (all, strided)
  if (tid < 16){
    int mm = tid >> 3, pp = tid & 7;
    float s = 0.f, s2 = 0.f;
    #pragma unroll
    for (int g = 0; g < 16; ++g){ s += ps[mm][pp][g]; s2 += ps2[mm][pp][g]; }
    float mu  = s * (1.0f / DIN);
    float var = s2 * (1.0f / DIN) - mu * mu;
    mu_s[mm][pp] = mu; inv_s[mm][pp] = rsqrtf(var + 1e-5f);
  }
  for (int i = tid; i < 2 * DIN; i += 256){
    int mm = (i >= DIN), dd = i - mm * DIN;
    const float* w2 = (mm == 1 ? fc1_w2 : fc2_w2);
    float e = 0.f;
    #pragma unroll
    for (int j = 0; j < 12; ++j) e += w2[dd * 12 + j] * hid[mm][j];
    exc_s[mm][dd] = sigmoidf_(e);
  }
  __syncthreads();
  // region D: normalize + SE scale into yt
  for (int idx = tid; idx < 2 * DIN * 8; idx += 256){
    int pp = idx & 7, row = idx >> 3;
    int mm = (row >= DIN), dd = row - mm * DIN;
    float g  = (mm ? n2g : n1g)[dd];
    float bb = (mm ? n2b : n1b)[dd];
    float v = (acc[row][pp] - mu_s[mm][pp]) * inv_s[mm][pp] * g + bb;
    yt[pp][row] = v * exc_s[mm][dd];
  }
  __syncthreads();
  // region E: out_proj 96x384 from LDS (32 groups x 3 outputs)
  int pp = tid & 7;
  int o0 = (tid >> 3) * 3;
  float a3[3] = {0.f, 0.f, 0.f};
  const float4* yv = reinterpret_cast<const float4*>(yt[pp]);
  for (int cc = 0; cc < 96; ++cc){
    float4 x4 = yv[cc];
    #pragma unroll
    for (int i = 0; i < 3; ++i){
      float4 w4 = *reinterpret_cast<const float4*>(wout + (o0 + i) * 2 * DIN + cc * 4);
      a3[i] += w4.x * x4.x + w4.y * x4.y + w4.z * x4.z + w4.w * x4.w;
    }
  }
  #pragma unroll
  for (int i = 0; i < 3; ++i)
    out[((size_t)b * CIN + o0 + i) * LL + p0 + pp] = a3[i];
}

extern "C" void kernel_launch(void* const* d_in, const int* in_sizes, int n_in,
                              void* d_out, int out_size, void* d_ws, size_t ws_size,
                              hipStream_t stream){
  const float* x_rgb   = (const float*)d_in[0];
  const float* x_e     = (const float*)d_in[1];
  const float* in_w    = (const float*)d_in[2];
  const float* in_mx_w = (const float*)d_in[3];
  const float* conv_w  = (const float*)d_in[4];
  const float* conv_b  = (const float*)d_in[5];
  const float* xp1     = (const float*)d_in[6];
  const float* xp2     = (const float*)d_in[7];
  const float* dtw1    = (const float*)d_in[8];
  const float* dtb1    = (const float*)d_in[9];
  const float* dtw2    = (const float*)d_in[10];
  const float* dtb2    = (const float*)d_in[11];
  const float* Alog1   = (const float*)d_in[12];
  const float* Alog2   = (const float*)d_in[13];
  const float* D1      = (const float*)d_in[14];
  const float* D2      = (const float*)d_in[15];
  const float* n1g     = (const float*)d_in[16];
  const float* n1b     = (const float*)d_in[17];
  const float* n2g     = (const float*)d_in[18];
  const float* n2b     = (const float*)d_in[19];
  const float* fc1_w1  = (const float*)d_in[20];
  const float* fc1_w2  = (const float*)d_in[21];
  const float* fc2_w1  = (const float*)d_in[22];
  const float* fc2_w2  = (const float*)d_in[23];
  const float* wout    = (const float*)d_in[24];

  float* ws = (float*)d_ws;
  float* u_chA   = ws;
  float* u_chT   = ws + 1228800;
  float* x_act   = ws + 2457600;
  float* x_actT  = ws + 3686400;
  float* xproj   = ws + 4915200;
  float* y_px    = ws + 6144000;
  float* B_ch    = ws + 11059200;
  float* C_ch    = ws + 11468800;
  float* tdt_ch  = ws + 11878400;
  float* sq      = ws + 12032000;

  k_inproj  <<<dim3(LL / 16, 2 * BN), 256, 0, stream>>>(x_rgb, x_e, in_w, in_mx_w, xproj);
  k_conv    <<<dim3(DIN, 2 * BN), 256, 0, stream>>>(xproj, conv_w, conv_b,
                                                    x_act, x_actT, u_chA, u_chT, sq);
  k_xproj   <<<dim3(LL / 64, KK, 2 * BN), 256, 0, stream>>>(x_act, x_actT, xp1, xp2,
                                                            tdt_ch, B_ch, C_ch);
  k_scan    <<<768, 256, 0, stream>>>(u_chA, u_chT, tdt_ch, B_ch, C_ch,
                                      Alog1, Alog2, D1, D2,
                                      dtw1, dtb1, dtw2, dtb2, y_px);
  k_mergeout<<<dim3(LL / 8, BN), 256, 0, stream>>>(y_px, sq,
                                                   fc1_w1, fc1_w2, fc2_w1, fc2_w2,
                                                   n1g, n1b, n2g, n2b,
                                                   wout, (float*)d_out);
}

// Round 15
// 156.808 us; speedup vs baseline: 1.5656x; 1.0712x over previous
//
#include <hip/hip_runtime.h>
#include <math.h>

#define BN   2
#define CIN  96
#define HH   40
#define WW   40
#define LL   1600
#define DIN  192
#define NS   16
#define RR   6
#define KK   4
#define CH   25   // chunk length per lane (LL/64)

typedef _Float16 h16;

__device__ __forceinline__ float sigmoidf_(float x){ return 1.0f/(1.0f+expf(-x)); }
__device__ __forceinline__ float softplus_fast(float x){
  return x > 20.0f ? x : __logf(1.0f + __expf(x));
}

// p[i] = R^(i+1) for i=0..15, log-depth tree (depth ~4, 15 muls)
__device__ __forceinline__ void pow_tree(float R, float* p){
  float R2 = R * R;
  float R4 = R2 * R2;
  float R8 = R4 * R4;
  p[0]  = R;        p[1]  = R2;       p[2]  = R2 * R;   p[3]  = R4;
  p[4]  = R4 * R;   p[5]  = R4 * R2;  p[6]  = R4 * p[2];p[7]  = R8;
  p[8]  = R8 * R;   p[9]  = R8 * R2;  p[10] = R8 * p[2];p[11] = R8 * R4;
  p[12] = R8 * p[4];p[13] = R8 * p[5];p[14] = R8 * p[6];p[15] = R8 * R8;
}

__device__ __forceinline__ void unpack8(float4 v, float* dst){
  const h16* hp = reinterpret_cast<const h16*>(&v);
  #pragma unroll
  for (int i = 0; i < 8; ++i) dst[i] = (float)hp[i];
}

// ---------------- K1: in_proj (1x1) for both modalities ----------------
// grid: (L/16, 2*B), block 256. xproj layout [mb][o][p] (f32)
__global__ void k_inproj(const float* __restrict__ x_rgb, const float* __restrict__ x_e,
                         const float* __restrict__ w_rgb, const float* __restrict__ w_e,
                         float* __restrict__ xproj){
  __shared__ float xin[16][100];          // [px][c], padded row
  int l0 = blockIdx.x * 16;
  int mb = blockIdx.y;                    // m*BN + b
  int m = mb / BN, b = mb % BN;
  const float* xsrc = (m == 0 ? x_rgb : x_e) + (size_t)b * CIN * LL;
  const float* w    = (m == 0 ? w_rgb : w_e);
  for (int idx = threadIdx.x; idx < CIN * 16; idx += 256){
    int c = idx >> 4, px = idx & 15;
    xin[px][c] = xsrc[c * LL + l0 + px];
  }
  __syncthreads();
  int px = threadIdx.x & 15;
  int o0 = (threadIdx.x >> 4) * 12;       // 16 groups x 12 outputs
  float acc[12];
  #pragma unroll
  for (int i = 0; i < 12; ++i) acc[i] = 0.f;
  const float4* xv = reinterpret_cast<const float4*>(xin[px]);
  for (int cc = 0; cc < CIN / 4; ++cc){
    float4 x4 = xv[cc];
    #pragma unroll
    for (int i = 0; i < 12; ++i){
      float4 w4 = *reinterpret_cast<const float4*>(w + (o0 + i) * CIN + cc * 4);
      acc[i] += w4.x * x4.x + w4.y * x4.y + w4.z * x4.z + w4.w * x4.w;
    }
  }
  #pragma unroll
  for (int i = 0; i < 12; ++i)
    xproj[((size_t)mb * DIN + o0 + i) * LL + l0 + px] = acc[i];
}

// ------ K2: depthwise 3x3 + bias + SiLU; emit HALF x_act/x_actT/u_ch + SE mean
// grid: (DIN, 2*B), block 256
__global__ void k_conv(const float* __restrict__ xproj, const float* __restrict__ conv_w,
                       const float* __restrict__ conv_b, h16* __restrict__ x_act,
                       h16* __restrict__ x_actT, h16* __restrict__ u_chA,
                       h16* __restrict__ u_chT, float* __restrict__ sq){
  __shared__ float pl[LL];
  __shared__ float sact[LL + HH];    // padded: index l + l/40
  __shared__ float red[4];
  int d  = blockIdx.x;
  int mb = blockIdx.y;
  const float* src = xproj + ((size_t)mb * DIN + d) * LL;
  for (int p = threadIdx.x; p < LL; p += blockDim.x) pl[p] = src[p];
  __syncthreads();
  float cw[9];
  #pragma unroll
  for (int j = 0; j < 9; ++j) cw[j] = conv_w[d * 9 + j];
  float bias = conv_b[d];
  h16* dst = x_act + ((size_t)mb * DIN + d) * LL;
  float lsum = 0.f;
  for (int p = threadIdx.x; p < LL; p += blockDim.x){
    int py = p / WW, px = p % WW;
    float acc = bias;
    #pragma unroll
    for (int dy = -1; dy <= 1; ++dy){
      int yy = py + dy;
      if (yy < 0 || yy >= HH) continue;
      #pragma unroll
      for (int dx = -1; dx <= 1; ++dx){
        int xx = px + dx;
        if (xx < 0 || xx >= WW) continue;
        acc += cw[(dy + 1) * 3 + (dx + 1)] * pl[yy * WW + xx];
      }
    }
    float s = acc * sigmoidf_(acc);
    dst[p] = (h16)s;
    sact[p + p / WW] = s;
    lsum += s;
  }
  #pragma unroll
  for (int off = 32; off; off >>= 1) lsum += __shfl_down(lsum, off);
  if ((threadIdx.x & 63) == 0) red[threadIdx.x >> 6] = lsum;
  __syncthreads();
  if (threadIdx.x == 0)
    sq[mb * DIN + d] = (red[0] + red[1] + red[2] + red[3]) * (1.0f / LL);
  size_t po = ((size_t)mb * DIN + d) * LL;
  h16* dstT = x_actT + po;
  h16* uA   = u_chA + po;
  h16* uT   = u_chT + po;
  for (int q = threadIdx.x; q < LL; q += blockDim.x){
    int lt = (q % WW) * WW + q / WW;
    dstT[q] = (h16)sact[lt + lt / WW];
    int l = (q & 63) * CH + (q >> 6);
    uA[q] = (h16)sact[l + l / WW];
    int pt = (l % WW) * WW + l / WW;
    uT[q] = (h16)sact[pt + pt / WW];
  }
}

// ------ K3: x_proj — register-blocked. B/C stored HALF in [mbk][n/8][q][8] --
// grid: (L/64, K, 2*B), block 256.
__global__ void k_xproj(const h16* __restrict__ x_act, const h16* __restrict__ x_actT,
                        const float* __restrict__ xp1, const float* __restrict__ xp2,
                        float* __restrict__ tdt_ch, h16* __restrict__ B_ch,
                        h16* __restrict__ C_ch){
  int l0 = blockIdx.x * 64;
  int k  = blockIdx.y;
  int mb = blockIdx.z; int m = mb / BN;
  const float* xw = (m == 0 ? xp1 : xp2) + k * 38 * DIN;
  const h16* xa = ((k & 1) ? x_actT : x_act) + (size_t)mb * DIN * LL;
  bool rev = (k >= 2);
  int ll = threadIdx.x & 63;
  int g  = threadIdx.x >> 6;            // wave id = output group
  int c0 = g * 10;                      // groups: 10,10,10,8 outputs
  int l  = l0 + ll; if (rev) l = LL - 1 - l;
  const h16* xcol = xa + l;             // xcol[dd*LL]
  float acc[10];
  #pragma unroll
  for (int i = 0; i < 10; ++i) acc[i] = 0.f;
  if (g < 3){
    for (int dd = 0; dd < DIN; ++dd){
      float xv = (float)xcol[(size_t)dd * LL];
      #pragma unroll
      for (int i = 0; i < 10; ++i) acc[i] += xw[(c0 + i) * DIN + dd] * xv;
    }
  } else {
    for (int dd = 0; dd < DIN; ++dd){
      float xv = (float)xcol[(size_t)dd * LL];
      #pragma unroll
      for (int i = 0; i < 8; ++i) acc[i] += xw[(c0 + i) * DIN + dd] * xv;
    }
  }
  int mbk = mb * KK + k;
  int lq = l0 + ll;                     // scan position (un-reversed)
  int q = (lq % CH) * 64 + lq / CH;     // chunk-order index
  int nc = (g < 3) ? 10 : 8;
  for (int i = 0; i < nc; ++i){
    int c = c0 + i;
    float v = acc[i];
    if (c < RR){
      tdt_ch[((size_t)mbk * RR + c) * LL + q] = v;
    } else if (c < RR + NS){
      int n = c - RR;
      B_ch[(((size_t)mbk * 2 + (n >> 3)) * LL + q) * 8 + (n & 7)] = (h16)v;
    } else {
      int n = c - RR - NS;
      C_ch[(((size_t)mbk * 2 + (n >> 3)) * LL + q) * 8 + (n & 7)] = (h16)v;
    }
  }
}

// ---------------- K4: chunked parallel selective scan -------------------
// ONE WAVE PER CHAIN, 16 states in registers, wave-private LDS. HALF inputs:
// B/C = 2 x dwordx4 (8 halfs each) per operand per step (was 4 loads);
// u half. Register double-buffered loads; pow_tree exps; half ystage.
// grid: 768 blocks of 256 (4 chains/block). y_px HALF [chain][pixel]
__global__ void __launch_bounds__(256, 4) k_scan(
    const h16* __restrict__ u_chA, const h16* __restrict__ u_chT,
    const float* __restrict__ tdt_all, const h16* __restrict__ B_ch,
    const h16* __restrict__ C_ch,
    const float* __restrict__ Alog1, const float* __restrict__ Alog2,
    const float* __restrict__ D1, const float* __restrict__ D2,
    const float* __restrict__ dtw1, const float* __restrict__ dtb1,
    const float* __restrict__ dtw2, const float* __restrict__ dtb2,
    h16* __restrict__ y_px){
  __shared__ h16 ysth[4][LL];               // [wave][l]  (wave-private)
  __shared__ float dt_lds[4][LL];           // [wave][q]  (wave-private)
  int wv   = threadIdx.x >> 6;
  int lane = threadIdx.x & 63;
  int chain = blockIdx.x * 4 + wv;          // = (mb*KK + k)*DIN + d
  int d   = chain % DIN;
  int mbk = chain / DIN;
  int k   = mbk % KK;
  int mb  = mbk / KK;
  int m = mb / BN, b = mb % BN;
  int kd = k * DIN + d;
  bool rev = (k >= 2);

  const float* Alog = (m == 0 ? Alog1 : Alog2) + kd * NS;
  float An[NS];
  bool fastA = true;
  #pragma unroll
  for (int n = 0; n < NS; ++n){
    An[n] = -__expf(Alog[n]);
    fastA = fastA && (fabsf(An[n] + (float)(n + 1)) <= 1e-4f * (float)(n + 1));
  }
  float Dv = (m == 0 ? D2 : D1)[kd];
  const float* dtw = (m == 0 ? dtw1 : dtw2) + kd * RR;
  float w0 = dtw[0], w1 = dtw[1], w2 = dtw[2], w3 = dtw[3], w4 = dtw[4], w5 = dtw[5];
  float dbias = (m == 0 ? dtb1 : dtb2)[kd];

  const float* t0 = tdt_all + (size_t)mbk * RR * LL;    // [r][q] rows
  for (int s = 0; s < CH; ++s){
    int q = s * 64 + lane;
    float dtpre = w0 * t0[q] + w1 * t0[LL + q] + w2 * t0[2 * LL + q]
                + w3 * t0[3 * LL + q] + w4 * t0[4 * LL + q] + w5 * t0[5 * LL + q] + dbias;
    dt_lds[wv][q] = softplus_fast(dtpre);
  }

  const float4* B0 = reinterpret_cast<const float4*>(B_ch) + (size_t)mbk * 2 * LL;
  int mbk_o = ((1 - m) * BN + b) * KK + k;              // other modality's C
  const float4* C0 = reinterpret_cast<const float4*>(C_ch) + (size_t)mbk_o * 2 * LL;
  const h16* urow = ((k & 1) ? u_chT : u_chA) + ((size_t)mb * DIN + d) * LL;

  float h[NS];
  #pragma unroll
  for (int n = 0; n < NS; ++n) h[n] = 0.f;
  float Sdt = 0.f;

  // phase 1: local chunk scan with register double-buffered loads
  if (fastA){
    float4 bP0, bP1, cP0, cP1; float uP, dtP;
    {
      int q0 = lane;
      dtP = dt_lds[wv][q0];
      uP  = (float)urow[rev ? (LL - 1 - q0) : q0];
      bP0 = B0[q0]; bP1 = B0[LL + q0];
      cP0 = C0[q0]; cP1 = C0[LL + q0];
    }
    #pragma unroll 5
    for (int s = 0; s < CH; ++s){
      float dt = dtP, u = uP;
      float4 b0 = bP0, b1 = bP1, c0 = cP0, c1 = cP1;
      if (s + 1 < CH){
        int q1 = (s + 1) * 64 + lane;
        dtP = dt_lds[wv][q1];
        uP  = (float)urow[rev ? (LL - 1 - q1) : q1];
        bP0 = B0[q1]; bP1 = B0[LL + q1];
        cP0 = C0[q1]; cP1 = C0[LL + q1];
      }
      Sdt += dt;
      float du = dt * u;
      float Bv[NS], Cv[NS];
      unpack8(b0, Bv); unpack8(b1, Bv + 8);
      unpack8(c0, Cv); unpack8(c1, Cv + 8);
      float p[NS];
      pow_tree(__expf(-dt), p);         // p[n] = exp(dt*An[n]), depth ~4
      float y0 = Dv * u, y1 = 0.f, y2 = 0.f, y3 = 0.f;
      #pragma unroll
      for (int n = 0; n < NS; ++n){
        h[n] = p[n] * h[n] + du * Bv[n];
        float t = h[n] * Cv[n];
        if      ((n & 3) == 0) y0 += t;
        else if ((n & 3) == 1) y1 += t;
        else if ((n & 3) == 2) y2 += t;
        else                   y3 += t;
      }
      ysth[wv][lane * CH + s] = (h16)((y0 + y1) + (y2 + y3));
    }
  } else {
    #pragma unroll 5
    for (int s = 0; s < CH; ++s){
      int q = s * 64 + lane;
      float dt = dt_lds[wv][q];
      Sdt += dt;
      float u  = (float)urow[rev ? (LL - 1 - q) : q];
      float du = dt * u;
      float Bv[NS], Cv[NS];
      unpack8(B0[q], Bv); unpack8(B0[LL + q], Bv + 8);
      unpack8(C0[q], Cv); unpack8(C0[LL + q], Cv + 8);
      float y0 = Dv * u, y1 = 0.f, y2 = 0.f, y3 = 0.f;
      #pragma unroll
      for (int n = 0; n < NS; ++n){
        float dA = __expf(dt * An[n]);
        h[n] = dA * h[n] + du * Bv[n];
        float t = h[n] * Cv[n];
        if      ((n & 3) == 0) y0 += t;
        else if ((n & 3) == 1) y1 += t;
        else if ((n & 3) == 2) y2 += t;
        else                   y3 += t;
      }
      ysth[wv][lane * CH + s] = (h16)((y0 + y1) + (y2 + y3));
    }
  }
  float aP[NS];
  if (fastA){
    pow_tree(__expf(-Sdt), aP);
  } else {
    #pragma unroll
    for (int n = 0; n < NS; ++n) aP[n] = __expf(Sdt * An[n]);
  }

  // Kogge-Stone inclusive scan of (aP,h) across 64 lanes (chunk order)
  #pragma unroll
  for (int off = 1; off < 64; off <<= 1){
    #pragma unroll
    for (int n = 0; n < NS; ++n){
      float ap = __shfl_up(aP[n], off);
      float bp = __shfl_up(h[n],  off);
      if (lane >= off){
        h[n]  = aP[n] * bp + h[n];
        aP[n] = aP[n] * ap;
      }
    }
  }
  // carry-in for this chunk = inclusive result of previous lane
  #pragma unroll
  for (int n = 0; n < NS; ++n){
    float v = __shfl_up(h[n], 1);
    h[n] = (lane == 0) ? 0.f : v;      // h[] now holds the carry
  }

  // phase 2: correction pass — ysth[l] += sum_n carry[n]*E_s^(n+1)*C[n]
  if (fastA){
    float4 cP0, cP1; float dtP;
    {
      int q0 = lane;
      dtP = dt_lds[wv][q0];
      cP0 = C0[q0]; cP1 = C0[LL + q0];
    }
    float cum = 0.f;
    #pragma unroll 5
    for (int s = 0; s < CH; ++s){
      float dt = dtP;
      float4 c0 = cP0, c1 = cP1;
      if (s + 1 < CH){
        int q1 = (s + 1) * 64 + lane;
        dtP = dt_lds[wv][q1];
        cP0 = C0[q1]; cP1 = C0[LL + q1];
      }
      cum += dt;                               // serial add chain only
      float Rc = __expf(-cum);                 // off the serial chain
      float Cv[NS];
      unpack8(c0, Cv); unpack8(c1, Cv + 8);
      float p[NS];
      pow_tree(Rc, p);                         // p[n] = exp(An[n]*cum)
      float s0 = 0.f, s1 = 0.f, s2 = 0.f, s3 = 0.f;
      #pragma unroll
      for (int n = 0; n < NS; ++n){
        float t = h[n] * p[n] * Cv[n];
        if      ((n & 3) == 0) s0 += t;
        else if ((n & 3) == 1) s1 += t;
        else if ((n & 3) == 2) s2 += t;
        else                   s3 += t;
      }
      int li = lane * CH + s;
      ysth[wv][li] = (h16)((float)ysth[wv][li] + (s0 + s1) + (s2 + s3));
    }
  } else {
    float cum = 0.f;
    #pragma unroll 5
    for (int s = 0; s < CH; ++s){
      int q = s * 64 + lane;
      cum += dt_lds[wv][q];
      float Cv[NS];
      unpack8(C0[q], Cv); unpack8(C0[LL + q], Cv + 8);
      float s0 = 0.f, s1 = 0.f, s2 = 0.f, s3 = 0.f;
      #pragma unroll
      for (int n = 0; n < NS; ++n){
        float t = h[n] * __expf(cum * An[n]) * Cv[n];
        if      ((n & 3) == 0) s0 += t;
        else if ((n & 3) == 1) s1 += t;
        else if ((n & 3) == 2) s2 += t;
        else                   s3 += t;
      }
      int li = lane * CH + s;
      ysth[wv][li] = (h16)((float)ysth[wv][li] + (s0 + s1) + (s2 + s3));
    }
  }

  // flush OWN ystage in PIXEL order (no barrier — wave-private buffer).
  h16* yo = y_px + (size_t)chain * LL;
  for (int qq = lane; qq < LL; qq += 64){
    int l;
    if      (k == 0) l = qq;
    else if (k == 1) l = (qq % WW) * WW + qq / WW;
    else if (k == 2) l = LL - 1 - qq;
    else             { int qt = (qq % WW) * WW + qq / WW; l = LL - 1 - qt; }
    yo[qq] = ysth[wv][l];
  }
}

// ------ K5: FUSED merge + LayerNorm + cross SE + out_proj ---------------
// grid: (L/8, B), block 256 — 400 blocks. y_px is HALF.
__global__ void __launch_bounds__(256) k_mergeout(
    const h16* __restrict__ y_px, const float* __restrict__ sq,
    const float* __restrict__ fc1_w1, const float* __restrict__ fc1_w2,
    const float* __restrict__ fc2_w1, const float* __restrict__ fc2_w2,
    const float* __restrict__ n1g, const float* __restrict__ n1b,
    const float* __restrict__ n2g, const float* __restrict__ n2b,
    const float* __restrict__ wout, float* __restrict__ out){
  __shared__ float acc[2 * DIN][9];       // [(m*DIN+dd)][pp]
  __shared__ float yt[8][388];            // [pp][m*DIN+dd], GEMM operand
  __shared__ float ps[2][8][16], ps2[2][8][16];
  __shared__ float mu_s[2][8], inv_s[2][8];
  __shared__ float sqs[2][DIN];           // sq of the OTHER modality, per m
  __shared__ float hid[2][12];
  __shared__ float exc_s[2][DIN];
  int p0 = blockIdx.x * 8;
  int b  = blockIdx.y;
  int tid = threadIdx.x;
  // region A: 4-direction merged sums + sq loads
  for (int idx = tid; idx < 2 * DIN * 8; idx += 256){
    int pp = idx & 7, row = idx >> 3;
    int mm = (row >= DIN), dd = row - mm * DIN;
    const h16* yb = y_px + ((size_t)(mm * BN + b) * KK * DIN + dd) * LL + p0 + pp;
    acc[row][pp] = (float)yb[0] + (float)yb[(size_t)DIN * LL]
                 + (float)yb[2 * (size_t)DIN * LL] + (float)yb[3 * (size_t)DIN * LL];
  }
  for (int i = tid; i < 2 * DIN; i += 256){
    int mm = (i >= DIN), dd = i - mm * DIN;
    sqs[mm][dd] = sq[((1 - mm) * BN + b) * DIN + dd];
  }
  __syncthreads();
  // region B: SE hidden layer (24 thr) + LN stats partials (all 256)
  if (tid < 24){
    int mm = tid / 12, j = tid - mm * 12;
    const float* w1 = (mm == 1 ? fc1_w1 : fc2_w1);
    float a = 0.f;
    for (int cch = 0; cch < DIN; ++cch) a += w1[j * DIN + cch] * sqs[mm][cch];
    hid[mm][j] = a * sigmoidf_(a);
  }
  {
    int pp = tid & 7, mm = (tid >> 3) & 1, g = tid >> 4;   // g in 0..15
    float s = 0.f, s2 = 0.f;
    #pragma unroll 4
    for (int j = 0; j < 12; ++j){
      float v = acc[mm * DIN + g * 12 + j][pp];
      s += v; s2 += v * v;
    }
    ps[mm][pp][g] = s; ps2[mm][pp][g] = s2;
  }
  __syncthreads();
  // region C: LN stats final (16 thr) + SE excitation (all, strided)
  if (tid < 16){
    int mm = tid >> 3, pp = tid & 7;
    float s = 0.f, s2 = 0.f;
    #pragma unroll
    for (int g = 0; g < 16; ++g){ s += ps[mm][pp][g]; s2 += ps2[mm][pp][g]; }
    float mu  = s * (1.0f / DIN);
    float var = s2 * (1.0f / DIN) - mu * mu;
    mu_s[mm][pp] = mu; inv_s[mm][pp] = rsqrtf(var + 1e-5f);
  }
  for (int i = tid; i < 2 * DIN; i += 256){
    int mm = (i >= DIN), dd = i - mm * DIN;
    const float* w2 = (mm == 1 ? fc1_w2 : fc2_w2);
    float e = 0.f;
    #pragma unroll
    for (int j = 0; j < 12; ++j) e += w2[dd * 12 + j] * hid[mm][j];
    exc_s[mm][dd] = sigmoidf_(e);
  }
  __syncthreads();
  // region D: normalize + SE scale into yt
  for (int idx = tid; idx < 2 * DIN * 8; idx += 256){
    int pp = idx & 7, row = idx >> 3;
    int mm = (row >= DIN), dd = row - mm * DIN;
    float g  = (mm ? n2g : n1g)[dd];
    float bb = (mm ? n2b : n1b)[dd];
    float v = (acc[row][pp] - mu_s[mm][pp]) * inv_s[mm][pp] * g + bb;
    yt[pp][row] = v * exc_s[mm][dd];
  }
  __syncthreads();
  // region E: out_proj 96x384 from LDS (32 groups x 3 outputs)
  int pp = tid & 7;
  int o0 = (tid >> 3) * 3;
  float a3[3] = {0.f, 0.f, 0.f};
  const float4* yv = reinterpret_cast<const float4*>(yt[pp]);
  for (int cc = 0; cc < 96; ++cc){
    float4 x4 = yv[cc];
    #pragma unroll
    for (int i = 0; i < 3; ++i){
      float4 w4 = *reinterpret_cast<const float4*>(wout + (o0 + i) * 2 * DIN + cc * 4);
      a3[i] += w4.x * x4.x + w4.y * x4.y + w4.z * x4.z + w4.w * x4.w;
    }
  }
  #pragma unroll
  for (int i = 0; i < 3; ++i)
    out[((size_t)b * CIN + o0 + i) * LL + p0 + pp] = a3[i];
}

extern "C" void kernel_launch(void* const* d_in, const int* in_sizes, int n_in,
                              void* d_out, int out_size, void* d_ws, size_t ws_size,
                              hipStream_t stream){
  const float* x_rgb   = (const float*)d_in[0];
  const float* x_e     = (const float*)d_in[1];
  const float* in_w    = (const float*)d_in[2];
  const float* in_mx_w = (const float*)d_in[3];
  const float* conv_w  = (const float*)d_in[4];
  const float* conv_b  = (const float*)d_in[5];
  const float* xp1     = (const float*)d_in[6];
  const float* xp2     = (const float*)d_in[7];
  const float* dtw1    = (const float*)d_in[8];
  const float* dtb1    = (const float*)d_in[9];
  const float* dtw2    = (const float*)d_in[10];
  const float* dtb2    = (const float*)d_in[11];
  const float* Alog1   = (const float*)d_in[12];
  const float* Alog2   = (const float*)d_in[13];
  const float* D1      = (const float*)d_in[14];
  const float* D2      = (const float*)d_in[15];
  const float* n1g     = (const float*)d_in[16];
  const float* n1b     = (const float*)d_in[17];
  const float* n2g     = (const float*)d_in[18];
  const float* n2b     = (const float*)d_in[19];
  const float* fc1_w1  = (const float*)d_in[20];
  const float* fc1_w2  = (const float*)d_in[21];
  const float* fc2_w1  = (const float*)d_in[22];
  const float* fc2_w2  = (const float*)d_in[23];
  const float* wout    = (const float*)d_in[24];

  float* ws = (float*)d_ws;
  // offsets in float units; half regions use half the space (rest padding)
  h16*   u_chA   = (h16*)(ws);                    // 1.2M halfs
  h16*   u_chT   = (h16*)(ws + 1228800);
  h16*   x_act   = (h16*)(ws + 2457600);
  h16*   x_actT  = (h16*)(ws + 3686400);
  float* xproj   = ws + 4915200;
  h16*   y_px    = (h16*)(ws + 6144000);
  h16*   B_ch    = (h16*)(ws + 11059200);
  h16*   C_ch    = (h16*)(ws + 11468800);
  float* tdt_ch  = ws + 11878400;
  float* sq      = ws + 12032000;

  k_inproj  <<<dim3(LL / 16, 2 * BN), 256, 0, stream>>>(x_rgb, x_e, in_w, in_mx_w, xproj);
  k_conv    <<<dim3(DIN, 2 * BN), 256, 0, stream>>>(xproj, conv_w, conv_b,
                                                    x_act, x_actT, u_chA, u_chT, sq);
  k_xproj   <<<dim3(LL / 64, KK, 2 * BN), 256, 0, stream>>>(x_act, x_actT, xp1, xp2,
                                                            tdt_ch, B_ch, C_ch);
  k_scan    <<<768, 256, 0, stream>>>(u_chA, u_chT, tdt_ch, B_ch, C_ch,
                                      Alog1, Alog2, D1, D2,
                                      dtw1, dtb1, dtw2, dtb2, y_px);
  k_mergeout<<<dim3(LL / 8, BN), 256, 0, stream>>>(y_px, sq,
                                                   fc1_w1, fc1_w2, fc2_w1, fc2_w2,
                                                   n1g, n1b, n2g, n2b,
                                                   wout, (float*)d_out);
}